// Round 4
// baseline (1324.510 us; speedup 1.0000x reference)
//
#include <hip/hip_runtime.h>

typedef unsigned short u16;
typedef __attribute__((ext_vector_type(8))) short bf16x8;
typedef __attribute__((ext_vector_type(4))) float f32x4;

#define N_PIX 16384
static constexpr long NP = 4L * 128 * N_PIX;   // elems in one [4,128,128,128]

__device__ __forceinline__ float bf2f(u16 h) {
  unsigned u = ((unsigned)h) << 16; float f; __builtin_memcpy(&f, &u, 4); return f;
}
__device__ __forceinline__ u16 f2bf(float f) {
  unsigned u; __builtin_memcpy(&u, &f, 4);
  u = (u + 0x7fffu + ((u >> 16) & 1u)) >> 16; return (u16)u;
}

__device__ __forceinline__ float blockReduceSum256(float v) {
  #pragma unroll
  for (int o = 32; o > 0; o >>= 1) v += __shfl_down(v, o, 64);
  __shared__ float sw[4];
  int lane = threadIdx.x & 63, w = threadIdx.x >> 6;
  if (lane == 0) sw[w] = v;
  __syncthreads();
  return (threadIdx.x == 0) ? (sw[0] + sw[1] + sw[2] + sw[3]) : 0.f;
}

// ---------------- squeeze: mean over HW of concat (f32 in) -> [4,256] f32 ----------------
__global__ __launch_bounds__(256) void squeeze_k(const float* __restrict__ vi,
                                                 const float* __restrict__ ir,
                                                 float* __restrict__ sq) {
  int c = blockIdx.x, b = blockIdx.y, tid = threadIdx.x;
  const float* src = (c < 128) ? (vi + ((long)b * 128 + c) * N_PIX)
                               : (ir + ((long)b * 128 + (c - 128)) * N_PIX);
  const f32x4* src4 = (const f32x4*)src;
  float s = 0.f;
  #pragma unroll
  for (int j = 0; j < 16; ++j) {
    f32x4 v = src4[j * 256 + tid];
    s += v.x + v.y + v.z + v.w;
  }
  float t = blockReduceSum256(s);
  if (tid == 0) sq[b * 256 + c] = t * (1.f / 16384.f);
}

// ---------------- SE MLP + top128 rank, text MLP + argsort256 (all f32) ----------------
__global__ __launch_bounds__(256) void control_k(const float* __restrict__ tc,
                                                 const float* __restrict__ sew1,
                                                 const float* __restrict__ sew2,
                                                 const float* __restrict__ tw1,
                                                 const float* __restrict__ tb1,
                                                 const float* __restrict__ tw2,
                                                 const float* __restrict__ tb2,
                                                 const float* __restrict__ sq,
                                                 int* __restrict__ idx,
                                                 int* __restrict__ sidx) {
  int b = blockIdx.x, tid = threadIdx.x;
  __shared__ float s_sq[256], s_h1[32], s_cw[256], s_tf1[512], s_tf[256];
  s_sq[tid] = sq[b * 256 + tid];
  __syncthreads();
  if (tid < 32) {
    float s = 0.f;
    for (int c = 0; c < 256; ++c) s += s_sq[c] * sew1[tid * 256 + c];
    s_h1[tid] = fmaxf(s, 0.f);
  }
  __syncthreads();
  {
    float s = 0.f;
    #pragma unroll
    for (int j = 0; j < 32; ++j) s += s_h1[j] * sew2[tid * 32 + j];
    s_cw[tid] = 1.f / (1.f + expf(-s));
  }
  __syncthreads();
  {
    float my = s_cw[tid];
    int rk = 0;
    for (int c = 0; c < 256; ++c) {
      float o = s_cw[c];
      rk += (o > my) || (o == my && c < tid);
    }
    if (rk < 128) idx[b * 128 + rk] = tid;
  }
  // text path
  for (int j = tid; j < 512; j += 256) {
    float s = tb1[j];
    for (int c = 0; c < 512; ++c) s += tc[b * 512 + c] * tw1[j * 512 + c];
    s_tf1[j] = fmaxf(s, 0.f);
  }
  __syncthreads();
  {
    float s = tb2[tid];
    for (int j = 0; j < 512; ++j) s += s_tf1[j] * tw2[tid * 512 + j];
    s_tf[tid] = s;
  }
  __syncthreads();
  {
    float my = s_tf[tid];
    int rk = 0;
    for (int c = 0; c < 256; ++c) {
      float o = s_tf[c];
      rk += (o > my) || (o == my && c < tid);
    }
    sidx[b * 256 + rk] = tid;
  }
}

// ---------------- fold conv1x1 + shuffle + conv_out + select into M_b[128,256] (f32) ----------------
__global__ __launch_bounds__(128) void mcomb_k(const float* __restrict__ w2,   // conv_out_w [128,256]
                                               const float* __restrict__ w2b,  // conv_out_b [128]
                                               const float* __restrict__ w1,   // conv1x1_w [256,128]
                                               const float* __restrict__ w1b,  // conv1x1_b [256]
                                               const int* __restrict__ idx,
                                               const int* __restrict__ sidx,
                                               float* __restrict__ mcomb,
                                               float* __restrict__ bcomb) {
  int o = blockIdx.x, b = blockIdx.y, tid = threadIdx.x;
  __shared__ float s_w2[256];
  __shared__ int s_sx[256];
  s_w2[tid] = w2[o * 256 + tid];
  s_w2[tid + 128] = w2[o * 256 + tid + 128];
  s_sx[tid] = sidx[b * 256 + tid] & 255;
  s_sx[tid + 128] = sidx[b * 256 + tid + 128] & 255;
  float* mrow = mcomb + ((long)b * 128 + o) * 256;
  mrow[tid] = 0.f;
  mrow[tid + 128] = 0.f;
  __syncthreads();
  float s = 0.f;
  for (int j = 0; j < 256; ++j) s += s_w2[j] * w1[s_sx[j] * 128 + tid];
  int cc = idx[b * 128 + tid] & 255;
  mrow[cc] = s;
  if (tid == 0) {
    float bb = w2b[o];
    for (int j = 0; j < 256; ++j) bb += s_w2[j] * w1b[s_sx[j]];
    bcomb[b * 128 + o] = bb;
  }
}

// ---------------- generic MFMA GEMM: out[b,o,n] = sum_k A[o,k] X[b,k,n] (+bias)(+res) ----------------
// AMODE: 0 = f32 global weights (bf16-rounded), 1 = f32 per-batch A split hi/lo.
// BMODE: 0 = single bf16 X, 1 = f32 concat(vi,ir).
// BIAS: 0 none, 1 global f32 bias[o], 2 per-batch f32 bias.
// RESADD: add bf16 residual.  OUTF: 0 bf16 out, 1 f32 out.
template<int AMODE, int BMODE, int BIAS, int RESADD, int OUTF>
__global__ __launch_bounds__(256) void gemm_k(
    const float* __restrict__ Aw, long a_bstride,
    const void* __restrict__ Xv, const float* __restrict__ X2f, long x_bstride,
    const float* __restrict__ bias, long bias_bstride,
    const u16* __restrict__ res, long res_bstride,
    void* __restrict__ outv, long out_bstride,
    int O, int K) {
  const int N = N_PIX;
  int n0 = blockIdx.x * 64;
  int o0 = blockIdx.y * 64;
  int bz = blockIdx.z;
  int tid = threadIdx.x;
  __shared__ __align__(16) u16 As[64][40];
  __shared__ __align__(16) u16 Al[64][40];
  __shared__ __align__(16) u16 Xs[64][40];
  f32x4 acc[4];
  #pragma unroll
  for (int i = 0; i < 4; ++i) acc[i] = (f32x4){0.f, 0.f, 0.f, 0.f};
  int wv = tid >> 6, lane = tid & 63;
  int lr = lane & 15, lk = (lane >> 4) * 8;
  int nk = (K + 31) >> 5;
  for (int kt = 0; kt < nk; ++kt) {
    int k0 = kt << 5;
    // stage A (64 rows x 32 k), f32 -> bf16 (hi/lo if AMODE==1)
    {
      int r = tid >> 2, cb = (tid & 3) << 3;
      int o = o0 + r;
      if (AMODE == 0) {
        if (o < O && (k0 + cb + 8 <= K)) {
          const float* ap = Aw + (long)o * K + k0 + cb;
          f32x4 v0 = *(const f32x4*)ap;
          f32x4 v1 = *(const f32x4*)(ap + 4);
          As[r][cb + 0] = f2bf(v0.x); As[r][cb + 1] = f2bf(v0.y);
          As[r][cb + 2] = f2bf(v0.z); As[r][cb + 3] = f2bf(v0.w);
          As[r][cb + 4] = f2bf(v1.x); As[r][cb + 5] = f2bf(v1.y);
          As[r][cb + 6] = f2bf(v1.z); As[r][cb + 7] = f2bf(v1.w);
        } else {
          #pragma unroll
          for (int i = 0; i < 8; ++i) {
            int k = k0 + cb + i;
            As[r][cb + i] = (o < O && k < K) ? f2bf(Aw[(long)o * K + k]) : (u16)0;
          }
        }
      } else {
        #pragma unroll
        for (int i = 0; i < 8; ++i) {
          int k = k0 + cb + i;
          float av = (o < O && k < K) ? Aw[(long)bz * a_bstride + (long)o * K + k] : 0.f;
          u16 hi = f2bf(av);
          As[r][cb + i] = hi;
          Al[r][cb + i] = f2bf(av - bf2f(hi));
        }
      }
    }
    // stage X transposed: Xs[n][k]
    {
      int kl = tid >> 3, nb = (tid & 7) << 3;
      int k = k0 + kl;
      u16 tmp[8];
      if (k < K) {
        if (BMODE == 1) {
          const float* src = (k < 128)
              ? ((const float*)Xv + ((long)bz * 128 + k) * N)
              : (X2f + ((long)bz * 128 + (k - 128)) * N);
          f32x4 v0 = *(const f32x4*)(src + n0 + nb);
          f32x4 v1 = *(const f32x4*)(src + n0 + nb + 4);
          tmp[0] = f2bf(v0.x); tmp[1] = f2bf(v0.y); tmp[2] = f2bf(v0.z); tmp[3] = f2bf(v0.w);
          tmp[4] = f2bf(v1.x); tmp[5] = f2bf(v1.y); tmp[6] = f2bf(v1.z); tmp[7] = f2bf(v1.w);
        } else {
          const u16* src = (const u16*)Xv + (long)bz * x_bstride + (long)k * N;
          bf16x8 t = *(const bf16x8*)(src + n0 + nb);
          #pragma unroll
          for (int i = 0; i < 8; ++i) tmp[i] = (u16)t[i];
        }
      } else {
        #pragma unroll
        for (int i = 0; i < 8; ++i) tmp[i] = 0;
      }
      #pragma unroll
      for (int i = 0; i < 8; ++i) Xs[nb + i][kl] = tmp[i];
    }
    __syncthreads();
    bf16x8 afr = *(const bf16x8*)&As[wv * 16 + lr][lk];
    bf16x8 alr;
    if (AMODE == 1) alr = *(const bf16x8*)&Al[wv * 16 + lr][lk];
    #pragma unroll
    for (int nt = 0; nt < 4; ++nt) {
      bf16x8 bfr = *(const bf16x8*)&Xs[nt * 16 + lr][lk];
      acc[nt] = __builtin_amdgcn_mfma_f32_16x16x32_bf16(afr, bfr, acc[nt], 0, 0, 0);
      if (AMODE == 1)
        acc[nt] = __builtin_amdgcn_mfma_f32_16x16x32_bf16(alr, bfr, acc[nt], 0, 0, 0);
    }
    __syncthreads();
  }
  #pragma unroll
  for (int nt = 0; nt < 4; ++nt) {
    #pragma unroll
    for (int r4 = 0; r4 < 4; ++r4) {
      int o = o0 + wv * 16 + (lane >> 4) * 4 + r4;
      int n = n0 + nt * 16 + (lane & 15);
      if (o < O) {
        float v = acc[nt][r4];
        if (BIAS == 1) v += bias[o];
        if (BIAS == 2) v += bias[(long)bz * bias_bstride + o];
        if (RESADD) v += bf2f(res[(long)bz * res_bstride + (long)o * N + n]);
        long oi = (long)bz * out_bstride + (long)o * N + n;
        if (OUTF) ((float*)outv)[oi] = v;
        else ((u16*)outv)[oi] = f2bf(v);
      }
    }
  }
}

// ---------------- LayerNorm over channel dim (C=128); INF: 0=f32 in, 1=bf16 in ----------------
template<int INF>
__global__ __launch_bounds__(256) void ln_k(const void* __restrict__ inv,
                                            const float* __restrict__ gamma,
                                            const float* __restrict__ beta,
                                            u16* __restrict__ out) {
  int p0 = blockIdx.x * 64, b = blockIdx.y, tid = threadIdx.x;
  int px = tid & 63, g4 = tid >> 6;
  __shared__ float tile[128][65];
  __shared__ float red[8][64];
  __shared__ float gmm[128], bta[128], mu_s[64], rs_s[64];
  if (tid < 128) { gmm[tid] = gamma[tid]; bta[tid] = beta[tid]; }
  long bofs = (long)b * 128 * N_PIX;
  float s = 0.f;
  for (int c = g4; c < 128; c += 4) {
    float v;
    if (INF == 0) v = ((const float*)inv)[bofs + (long)c * N_PIX + p0 + px];
    else          v = bf2f(((const u16*)inv)[bofs + (long)c * N_PIX + p0 + px]);
    tile[c][px] = v;
    s += v;
  }
  red[g4][px] = s;
  __syncthreads();
  if (g4 == 0) mu_s[px] = (red[0][px] + red[1][px] + red[2][px] + red[3][px]) * (1.f / 128.f);
  __syncthreads();
  float mu = mu_s[px];
  float s2 = 0.f;
  for (int c = g4; c < 128; c += 4) { float d = tile[c][px] - mu; s2 += d * d; }
  red[4 + g4][px] = s2;
  __syncthreads();
  if (g4 == 0) {
    float var = (red[4][px] + red[5][px] + red[6][px] + red[7][px]) * (1.f / 128.f);
    rs_s[px] = rsqrtf(var + 1e-5f);
  }
  __syncthreads();
  float rs = rs_s[px];
  for (int c = g4; c < 128; c += 4)
    out[bofs + (long)c * N_PIX + p0 + px] = f2bf((tile[c][px] - mu) * rs * gmm[c] + bta[c]);
}

// ---------------- depthwise 3x3, SAME, zero pad (bf16 in/out, f32 w) ----------------
__global__ __launch_bounds__(256) void dw3_k(const u16* __restrict__ in,
                                             const float* __restrict__ w,
                                             u16* __restrict__ out,
                                             int C, long total) {
  long idx = (long)blockIdx.x * 256 + threadIdx.x;
  if (idx >= total) return;
  int p = (int)(idx & (N_PIX - 1));
  long rest = idx >> 14;
  int c = (int)(rest % C);
  int y = p >> 7, x = p & 127;
  const u16* ip = in + (idx - p);   // base of this (b,c) row
  float wv[9];
  #pragma unroll
  for (int j = 0; j < 9; ++j) wv[j] = w[c * 9 + j];
  float s = 0.f;
  #pragma unroll
  for (int ky = -1; ky <= 1; ++ky) {
    int yy = y + ky;
    if (yy < 0 || yy > 127) continue;
    #pragma unroll
    for (int kx = -1; kx <= 1; ++kx) {
      int xx = x + kx;
      if (xx < 0 || xx > 127) continue;
      s += wv[(ky + 1) * 3 + (kx + 1)] * bf2f(ip[yy * 128 + xx]);
    }
  }
  out[idx] = f2bf(s);
}

// ---------------- row L2 norms: out[b*128+r] = ||row||_2 (bf16 in) ----------------
__global__ __launch_bounds__(256) void rownorm_k(const u16* __restrict__ base, long bstride,
                                                 float* __restrict__ out) {
  int r = blockIdx.x, b = blockIdx.y, tid = threadIdx.x;
  const u16* src = base + (long)b * bstride + (long)r * N_PIX;
  float s = 0.f;
  #pragma unroll
  for (int j = 0; j < 8; ++j) {
    bf16x8 v = *(const bf16x8*)(src + j * 2048 + tid * 8);
    #pragma unroll
    for (int i = 0; i < 8; ++i) { float f = bf2f((u16)v[i]); s += f * f; }
  }
  float t = blockReduceSum256(s);
  if (tid == 0) out[b * 128 + r] = sqrtf(t);
}

// ---------------- attn logits: [4,8,16,16] ----------------
__global__ __launch_bounds__(256) void attn_k(const u16* __restrict__ q,
                                              const u16* __restrict__ kbase, long kbstride,
                                              const float* __restrict__ qn,
                                              const float* __restrict__ kn,
                                              const float* __restrict__ temp,
                                              float* __restrict__ attnm) {
  int h = blockIdx.x, b = blockIdx.y, tid = threadIdx.x;
  __shared__ u16 qc[16][520];
  __shared__ u16 kc[16][520];
  int c = tid >> 4, d = tid & 15;
  float acc = 0.f;
  for (int ch = 0; ch < 32; ++ch) {
    int n0 = ch * 512;
    for (int i = tid; i < 16 * 512; i += 256) {
      int r = i >> 9, n = i & 511;
      qc[r][n] = q[((long)b * 128 + h * 16 + r) * N_PIX + n0 + n];
      kc[r][n] = kbase[(long)b * kbstride + (long)(h * 16 + r) * N_PIX + n0 + n];
    }
    __syncthreads();
    #pragma unroll 8
    for (int n = 0; n < 512; ++n) acc += bf2f(qc[c][n]) * bf2f(kc[d][n]);
    __syncthreads();
  }
  float nq = fmaxf(qn[b * 128 + h * 16 + c], 1e-12f);
  float nk = fmaxf(kn[b * 128 + h * 16 + d], 1e-12f);
  attnm[(((long)b * 8 + h) * 16 + c) * 16 + d] = acc / (nq * nk) * temp[h];
}

// ---------------- top14 threshold + softmax + fold proj into Cmb[b,128,128] ----------------
__global__ __launch_bounds__(128) void score_cmb_k(const float* __restrict__ attnm,
                                                   const float* __restrict__ projw,
                                                   const float* __restrict__ attn4p,
                                                   float* __restrict__ cmb) {
  int b = blockIdx.x, tid = threadIdx.x;
  __shared__ float att_s[2048], score_s[2048];
  for (int i = tid; i < 2048; i += 128) att_s[i] = attnm[(long)b * 2048 + i];
  __syncthreads();
  {
    int h = tid >> 4, c = tid & 15;
    float v[16], t[16];
    #pragma unroll
    for (int d = 0; d < 16; ++d) { v[d] = att_s[(h * 16 + c) * 16 + d]; t[d] = v[d]; }
    float thr = 0.f, M = -1e30f;
    for (int it = 0; it < 14; ++it) {
      float m = -1e30f; int mi = 0;
      #pragma unroll
      for (int d = 0; d < 16; ++d) if (t[d] > m) { m = t[d]; mi = d; }
      if (it == 0) M = m;
      thr = m;
      t[mi] = -1e31f;
    }
    float s = 0.f, e[16];
    #pragma unroll
    for (int d = 0; d < 16; ++d) { e[d] = (v[d] >= thr) ? expf(v[d] - M) : 0.f; s += e[d]; }
    float inv = 1.f / s;
    #pragma unroll
    for (int d = 0; d < 16; ++d) score_s[(h * 16 + c) * 16 + d] = e[d] * inv;
  }
  __syncthreads();
  float a4 = attn4p[0];
  int o = tid;
  for (int hd = 0; hd < 128; ++hd) {
    int h = hd >> 4, d = hd & 15;
    float s = 0.f;
    #pragma unroll
    for (int c = 0; c < 16; ++c)
      s += projw[o * 128 + h * 16 + c] * score_s[(h * 16 + c) * 16 + d];
    cmb[((long)b * 128 + o) * 128 + hd] = a4 * s;
  }
}

// ---------------- gelu(y1)*y2 -> g [340,N] (bf16) ----------------
__global__ __launch_bounds__(256) void gelumul_k(const u16* __restrict__ y1,
                                                 const u16* __restrict__ y2,
                                                 u16* __restrict__ g) {
  long base = ((long)blockIdx.x * 256 + threadIdx.x) * 8;
  if (base >= 340L * N_PIX) return;
  bf16x8 a = *(const bf16x8*)(y1 + base);
  bf16x8 bv = *(const bf16x8*)(y2 + base);
  u16 r[8];
  #pragma unroll
  for (int i = 0; i < 8; ++i) {
    float x = bf2f((u16)a[i]);
    float gl = 0.5f * x * (1.f + erff(x * 0.70710678118f));
    r[i] = f2bf(gl * bf2f((u16)bv[i]));
  }
  #pragma unroll
  for (int i = 0; i < 8; ++i) g[base + i] = r[i];
}

extern "C" void kernel_launch(void* const* d_in, const int* in_sizes, int n_in,
                              void* d_out, int out_size, void* d_ws, size_t ws_size,
                              hipStream_t stream) {
  (void)in_sizes; (void)n_in; (void)out_size; (void)ws_size;
  const float* vi        = (const float*)d_in[0];
  const float* ir        = (const float*)d_in[1];
  const float* text_code = (const float*)d_in[2];
  const float* se_w1     = (const float*)d_in[3];
  const float* se_w2     = (const float*)d_in[4];
  const float* conv1x1_w = (const float*)d_in[5];
  const float* conv1x1_b = (const float*)d_in[6];
  const float* conv_out_w= (const float*)d_in[7];
  const float* conv_out_b= (const float*)d_in[8];
  const float* text_w1   = (const float*)d_in[9];
  const float* text_b1   = (const float*)d_in[10];
  const float* text_w2   = (const float*)d_in[11];
  const float* text_b2   = (const float*)d_in[12];
  const float* norm1_w   = (const float*)d_in[13];
  const float* norm1_b   = (const float*)d_in[14];
  const float* norm2_w   = (const float*)d_in[15];
  const float* norm2_b   = (const float*)d_in[16];
  const float* norm3_w   = (const float*)d_in[17];
  const float* norm3_b   = (const float*)d_in[18];
  const float* q_w       = (const float*)d_in[19];
  const float* q_dw_w    = (const float*)d_in[20];
  const float* kv_w      = (const float*)d_in[21];
  const float* kv_dw_w   = (const float*)d_in[22];
  const float* temperature = (const float*)d_in[23];
  const float* attn4     = (const float*)d_in[24];
  const float* proj_w    = (const float*)d_in[25];
  const float* ffn_in_w  = (const float*)d_in[26];
  const float* ffn_dw_w  = (const float*)d_in[27];
  const float* ffn_out_w = (const float*)d_in[28];
  float* out0 = (float*)d_out;       // output 0 [4,128,128,128] f32
  float* out1 = out0 + NP;           // output 1 (img_feature2) f32

  // ---- workspace: 1 MiB small pool + bf16 arena of 2048*N_PIX elems (64 MiB) ----
  char* W = (char*)d_ws;
  float* sq_f  = (float*)(W + 0);        // 4KB
  int*   idx_i = (int*)(W + 4096);       // 2KB
  int*   sidx_i= (int*)(W + 6144);       // 4KB
  float* mcomb = (float*)(W + 12288);    // 512KB
  float* bcomb = (float*)(W + 536576);   // 2KB
  float* qn_f  = (float*)(W + 538624);   // 2KB
  float* kn_f  = (float*)(W + 540672);   // 2KB
  float* attnm = (float*)(W + 542720);   // 32KB
  float* cmb   = (float*)(W + 575488);   // 256KB
  u16* S   = (u16*)(W + (1 << 20));      // arena, N_PIX-elem units
  u16* CC  = S;                          // [0,512N): xkv -> xq -> qd -> x3
  u16* KD  = S + 512L * N_PIX;           // [512N,1024N): K -> ATT
  u16* VD  = S + 1024L * N_PIX;          // [1024N,1536N): V
  u16* TMP = S + 1536L * N_PIX;          // [1536N,2048N): kvt/q_in/qt
  u16* FY1 = S + 1024L * N_PIX;          // FFN y1 [1024N,1364N)  (VD dead)
  u16* FT  = S + 1364L * N_PIX;          // FFN t1/t2/g [1364N,1704N)
  u16* FY2 = S + 1704L * N_PIX;          // FFN y2 [1704N,2044N)
  u16* ATT = KD;

  const long SN = 128L * N_PIX;  // per-batch stride of a 128-ch tensor

  // control path
  squeeze_k<<<dim3(256, 4), 256, 0, stream>>>(vi, ir, sq_f);
  control_k<<<4, 256, 0, stream>>>(text_code, se_w1, se_w2, text_w1, text_b1,
                                   text_w2, text_b2, sq_f, idx_i, sidx_i);
  mcomb_k<<<dim3(128, 4), 128, 0, stream>>>(conv_out_w, conv_out_b, conv1x1_w,
                                            conv1x1_b, idx_i, sidx_i, mcomb, bcomb);
  // img_feature2 = conv_out_w @ concat + b  -> out1 (f32)
  gemm_k<0, 1, 1, 0, 1><<<dim3(256, 2, 4), 256, 0, stream>>>(
      conv_out_w, 0, vi, ir, 0, conv_out_b, 0, nullptr, 0, out1, SN, 128, 256);
  // KV path
  ln_k<0><<<dim3(256, 4), 256, 0, stream>>>(out1, norm2_w, norm2_b, CC);     // xkv
  gemm_k<0, 0, 0, 0, 0><<<dim3(256, 2, 4), 256, 0, stream>>>(
      kv_w, 0, CC, nullptr, SN, nullptr, 0, nullptr, 0, TMP, SN, 128, 128);  // kvt_k
  dw3_k<<<32768, 256, 0, stream>>>(TMP, kv_dw_w, KD, 128, NP);               // K
  gemm_k<0, 0, 0, 0, 0><<<dim3(256, 2, 4), 256, 0, stream>>>(
      kv_w + 128 * 128, 0, CC, nullptr, SN, nullptr, 0, nullptr, 0, TMP, SN, 128, 128);
  dw3_k<<<32768, 256, 0, stream>>>(TMP, kv_dw_w + 128 * 9, VD, 128, NP);     // V
  // Q path
  gemm_k<1, 1, 2, 0, 0><<<dim3(256, 2, 4), 256, 0, stream>>>(
      mcomb, 128L * 256, vi, ir, 0, bcomb, 128, nullptr, 0, TMP, SN, 128, 256); // q_in
  ln_k<1><<<dim3(256, 4), 256, 0, stream>>>(TMP, norm1_w, norm1_b, CC);      // xq
  gemm_k<0, 0, 0, 0, 0><<<dim3(256, 2, 4), 256, 0, stream>>>(
      q_w, 0, CC, nullptr, SN, nullptr, 0, nullptr, 0, TMP, SN, 128, 128);   // qt
  dw3_k<<<32768, 256, 0, stream>>>(TMP, q_dw_w, CC, 128, NP);                // qd
  // attention
  rownorm_k<<<dim3(128, 4), 256, 0, stream>>>(CC, SN, qn_f);
  rownorm_k<<<dim3(128, 4), 256, 0, stream>>>(KD, SN, kn_f);
  attn_k<<<dim3(8, 4), 256, 0, stream>>>(CC, KD, SN, qn_f, kn_f, temperature, attnm);
  score_cmb_k<<<4, 128, 0, stream>>>(attnm, proj_w, attn4, cmb);
  // att = Cmb_b @ v -> ATT (=KD slot, K dead)
  gemm_k<1, 0, 0, 0, 0><<<dim3(256, 2, 4), 256, 0, stream>>>(
      cmb, 128L * 128, VD, nullptr, SN, nullptr, 0, nullptr, 0, ATT, SN, 128, 128);
  ln_k<1><<<dim3(256, 4), 256, 0, stream>>>(ATT, norm3_w, norm3_b, CC);      // x3
  // FFN per batch (halved GEGLU): t1->FT, y1->FY1, t2->FT, y2->FY2, g->FT
  for (int b = 0; b < 4; ++b) {
    const u16* x3b = CC + (long)b * SN;
    gemm_k<0, 0, 0, 0, 0><<<dim3(256, 6, 1), 256, 0, stream>>>(
        ffn_in_w, 0, x3b, nullptr, 0, nullptr, 0, nullptr, 0, FT, 0, 340, 128);
    dw3_k<<<21760, 256, 0, stream>>>(FT, ffn_dw_w, FY1, 340, 340L * N_PIX);
    gemm_k<0, 0, 0, 0, 0><<<dim3(256, 6, 1), 256, 0, stream>>>(
        ffn_in_w + 340 * 128, 0, x3b, nullptr, 0, nullptr, 0, nullptr, 0, FT, 0, 340, 128);
    dw3_k<<<21760, 256, 0, stream>>>(FT, ffn_dw_w + 340 * 9, FY2, 340, 340L * N_PIX);
    gelumul_k<<<2720, 256, 0, stream>>>(FY1, FY2, FT);
    gemm_k<0, 0, 0, 1, 1><<<dim3(256, 2, 1), 256, 0, stream>>>(
        ffn_out_w, 0, FT, nullptr, 0, nullptr, 0, ATT + (long)b * SN, 0,
        out0 + (long)b * SN, 0, 128, 340);
  }
}

// Round 5
// 825.847 us; speedup vs baseline: 1.6038x; 1.6038x over previous
//
#include <hip/hip_runtime.h>

typedef unsigned short u16;
typedef __attribute__((ext_vector_type(8))) short bf16x8;
typedef __attribute__((ext_vector_type(4))) float f32x4;

#define N_PIX 16384
static constexpr long NP = 4L * 128 * N_PIX;   // elems in one [4,128,128,128]

__device__ __forceinline__ float bf2f(u16 h) {
  unsigned u = ((unsigned)h) << 16; float f; __builtin_memcpy(&f, &u, 4); return f;
}
__device__ __forceinline__ u16 f2bf(float f) {
  unsigned u; __builtin_memcpy(&u, &f, 4);
  u = (u + 0x7fffu + ((u >> 16) & 1u)) >> 16; return (u16)u;
}

__device__ __forceinline__ float blockReduceSum256(float v) {
  #pragma unroll
  for (int o = 32; o > 0; o >>= 1) v += __shfl_down(v, o, 64);
  __shared__ float sw[4];
  int lane = threadIdx.x & 63, w = threadIdx.x >> 6;
  if (lane == 0) sw[w] = v;
  __syncthreads();
  return (threadIdx.x == 0) ? (sw[0] + sw[1] + sw[2] + sw[3]) : 0.f;
}

// ---- squeeze: mean over HW of concat (f32 in) -> [4,256] f32 ; also emit bf16 concat ----
__global__ __launch_bounds__(256) void squeeze_k(const float* __restrict__ vi,
                                                 const float* __restrict__ ir,
                                                 float* __restrict__ sq,
                                                 u16* __restrict__ cbf) {
  int c = blockIdx.x, b = blockIdx.y, tid = threadIdx.x;
  const float* src = (c < 128) ? (vi + ((long)b * 128 + c) * N_PIX)
                               : (ir + ((long)b * 128 + (c - 128)) * N_PIX);
  const f32x4* src4 = (const f32x4*)src;
  u16* dst = cbf + ((long)b * 256 + c) * N_PIX;
  float s = 0.f;
  #pragma unroll
  for (int j = 0; j < 8; ++j) {
    f32x4 v0 = src4[j * 512 + tid * 2];
    f32x4 v1 = src4[j * 512 + tid * 2 + 1];
    s += v0.x + v0.y + v0.z + v0.w + v1.x + v1.y + v1.z + v1.w;
    bf16x8 r;
    r[0] = (short)f2bf(v0.x); r[1] = (short)f2bf(v0.y);
    r[2] = (short)f2bf(v0.z); r[3] = (short)f2bf(v0.w);
    r[4] = (short)f2bf(v1.x); r[5] = (short)f2bf(v1.y);
    r[6] = (short)f2bf(v1.z); r[7] = (short)f2bf(v1.w);
    *(bf16x8*)(dst + j * 2048 + tid * 8) = r;
  }
  float t = blockReduceSum256(s);
  if (tid == 0) sq[b * 256 + c] = t * (1.f / 16384.f);
}

// ---------------- SE MLP + top128 rank, text MLP + argsort256 (all f32) ----------------
__global__ __launch_bounds__(256) void control_k(const float* __restrict__ tc,
                                                 const float* __restrict__ sew1,
                                                 const float* __restrict__ sew2,
                                                 const float* __restrict__ tw1,
                                                 const float* __restrict__ tb1,
                                                 const float* __restrict__ tw2,
                                                 const float* __restrict__ tb2,
                                                 const float* __restrict__ sq,
                                                 int* __restrict__ idx,
                                                 int* __restrict__ sidx) {
  int b = blockIdx.x, tid = threadIdx.x;
  __shared__ float s_sq[256], s_h1[32], s_cw[256], s_tf1[512], s_tf[256];
  s_sq[tid] = sq[b * 256 + tid];
  __syncthreads();
  if (tid < 32) {
    float s = 0.f;
    for (int c = 0; c < 256; ++c) s += s_sq[c] * sew1[tid * 256 + c];
    s_h1[tid] = fmaxf(s, 0.f);
  }
  __syncthreads();
  {
    float s = 0.f;
    #pragma unroll
    for (int j = 0; j < 32; ++j) s += s_h1[j] * sew2[tid * 32 + j];
    s_cw[tid] = 1.f / (1.f + expf(-s));
  }
  __syncthreads();
  {
    float my = s_cw[tid];
    int rk = 0;
    for (int c = 0; c < 256; ++c) {
      float o = s_cw[c];
      rk += (o > my) || (o == my && c < tid);
    }
    if (rk < 128) idx[b * 128 + rk] = tid;
  }
  for (int j = tid; j < 512; j += 256) {
    float s = tb1[j];
    for (int c = 0; c < 512; ++c) s += tc[b * 512 + c] * tw1[j * 512 + c];
    s_tf1[j] = fmaxf(s, 0.f);
  }
  __syncthreads();
  {
    float s = tb2[tid];
    for (int j = 0; j < 512; ++j) s += s_tf1[j] * tw2[tid * 512 + j];
    s_tf[tid] = s;
  }
  __syncthreads();
  {
    float my = s_tf[tid];
    int rk = 0;
    for (int c = 0; c < 256; ++c) {
      float o = s_tf[c];
      rk += (o > my) || (o == my && c < tid);
    }
    sidx[b * 256 + rk] = tid;
  }
}

// ---------------- fold conv1x1 + shuffle + conv_out + select into M_b[128,256] ----------------
__global__ __launch_bounds__(128) void mcomb_k(const float* __restrict__ w2,
                                               const float* __restrict__ w2b,
                                               const float* __restrict__ w1,
                                               const float* __restrict__ w1b,
                                               const int* __restrict__ idx,
                                               const int* __restrict__ sidx,
                                               float* __restrict__ mcomb,
                                               float* __restrict__ bcomb) {
  int o = blockIdx.x, b = blockIdx.y, tid = threadIdx.x;
  __shared__ float s_w2[256];
  __shared__ int s_sx[256];
  s_w2[tid] = w2[o * 256 + tid];
  s_w2[tid + 128] = w2[o * 256 + tid + 128];
  s_sx[tid] = sidx[b * 256 + tid] & 255;
  s_sx[tid + 128] = sidx[b * 256 + tid + 128] & 255;
  float* mrow = mcomb + ((long)b * 128 + o) * 256;
  mrow[tid] = 0.f;
  mrow[tid + 128] = 0.f;
  __syncthreads();
  float s = 0.f;
  for (int j = 0; j < 256; ++j) s += s_w2[j] * w1[s_sx[j] * 128 + tid];
  int cc = idx[b * 128 + tid] & 255;
  mrow[cc] = s;
  if (tid == 0) {
    float bb = w2b[o];
    for (int j = 0; j < 256; ++j) bb += s_w2[j] * w1b[s_sx[j]];
    bcomb[b * 128 + o] = bb;
  }
}

// ---- fused dual GEMM over bf16 concat: out1/img2b = conv_out@X + b ; qin = M_b@X + bcomb ----
__global__ __launch_bounds__(256) void gemm_dual_k(
    const float* __restrict__ W2, const float* __restrict__ b2,
    const float* __restrict__ Mc, const float* __restrict__ bc,
    const u16* __restrict__ Xb,
    float* __restrict__ out1, u16* __restrict__ img2b, u16* __restrict__ qin) {
  const int N = N_PIX;
  int n0 = blockIdx.x * 64, o0 = blockIdx.y * 64, bz = blockIdx.z, tid = threadIdx.x;
  __shared__ __align__(16) u16 A1[64][40];
  __shared__ __align__(16) u16 A2h[64][40];
  __shared__ __align__(16) u16 A2l[64][40];
  __shared__ __align__(16) u16 Xs[64][40];
  f32x4 acc1[4], acc2[4];
  #pragma unroll
  for (int i = 0; i < 4; ++i) { acc1[i] = (f32x4){0,0,0,0}; acc2[i] = (f32x4){0,0,0,0}; }
  int wv = tid >> 6, lane = tid & 63;
  int lr = lane & 15, lk = (lane >> 4) * 8;
  for (int kt = 0; kt < 8; ++kt) {
    int k0 = kt << 5;
    {
      int r = tid >> 2, cb = (tid & 3) << 3, o = o0 + r;
      const float* a1p = W2 + (long)o * 256 + k0 + cb;
      f32x4 u0 = *(const f32x4*)a1p, u1 = *(const f32x4*)(a1p + 4);
      A1[r][cb+0]=f2bf(u0.x); A1[r][cb+1]=f2bf(u0.y); A1[r][cb+2]=f2bf(u0.z); A1[r][cb+3]=f2bf(u0.w);
      A1[r][cb+4]=f2bf(u1.x); A1[r][cb+5]=f2bf(u1.y); A1[r][cb+6]=f2bf(u1.z); A1[r][cb+7]=f2bf(u1.w);
      const float* a2p = Mc + ((long)bz * 128 + o) * 256 + k0 + cb;
      f32x4 v0 = *(const f32x4*)a2p, v1 = *(const f32x4*)(a2p + 4);
      float av[8] = {v0.x, v0.y, v0.z, v0.w, v1.x, v1.y, v1.z, v1.w};
      #pragma unroll
      for (int i = 0; i < 8; ++i) {
        u16 hi = f2bf(av[i]);
        A2h[r][cb + i] = hi;
        A2l[r][cb + i] = f2bf(av[i] - bf2f(hi));
      }
    }
    {
      int kl = tid >> 3, nb = (tid & 7) << 3;
      const u16* src = Xb + ((long)bz * 256 + k0 + kl) * N + n0 + nb;
      bf16x8 t = *(const bf16x8*)src;
      #pragma unroll
      for (int i = 0; i < 8; ++i) Xs[nb + i][kl] = (u16)t[i];
    }
    __syncthreads();
    bf16x8 a1 = *(const bf16x8*)&A1[wv * 16 + lr][lk];
    bf16x8 a2h = *(const bf16x8*)&A2h[wv * 16 + lr][lk];
    bf16x8 a2l = *(const bf16x8*)&A2l[wv * 16 + lr][lk];
    #pragma unroll
    for (int nt = 0; nt < 4; ++nt) {
      bf16x8 bfr = *(const bf16x8*)&Xs[nt * 16 + lr][lk];
      acc1[nt] = __builtin_amdgcn_mfma_f32_16x16x32_bf16(a1, bfr, acc1[nt], 0, 0, 0);
      acc2[nt] = __builtin_amdgcn_mfma_f32_16x16x32_bf16(a2h, bfr, acc2[nt], 0, 0, 0);
      acc2[nt] = __builtin_amdgcn_mfma_f32_16x16x32_bf16(a2l, bfr, acc2[nt], 0, 0, 0);
    }
    __syncthreads();
  }
  #pragma unroll
  for (int nt = 0; nt < 4; ++nt) {
    #pragma unroll
    for (int r4 = 0; r4 < 4; ++r4) {
      int o = o0 + wv * 16 + (lane >> 4) * 4 + r4;
      int n = n0 + nt * 16 + (lane & 15);
      long oi = ((long)bz * 128 + o) * N + n;
      float v1 = acc1[nt][r4] + b2[o];
      out1[oi] = v1;
      img2b[oi] = f2bf(v1);
      qin[oi] = f2bf(acc2[nt][r4] + bc[bz * 128 + o]);
    }
  }
}

// ---------------- generic MFMA GEMM: out[b,o,n] = sum_k A[o,k] X[b,k,n] (+bias)(+res) ----------------
template<int AMODE, int BIAS, int RESADD, int OUTF>
__global__ __launch_bounds__(256) void gemm_k(
    const float* __restrict__ Aw, long a_bstride,
    const u16* __restrict__ X, long x_bstride,
    const float* __restrict__ bias, long bias_bstride,
    const u16* __restrict__ res, long res_bstride,
    void* __restrict__ outv, long out_bstride,
    int O, int K) {
  const int N = N_PIX;
  int n0 = blockIdx.x * 64;
  int o0 = blockIdx.y * 64;
  int bz = blockIdx.z;
  int tid = threadIdx.x;
  __shared__ __align__(16) u16 As[64][40];
  __shared__ __align__(16) u16 Al[64][40];
  __shared__ __align__(16) u16 Xs[64][40];
  f32x4 acc[4];
  #pragma unroll
  for (int i = 0; i < 4; ++i) acc[i] = (f32x4){0.f, 0.f, 0.f, 0.f};
  int wv = tid >> 6, lane = tid & 63;
  int lr = lane & 15, lk = (lane >> 4) * 8;
  int nk = (K + 31) >> 5;
  for (int kt = 0; kt < nk; ++kt) {
    int k0 = kt << 5;
    {
      int r = tid >> 2, cb = (tid & 3) << 3;
      int o = o0 + r;
      if (AMODE == 0) {
        if (o < O && (k0 + cb + 8 <= K)) {
          const float* ap = Aw + (long)o * K + k0 + cb;
          f32x4 v0 = *(const f32x4*)ap;
          f32x4 v1 = *(const f32x4*)(ap + 4);
          As[r][cb + 0] = f2bf(v0.x); As[r][cb + 1] = f2bf(v0.y);
          As[r][cb + 2] = f2bf(v0.z); As[r][cb + 3] = f2bf(v0.w);
          As[r][cb + 4] = f2bf(v1.x); As[r][cb + 5] = f2bf(v1.y);
          As[r][cb + 6] = f2bf(v1.z); As[r][cb + 7] = f2bf(v1.w);
        } else {
          #pragma unroll
          for (int i = 0; i < 8; ++i) {
            int k = k0 + cb + i;
            As[r][cb + i] = (o < O && k < K) ? f2bf(Aw[(long)o * K + k]) : (u16)0;
          }
        }
      } else {
        #pragma unroll
        for (int i = 0; i < 8; ++i) {
          int k = k0 + cb + i;
          float av = (o < O && k < K) ? Aw[(long)bz * a_bstride + (long)o * K + k] : 0.f;
          u16 hi = f2bf(av);
          As[r][cb + i] = hi;
          Al[r][cb + i] = f2bf(av - bf2f(hi));
        }
      }
    }
    {
      int kl = tid >> 3, nb = (tid & 7) << 3;
      int k = k0 + kl;
      u16 tmp[8];
      if (k < K) {
        const u16* src = X + (long)bz * x_bstride + (long)k * N;
        bf16x8 t = *(const bf16x8*)(src + n0 + nb);
        #pragma unroll
        for (int i = 0; i < 8; ++i) tmp[i] = (u16)t[i];
      } else {
        #pragma unroll
        for (int i = 0; i < 8; ++i) tmp[i] = 0;
      }
      #pragma unroll
      for (int i = 0; i < 8; ++i) Xs[nb + i][kl] = tmp[i];
    }
    __syncthreads();
    bf16x8 afr = *(const bf16x8*)&As[wv * 16 + lr][lk];
    bf16x8 alr;
    if (AMODE == 1) alr = *(const bf16x8*)&Al[wv * 16 + lr][lk];
    #pragma unroll
    for (int nt = 0; nt < 4; ++nt) {
      bf16x8 bfr = *(const bf16x8*)&Xs[nt * 16 + lr][lk];
      acc[nt] = __builtin_amdgcn_mfma_f32_16x16x32_bf16(afr, bfr, acc[nt], 0, 0, 0);
      if (AMODE == 1)
        acc[nt] = __builtin_amdgcn_mfma_f32_16x16x32_bf16(alr, bfr, acc[nt], 0, 0, 0);
    }
    __syncthreads();
  }
  #pragma unroll
  for (int nt = 0; nt < 4; ++nt) {
    #pragma unroll
    for (int r4 = 0; r4 < 4; ++r4) {
      int o = o0 + wv * 16 + (lane >> 4) * 4 + r4;
      int n = n0 + nt * 16 + (lane & 15);
      if (o < O) {
        float v = acc[nt][r4];
        if (BIAS == 1) v += bias[o];
        if (BIAS == 2) v += bias[(long)bz * bias_bstride + o];
        if (RESADD) v += bf2f(res[(long)bz * res_bstride + (long)o * N + n]);
        long oi = (long)bz * out_bstride + (long)o * N + n;
        if (OUTF) ((float*)outv)[oi] = v;
        else ((u16*)outv)[oi] = f2bf(v);
      }
    }
  }
}

// ---------------- LayerNorm over channel dim (C=128), bf16 in (in-place safe) ----------------
__global__ __launch_bounds__(256) void ln_k(const u16* __restrict__ in,
                                            const float* __restrict__ gamma,
                                            const float* __restrict__ beta,
                                            u16* __restrict__ out) {
  int p0 = blockIdx.x * 64, b = blockIdx.y, tid = threadIdx.x;
  int px = tid & 63, g4 = tid >> 6;
  __shared__ float tile[128][65];
  __shared__ float red[8][64];
  __shared__ float gmm[128], bta[128], mu_s[64], rs_s[64];
  if (tid < 128) { gmm[tid] = gamma[tid]; bta[tid] = beta[tid]; }
  long bofs = (long)b * 128 * N_PIX;
  float s = 0.f;
  for (int c = g4; c < 128; c += 4) {
    float v = bf2f(in[bofs + (long)c * N_PIX + p0 + px]);
    tile[c][px] = v;
    s += v;
  }
  red[g4][px] = s;
  __syncthreads();
  if (g4 == 0) mu_s[px] = (red[0][px] + red[1][px] + red[2][px] + red[3][px]) * (1.f / 128.f);
  __syncthreads();
  float mu = mu_s[px];
  float s2 = 0.f;
  for (int c = g4; c < 128; c += 4) { float d = tile[c][px] - mu; s2 += d * d; }
  red[4 + g4][px] = s2;
  __syncthreads();
  if (g4 == 0) {
    float var = (red[4][px] + red[5][px] + red[6][px] + red[7][px]) * (1.f / 128.f);
    rs_s[px] = rsqrtf(var + 1e-5f);
  }
  __syncthreads();
  float rs = rs_s[px];
  for (int c = g4; c < 128; c += 4)
    out[bofs + (long)c * N_PIX + p0 + px] = f2bf((tile[c][px] - mu) * rs * gmm[c] + bta[c]);
}

// ---------------- depthwise 3x3, SAME, zero pad (bf16 in/out, f32 w) ----------------
__global__ __launch_bounds__(256) void dw3_k(const u16* __restrict__ in,
                                             const float* __restrict__ w,
                                             u16* __restrict__ out,
                                             int C, long total) {
  long idx = (long)blockIdx.x * 256 + threadIdx.x;
  if (idx >= total) return;
  int p = (int)(idx & (N_PIX - 1));
  long rest = idx >> 14;
  int c = (int)(rest % C);
  int y = p >> 7, x = p & 127;
  const u16* ip = in + (idx - p);
  float wv[9];
  #pragma unroll
  for (int j = 0; j < 9; ++j) wv[j] = w[c * 9 + j];
  float s = 0.f;
  #pragma unroll
  for (int ky = -1; ky <= 1; ++ky) {
    int yy = y + ky;
    if (yy < 0 || yy > 127) continue;
    #pragma unroll
    for (int kx = -1; kx <= 1; ++kx) {
      int xx = x + kx;
      if (xx < 0 || xx > 127) continue;
      s += wv[(ky + 1) * 3 + (kx + 1)] * bf2f(ip[yy * 128 + xx]);
    }
  }
  out[idx] = f2bf(s);
}

// ---- fused FFN tail: y1=dw3(t1), y2=dw3(t2), g = gelu(y1)*y2  (340 channels) ----
__global__ __launch_bounds__(256) void dw3gelu_k(const u16* __restrict__ t1,
                                                 const u16* __restrict__ t2,
                                                 const float* __restrict__ w,
                                                 u16* __restrict__ g) {
  long idx = (long)blockIdx.x * 256 + threadIdx.x;
  if (idx >= 340L * N_PIX) return;
  int p = (int)(idx & (N_PIX - 1));
  int c = (int)(idx >> 14);
  int y = p >> 7, x = p & 127;
  const u16* ip1 = t1 + (idx - p);
  const u16* ip2 = t2 + (idx - p);
  float w1[9], w2[9];
  #pragma unroll
  for (int j = 0; j < 9; ++j) { w1[j] = w[c * 9 + j]; w2[j] = w[(340 + c) * 9 + j]; }
  float s1 = 0.f, s2 = 0.f;
  #pragma unroll
  for (int ky = -1; ky <= 1; ++ky) {
    int yy = y + ky;
    if (yy < 0 || yy > 127) continue;
    #pragma unroll
    for (int kx = -1; kx <= 1; ++kx) {
      int xx = x + kx;
      if (xx < 0 || xx > 127) continue;
      int j = (ky + 1) * 3 + (kx + 1);
      float v1 = bf2f(ip1[yy * 128 + xx]);
      float v2 = bf2f(ip2[yy * 128 + xx]);
      s1 += w1[j] * v1;
      s2 += w2[j] * v2;
    }
  }
  float gl = 0.5f * s1 * (1.f + erff(s1 * 0.70710678118f));
  g[idx] = f2bf(gl * s2);
}

// ---------------- row L2 norms (bf16 in) ----------------
__global__ __launch_bounds__(256) void rownorm_k(const u16* __restrict__ base, long bstride,
                                                 float* __restrict__ out) {
  int r = blockIdx.x, b = blockIdx.y, tid = threadIdx.x;
  const u16* src = base + (long)b * bstride + (long)r * N_PIX;
  float s = 0.f;
  #pragma unroll
  for (int j = 0; j < 8; ++j) {
    bf16x8 v = *(const bf16x8*)(src + j * 2048 + tid * 8);
    #pragma unroll
    for (int i = 0; i < 8; ++i) { float f = bf2f((u16)v[i]); s += f * f; }
  }
  float t = blockReduceSum256(s);
  if (tid == 0) out[b * 128 + r] = sqrtf(t);
}

// ---- attn partials: per 256-pixel chunk, 16x16 Gram of (Q,K) per (b,h) ----
__global__ __launch_bounds__(256) void attn_part_k(const u16* __restrict__ q,
                                                   const u16* __restrict__ kbase,
                                                   float* __restrict__ part) {
  int ch = blockIdx.x, h = blockIdx.y, b = blockIdx.z, tid = threadIdx.x;
  int n0 = ch * 256;
  __shared__ __align__(16) u16 qc[16][280];
  __shared__ __align__(16) u16 kc[16][280];
  #pragma unroll
  for (int j = 0; j < 2; ++j) {
    int v = tid + j * 256;
    int r = v >> 5, col = (v & 31) << 3;
    long go = ((long)b * 128 + h * 16 + r) * N_PIX + n0 + col;
    *(bf16x8*)&qc[r][col] = *(const bf16x8*)(q + go);
    *(bf16x8*)&kc[r][col] = *(const bf16x8*)(kbase + go);
  }
  __syncthreads();
  int c = tid >> 4, d = tid & 15;
  float acc = 0.f;
  #pragma unroll 4
  for (int nb = 0; nb < 32; ++nb) {
    bf16x8 qv = *(const bf16x8*)&qc[c][nb * 8];
    bf16x8 kv = *(const bf16x8*)&kc[d][nb * 8];
    #pragma unroll
    for (int i = 0; i < 8; ++i) acc += bf2f((u16)qv[i]) * bf2f((u16)kv[i]);
  }
  part[(long)((((b * 8 + h) * 16 + c) * 16 + d)) * 64 + ch] = acc;
}

// ---- reduce partials + cosine scaling -> attnm [4,8,16,16] ----
__global__ __launch_bounds__(256) void attn_reduce_k(const float* __restrict__ part,
                                                     const float* __restrict__ qn,
                                                     const float* __restrict__ kn,
                                                     const float* __restrict__ temp,
                                                     float* __restrict__ attnm) {
  int idx = blockIdx.x * 256 + threadIdx.x;   // 8192 entries
  const float* p = part + (long)idx * 64;
  float s = 0.f;
  #pragma unroll
  for (int j = 0; j < 64; ++j) s += p[j];
  int d = idx & 15, c = (idx >> 4) & 15, h = (idx >> 8) & 7, b = idx >> 11;
  float nq = fmaxf(qn[b * 128 + h * 16 + c], 1e-12f);
  float nk = fmaxf(kn[b * 128 + h * 16 + d], 1e-12f);
  attnm[idx] = s / (nq * nk) * temp[h];
}

// ---------------- top14 threshold + softmax + fold proj into Cmb[b,128,128] ----------------
__global__ __launch_bounds__(128) void score_cmb_k(const float* __restrict__ attnm,
                                                   const float* __restrict__ projw,
                                                   const float* __restrict__ attn4p,
                                                   float* __restrict__ cmb) {
  int b = blockIdx.x, tid = threadIdx.x;
  __shared__ float att_s[2048], score_s[2048];
  for (int i = tid; i < 2048; i += 128) att_s[i] = attnm[(long)b * 2048 + i];
  __syncthreads();
  {
    int h = tid >> 4, c = tid & 15;
    float v[16], t[16];
    #pragma unroll
    for (int d = 0; d < 16; ++d) { v[d] = att_s[(h * 16 + c) * 16 + d]; t[d] = v[d]; }
    float thr = 0.f, M = -1e30f;
    for (int it = 0; it < 14; ++it) {
      float m = -1e30f; int mi = 0;
      #pragma unroll
      for (int d = 0; d < 16; ++d) if (t[d] > m) { m = t[d]; mi = d; }
      if (it == 0) M = m;
      thr = m;
      t[mi] = -1e31f;
    }
    float s = 0.f, e[16];
    #pragma unroll
    for (int d = 0; d < 16; ++d) { e[d] = (v[d] >= thr) ? expf(v[d] - M) : 0.f; s += e[d]; }
    float inv = 1.f / s;
    #pragma unroll
    for (int d = 0; d < 16; ++d) score_s[(h * 16 + c) * 16 + d] = e[d] * inv;
  }
  __syncthreads();
  float a4 = attn4p[0];
  int o = tid;
  for (int hd = 0; hd < 128; ++hd) {
    int h = hd >> 4, d = hd & 15;
    float s = 0.f;
    #pragma unroll
    for (int c = 0; c < 16; ++c)
      s += projw[o * 128 + h * 16 + c] * score_s[(h * 16 + c) * 16 + d];
    cmb[((long)b * 128 + o) * 128 + hd] = a4 * s;
  }
}

extern "C" void kernel_launch(void* const* d_in, const int* in_sizes, int n_in,
                              void* d_out, int out_size, void* d_ws, size_t ws_size,
                              hipStream_t stream) {
  (void)in_sizes; (void)n_in; (void)out_size; (void)ws_size;
  const float* vi        = (const float*)d_in[0];
  const float* ir        = (const float*)d_in[1];
  const float* text_code = (const float*)d_in[2];
  const float* se_w1     = (const float*)d_in[3];
  const float* se_w2     = (const float*)d_in[4];
  const float* conv1x1_w = (const float*)d_in[5];
  const float* conv1x1_b = (const float*)d_in[6];
  const float* conv_out_w= (const float*)d_in[7];
  const float* conv_out_b= (const float*)d_in[8];
  const float* text_w1   = (const float*)d_in[9];
  const float* text_b1   = (const float*)d_in[10];
  const float* text_w2   = (const float*)d_in[11];
  const float* text_b2   = (const float*)d_in[12];
  const float* norm1_w   = (const float*)d_in[13];
  const float* norm1_b   = (const float*)d_in[14];
  const float* norm2_w   = (const float*)d_in[15];
  const float* norm2_b   = (const float*)d_in[16];
  const float* norm3_w   = (const float*)d_in[17];
  const float* norm3_b   = (const float*)d_in[18];
  const float* q_w       = (const float*)d_in[19];
  const float* q_dw_w    = (const float*)d_in[20];
  const float* kv_w      = (const float*)d_in[21];
  const float* kv_dw_w   = (const float*)d_in[22];
  const float* temperature = (const float*)d_in[23];
  const float* attn4     = (const float*)d_in[24];
  const float* proj_w    = (const float*)d_in[25];
  const float* ffn_in_w  = (const float*)d_in[26];
  const float* ffn_dw_w  = (const float*)d_in[27];
  const float* ffn_out_w = (const float*)d_in[28];
  float* out0 = (float*)d_out;       // output 0 [4,128,128,128] f32
  float* out1 = out0 + NP;           // output 1 (img_feature2) f32

  // ---- workspace: 1 MiB small pool + bf16 arena of 2048*N_PIX elems (64 MiB) ----
  char* W = (char*)d_ws;
  float* sq_f  = (float*)(W + 0);        // 4KB
  int*   idx_i = (int*)(W + 4096);       // 2KB
  int*   sidx_i= (int*)(W + 6144);       // 4KB
  float* mcomb = (float*)(W + 12288);    // 512KB
  float* bcomb = (float*)(W + 536576);   // 2KB
  float* qn_f  = (float*)(W + 538624);   // 2KB
  float* kn_f  = (float*)(W + 540672);   // 2KB
  float* attnm = (float*)(W + 542720);   // 32KB
  float* cmb   = (float*)(W + 575488);   // 256KB
  u16* S   = (u16*)(W + (1 << 20));      // arena, N_PIX-elem units
  u16* CC  = S;                          // [0,512N)
  u16* KD  = S + 512L * N_PIX;           // [512N,1024N)
  u16* VD  = S + 1024L * N_PIX;          // [1024N,1536N)
  u16* TMP = S + 1536L * N_PIX;          // [1536N,2048N)
  u16* CBF = S + 1024L * N_PIX;          // bf16 concat [4,256,N] = [1024N,2048N)
  u16* FT1 = S;                          // FFN t1 [0,340N)
  u16* FT2 = S + 340L * N_PIX;           // FFN t2 [340N,680N)
  u16* FG  = S + 680L * N_PIX;           // FFN g  [680N,1020N)

  const long SN = 128L * N_PIX;

  // control path (+ bf16 concat emit)
  squeeze_k<<<dim3(256, 4), 256, 0, stream>>>(vi, ir, sq_f, CBF);
  control_k<<<4, 256, 0, stream>>>(text_code, se_w1, se_w2, text_w1, text_b1,
                                   text_w2, text_b2, sq_f, idx_i, sidx_i);
  mcomb_k<<<dim3(128, 4), 128, 0, stream>>>(conv_out_w, conv_out_b, conv1x1_w,
                                            conv1x1_b, idx_i, sidx_i, mcomb, bcomb);
  // fused: img_feature2 (f32 + bf16 copy) and q_in
  gemm_dual_k<<<dim3(256, 2, 4), 256, 0, stream>>>(
      conv_out_w, conv_out_b, mcomb, bcomb, CBF, out1, KD, CC);
  // LayerNorms (in-place)
  ln_k<<<dim3(256, 4), 256, 0, stream>>>(CC, norm1_w, norm1_b, CC);          // xq
  ln_k<<<dim3(256, 4), 256, 0, stream>>>(KD, norm2_w, norm2_b, KD);          // xkv
  // Q path: qt -> TMP, qd -> CC
  gemm_k<0, 0, 0, 0><<<dim3(256, 2, 4), 256, 0, stream>>>(
      q_w, 0, CC, SN, nullptr, 0, nullptr, 0, TMP, SN, 128, 128);
  dw3_k<<<32768, 256, 0, stream>>>(TMP, q_dw_w, CC, 128, NP);                // Q=CC
  // KV path: K -> VD, V -> KD
  gemm_k<0, 0, 0, 0><<<dim3(256, 2, 4), 256, 0, stream>>>(
      kv_w, 0, KD, SN, nullptr, 0, nullptr, 0, TMP, SN, 128, 128);
  dw3_k<<<32768, 256, 0, stream>>>(TMP, kv_dw_w, VD, 128, NP);               // K=VD
  gemm_k<0, 0, 0, 0><<<dim3(256, 2, 4), 256, 0, stream>>>(
      kv_w + 128 * 128, 0, KD, SN, nullptr, 0, nullptr, 0, TMP, SN, 128, 128);
  dw3_k<<<32768, 256, 0, stream>>>(TMP, kv_dw_w + 128 * 9, KD, 128, NP);     // V=KD
  // attention logits
  rownorm_k<<<dim3(128, 4), 256, 0, stream>>>(CC, SN, qn_f);
  rownorm_k<<<dim3(128, 4), 256, 0, stream>>>(VD, SN, kn_f);
  float* part = (float*)TMP;
  attn_part_k<<<dim3(64, 8, 4), 256, 0, stream>>>(CC, VD, part);
  attn_reduce_k<<<32, 256, 0, stream>>>(part, qn_f, kn_f, temperature, attnm);
  score_cmb_k<<<4, 128, 0, stream>>>(attnm, proj_w, attn4, cmb);
  // att = Cmb_b @ V -> TMP
  gemm_k<1, 0, 0, 0><<<dim3(256, 2, 4), 256, 0, stream>>>(
      cmb, 128L * 128, KD, SN, nullptr, 0, nullptr, 0, TMP, SN, 128, 128);   // ATT=TMP
  ln_k<<<dim3(256, 4), 256, 0, stream>>>(TMP, norm3_w, norm3_b, VD);         // x3=VD
  // FFN per batch
  for (int b = 0; b < 4; ++b) {
    const u16* x3b = VD + (long)b * SN;
    gemm_k<0, 0, 0, 0><<<dim3(256, 6, 1), 256, 0, stream>>>(
        ffn_in_w, 0, x3b, 0, nullptr, 0, nullptr, 0, FT1, 0, 340, 128);
    gemm_k<0, 0, 0, 0><<<dim3(256, 6, 1), 256, 0, stream>>>(
        ffn_in_w + 340 * 128, 0, x3b, 0, nullptr, 0, nullptr, 0, FT2, 0, 340, 128);
    dw3gelu_k<<<21760, 256, 0, stream>>>(FT1, FT2, ffn_dw_w, FG);
    gemm_k<0, 0, 1, 1><<<dim3(256, 2, 1), 256, 0, stream>>>(
        ffn_out_w, 0, FG, 0, nullptr, 0, TMP + (long)b * SN, 0,
        out0 + (long)b * SN, 0, 128, 340);
  }
}

// Round 6
// 780.560 us; speedup vs baseline: 1.6969x; 1.0580x over previous
//
#include <hip/hip_runtime.h>

typedef unsigned short u16;
typedef __attribute__((ext_vector_type(8))) short bf16x8;
typedef __attribute__((ext_vector_type(4))) float f32x4;

#define N_PIX 16384
static constexpr long NP = 4L * 128 * N_PIX;   // elems in one [4,128,128,128]

__device__ __forceinline__ float bf2f(u16 h) {
  unsigned u = ((unsigned)h) << 16; float f; __builtin_memcpy(&f, &u, 4); return f;
}
__device__ __forceinline__ u16 f2bf(float f) {
  unsigned u; __builtin_memcpy(&u, &f, 4);
  u = (u + 0x7fffu + ((u >> 16) & 1u)) >> 16; return (u16)u;
}

__device__ __forceinline__ float blockReduceSum256(float v) {
  #pragma unroll
  for (int o = 32; o > 0; o >>= 1) v += __shfl_down(v, o, 64);
  __shared__ float sw[4];
  int lane = threadIdx.x & 63, w = threadIdx.x >> 6;
  if (lane == 0) sw[w] = v;
  __syncthreads();
  return (threadIdx.x == 0) ? (sw[0] + sw[1] + sw[2] + sw[3]) : 0.f;
}

// ---- squeeze: mean over HW of concat (f32 in) -> [4,256] f32 ; also emit bf16 concat ----
__global__ __launch_bounds__(256) void squeeze_k(const float* __restrict__ vi,
                                                 const float* __restrict__ ir,
                                                 float* __restrict__ sq,
                                                 u16* __restrict__ cbf) {
  int c = blockIdx.x, b = blockIdx.y, tid = threadIdx.x;
  const float* src = (c < 128) ? (vi + ((long)b * 128 + c) * N_PIX)
                               : (ir + ((long)b * 128 + (c - 128)) * N_PIX);
  const f32x4* src4 = (const f32x4*)src;
  u16* dst = cbf + ((long)b * 256 + c) * N_PIX;
  float s = 0.f;
  #pragma unroll
  for (int j = 0; j < 8; ++j) {
    f32x4 v0 = src4[j * 512 + tid * 2];
    f32x4 v1 = src4[j * 512 + tid * 2 + 1];
    s += v0.x + v0.y + v0.z + v0.w + v1.x + v1.y + v1.z + v1.w;
    bf16x8 r;
    r[0] = (short)f2bf(v0.x); r[1] = (short)f2bf(v0.y);
    r[2] = (short)f2bf(v0.z); r[3] = (short)f2bf(v0.w);
    r[4] = (short)f2bf(v1.x); r[5] = (short)f2bf(v1.y);
    r[6] = (short)f2bf(v1.z); r[7] = (short)f2bf(v1.w);
    *(bf16x8*)(dst + j * 2048 + tid * 8) = r;
  }
  float t = blockReduceSum256(s);
  if (tid == 0) sq[b * 256 + c] = t * (1.f / 16384.f);
}

// ---- SE MLP + top128 rank (tiny) ----
__global__ __launch_bounds__(256) void se_rank_k(const float* __restrict__ sq,
                                                 const float* __restrict__ sew1,
                                                 const float* __restrict__ sew2,
                                                 int* __restrict__ idx) {
  int b = blockIdx.x, tid = threadIdx.x;
  __shared__ float s_sq[256], s_h1[32], s_cw[256];
  s_sq[tid] = sq[b * 256 + tid];
  __syncthreads();
  if (tid < 32) {
    float s = 0.f;
    for (int c = 0; c < 256; ++c) s += s_sq[c] * sew1[tid * 256 + c];
    s_h1[tid] = fmaxf(s, 0.f);
  }
  __syncthreads();
  {
    float s = 0.f;
    #pragma unroll
    for (int j = 0; j < 32; ++j) s += s_h1[j] * sew2[tid * 32 + j];
    s_cw[tid] = 1.f / (1.f + expf(-s));
  }
  __syncthreads();
  float my = s_cw[tid];
  int rk = 0;
  for (int c = 0; c < 256; ++c) {
    float o = s_cw[c];
    rk += (o > my) || (o == my && c < tid);
  }
  if (rk < 128) idx[b * 128 + rk] = tid;
}

// ---- text MLP layer1: t1 = relu(tc @ tw1^T + tb1), wave-parallel dots ----
__global__ __launch_bounds__(256) void text1_k(const float* __restrict__ tc,
                                               const float* __restrict__ tw1,
                                               const float* __restrict__ tb1,
                                               float* __restrict__ t1f) {
  int b = blockIdx.y, j0 = blockIdx.x * 8, tid = threadIdx.x;
  __shared__ float s_tc[512];
  s_tc[tid] = tc[b * 512 + tid];
  s_tc[tid + 256] = tc[b * 512 + 256 + tid];
  __syncthreads();
  int w = tid >> 6, lane = tid & 63;
  #pragma unroll
  for (int r = 0; r < 2; ++r) {
    int j = j0 + w * 2 + r;
    const float* wr = tw1 + (long)j * 512;
    float s = 0.f;
    #pragma unroll
    for (int k = 0; k < 8; ++k) s += s_tc[lane + k * 64] * wr[lane + k * 64];
    #pragma unroll
    for (int o = 32; o > 0; o >>= 1) s += __shfl_down(s, o, 64);
    if (lane == 0) t1f[b * 512 + j] = fmaxf(s + tb1[j], 0.f);
  }
}

// ---- text MLP layer2: tf = t1 @ tw2^T + tb2 ----
__global__ __launch_bounds__(256) void text2_k(const float* __restrict__ t1f,
                                               const float* __restrict__ tw2,
                                               const float* __restrict__ tb2,
                                               float* __restrict__ tf) {
  int b = blockIdx.y, j0 = blockIdx.x * 8, tid = threadIdx.x;
  __shared__ float s_t1[512];
  s_t1[tid] = t1f[b * 512 + tid];
  s_t1[tid + 256] = t1f[b * 512 + 256 + tid];
  __syncthreads();
  int w = tid >> 6, lane = tid & 63;
  #pragma unroll
  for (int r = 0; r < 2; ++r) {
    int j = j0 + w * 2 + r;
    const float* wr = tw2 + (long)j * 512;
    float s = 0.f;
    #pragma unroll
    for (int k = 0; k < 8; ++k) s += s_t1[lane + k * 64] * wr[lane + k * 64];
    #pragma unroll
    for (int o = 32; o > 0; o >>= 1) s += __shfl_down(s, o, 64);
    if (lane == 0) tf[b * 256 + j] = s + tb2[j];
  }
}

// ---- argsort-rank of tf -> sidx ----
__global__ __launch_bounds__(256) void rank2_k(const float* __restrict__ tf,
                                               int* __restrict__ sidx) {
  int b = blockIdx.x, tid = threadIdx.x;
  __shared__ float s_tf[256];
  s_tf[tid] = tf[b * 256 + tid];
  __syncthreads();
  float my = s_tf[tid];
  int rk = 0;
  for (int c = 0; c < 256; ++c) {
    float o = s_tf[c];
    rk += (o > my) || (o == my && c < tid);
  }
  sidx[b * 256 + rk] = tid;
}

// ---------------- fold conv1x1 + shuffle + conv_out + select into M_b[128,256] ----------------
__global__ __launch_bounds__(128) void mcomb_k(const float* __restrict__ w2,
                                               const float* __restrict__ w2b,
                                               const float* __restrict__ w1,
                                               const float* __restrict__ w1b,
                                               const int* __restrict__ idx,
                                               const int* __restrict__ sidx,
                                               float* __restrict__ mcomb,
                                               float* __restrict__ bcomb) {
  int o = blockIdx.x, b = blockIdx.y, tid = threadIdx.x;
  __shared__ float s_w2[256];
  __shared__ int s_sx[256];
  s_w2[tid] = w2[o * 256 + tid];
  s_w2[tid + 128] = w2[o * 256 + tid + 128];
  s_sx[tid] = sidx[b * 256 + tid] & 255;
  s_sx[tid + 128] = sidx[b * 256 + tid + 128] & 255;
  float* mrow = mcomb + ((long)b * 128 + o) * 256;
  mrow[tid] = 0.f;
  mrow[tid + 128] = 0.f;
  __syncthreads();
  float s = 0.f;
  for (int j = 0; j < 256; ++j) s += s_w2[j] * w1[s_sx[j] * 128 + tid];
  int cc = idx[b * 128 + tid] & 255;
  mrow[cc] = s;
  if (tid == 0) {
    float bb = w2b[o];
    for (int j = 0; j < 256; ++j) bb += s_w2[j] * w1b[s_sx[j]];
    bcomb[b * 128 + o] = bb;
  }
}

// ---- fused dual GEMM (128-row o-tile): out1/img2b = W2@X + b2 ; qin = M_b@X + bc ----
__global__ __launch_bounds__(256) void gemm_dual_k(
    const float* __restrict__ W2, const float* __restrict__ b2,
    const float* __restrict__ Mc, const float* __restrict__ bc,
    const u16* __restrict__ Xb,
    float* __restrict__ out1, u16* __restrict__ img2b, u16* __restrict__ qin) {
  const int N = N_PIX;
  int n0 = blockIdx.x * 64, bz = blockIdx.y, tid = threadIdx.x;
  __shared__ __align__(16) u16 A1[128][40];
  __shared__ __align__(16) u16 A2h[128][40];
  __shared__ __align__(16) u16 A2l[128][40];
  __shared__ __align__(16) u16 Xs[64][40];
  f32x4 acc1[2][4], acc2[2][4];
  #pragma unroll
  for (int ot = 0; ot < 2; ++ot)
    #pragma unroll
    for (int i = 0; i < 4; ++i) { acc1[ot][i] = (f32x4){0,0,0,0}; acc2[ot][i] = (f32x4){0,0,0,0}; }
  int wv = tid >> 6, lane = tid & 63;
  int lr = lane & 15, lk = (lane >> 4) * 8;
  for (int kt = 0; kt < 8; ++kt) {
    int k0 = kt << 5;
    #pragma unroll
    for (int ot = 0; ot < 2; ++ot) {
      int r = (tid >> 2) + ot * 64, cb = (tid & 3) << 3;
      const float* a1p = W2 + (long)r * 256 + k0 + cb;
      f32x4 u0 = *(const f32x4*)a1p, u1 = *(const f32x4*)(a1p + 4);
      A1[r][cb+0]=f2bf(u0.x); A1[r][cb+1]=f2bf(u0.y); A1[r][cb+2]=f2bf(u0.z); A1[r][cb+3]=f2bf(u0.w);
      A1[r][cb+4]=f2bf(u1.x); A1[r][cb+5]=f2bf(u1.y); A1[r][cb+6]=f2bf(u1.z); A1[r][cb+7]=f2bf(u1.w);
      const float* a2p = Mc + ((long)bz * 128 + r) * 256 + k0 + cb;
      f32x4 v0 = *(const f32x4*)a2p, v1 = *(const f32x4*)(a2p + 4);
      float av[8] = {v0.x, v0.y, v0.z, v0.w, v1.x, v1.y, v1.z, v1.w};
      #pragma unroll
      for (int i = 0; i < 8; ++i) {
        u16 hi = f2bf(av[i]);
        A2h[r][cb + i] = hi;
        A2l[r][cb + i] = f2bf(av[i] - bf2f(hi));
      }
    }
    {
      int kl = tid >> 3, nb = (tid & 7) << 3;
      const u16* src = Xb + ((long)bz * 256 + k0 + kl) * N + n0 + nb;
      bf16x8 t = *(const bf16x8*)src;
      #pragma unroll
      for (int i = 0; i < 8; ++i) Xs[nb + i][kl] = (u16)t[i];
    }
    __syncthreads();
    bf16x8 bfr[4];
    #pragma unroll
    for (int nt = 0; nt < 4; ++nt) bfr[nt] = *(const bf16x8*)&Xs[nt * 16 + lr][lk];
    #pragma unroll
    for (int ot = 0; ot < 2; ++ot) {
      bf16x8 a1 = *(const bf16x8*)&A1[ot * 64 + wv * 16 + lr][lk];
      bf16x8 a2h = *(const bf16x8*)&A2h[ot * 64 + wv * 16 + lr][lk];
      bf16x8 a2l = *(const bf16x8*)&A2l[ot * 64 + wv * 16 + lr][lk];
      #pragma unroll
      for (int nt = 0; nt < 4; ++nt) {
        acc1[ot][nt] = __builtin_amdgcn_mfma_f32_16x16x32_bf16(a1, bfr[nt], acc1[ot][nt], 0, 0, 0);
        acc2[ot][nt] = __builtin_amdgcn_mfma_f32_16x16x32_bf16(a2h, bfr[nt], acc2[ot][nt], 0, 0, 0);
        acc2[ot][nt] = __builtin_amdgcn_mfma_f32_16x16x32_bf16(a2l, bfr[nt], acc2[ot][nt], 0, 0, 0);
      }
    }
    __syncthreads();
  }
  #pragma unroll
  for (int ot = 0; ot < 2; ++ot)
    #pragma unroll
    for (int nt = 0; nt < 4; ++nt)
      #pragma unroll
      for (int r4 = 0; r4 < 4; ++r4) {
        int o = ot * 64 + wv * 16 + (lane >> 4) * 4 + r4;
        int n = n0 + nt * 16 + (lane & 15);
        long oi = ((long)bz * 128 + o) * N + n;
        float v1 = acc1[ot][nt][r4] + b2[o];
        out1[oi] = v1;
        img2b[oi] = f2bf(v1);
        qin[oi] = f2bf(acc2[ot][nt][r4] + bc[bz * 128 + o]);
      }
}

// ---------------- generic MFMA GEMM, OT o-tiles of 64 rows per block ----------------
template<int AMODE, int BIAS, int RESADD, int OUTF, int OT>
__global__ __launch_bounds__(256) void gemm_k(
    const float* __restrict__ Aw, long a_bstride,
    const u16* __restrict__ X, long x_bstride,
    const float* __restrict__ bias, long bias_bstride,
    const u16* __restrict__ res, long res_bstride,
    void* __restrict__ outv, long out_bstride,
    int O, int K) {
  const int N = N_PIX;
  int n0 = blockIdx.x * 64;
  int o0 = blockIdx.y * 64 * OT;
  int bz = blockIdx.z;
  int tid = threadIdx.x;
  __shared__ __align__(16) u16 As[64 * OT][40];
  __shared__ __align__(16) u16 Al[AMODE ? 64 * OT : 1][40];
  __shared__ __align__(16) u16 Xs[64][40];
  f32x4 acc[OT][4];
  #pragma unroll
  for (int ot = 0; ot < OT; ++ot)
    #pragma unroll
    for (int i = 0; i < 4; ++i) acc[ot][i] = (f32x4){0.f, 0.f, 0.f, 0.f};
  int wv = tid >> 6, lane = tid & 63;
  int lr = lane & 15, lk = (lane >> 4) * 8;
  int nk = (K + 31) >> 5;
  for (int kt = 0; kt < nk; ++kt) {
    int k0 = kt << 5;
    #pragma unroll
    for (int ot = 0; ot < OT; ++ot) {
      int r = (tid >> 2) + ot * 64, cb = (tid & 3) << 3;
      int o = o0 + r;
      if (AMODE == 0) {
        if (o < O && (k0 + cb + 8 <= K)) {
          const float* ap = Aw + (long)o * K + k0 + cb;
          f32x4 v0 = *(const f32x4*)ap;
          f32x4 v1 = *(const f32x4*)(ap + 4);
          As[r][cb + 0] = f2bf(v0.x); As[r][cb + 1] = f2bf(v0.y);
          As[r][cb + 2] = f2bf(v0.z); As[r][cb + 3] = f2bf(v0.w);
          As[r][cb + 4] = f2bf(v1.x); As[r][cb + 5] = f2bf(v1.y);
          As[r][cb + 6] = f2bf(v1.z); As[r][cb + 7] = f2bf(v1.w);
        } else {
          #pragma unroll
          for (int i = 0; i < 8; ++i) {
            int k = k0 + cb + i;
            As[r][cb + i] = (o < O && k < K) ? f2bf(Aw[(long)o * K + k]) : (u16)0;
          }
        }
      } else {
        #pragma unroll
        for (int i = 0; i < 8; ++i) {
          int k = k0 + cb + i;
          float av = (o < O && k < K) ? Aw[(long)bz * a_bstride + (long)o * K + k] : 0.f;
          u16 hi = f2bf(av);
          As[r][cb + i] = hi;
          Al[r][cb + i] = f2bf(av - bf2f(hi));
        }
      }
    }
    {
      int kl = tid >> 3, nb = (tid & 7) << 3;
      int k = k0 + kl;
      u16 tmp[8];
      if (k < K) {
        const u16* src = X + (long)bz * x_bstride + (long)k * N;
        bf16x8 t = *(const bf16x8*)(src + n0 + nb);
        #pragma unroll
        for (int i = 0; i < 8; ++i) tmp[i] = (u16)t[i];
      } else {
        #pragma unroll
        for (int i = 0; i < 8; ++i) tmp[i] = 0;
      }
      #pragma unroll
      for (int i = 0; i < 8; ++i) Xs[nb + i][kl] = tmp[i];
    }
    __syncthreads();
    bf16x8 bfr[4];
    #pragma unroll
    for (int nt = 0; nt < 4; ++nt) bfr[nt] = *(const bf16x8*)&Xs[nt * 16 + lr][lk];
    #pragma unroll
    for (int ot = 0; ot < OT; ++ot) {
      bf16x8 afr = *(const bf16x8*)&As[ot * 64 + wv * 16 + lr][lk];
      bf16x8 alr;
      if (AMODE == 1) alr = *(const bf16x8*)&Al[ot * 64 + wv * 16 + lr][lk];
      #pragma unroll
      for (int nt = 0; nt < 4; ++nt) {
        acc[ot][nt] = __builtin_amdgcn_mfma_f32_16x16x32_bf16(afr, bfr[nt], acc[ot][nt], 0, 0, 0);
        if (AMODE == 1)
          acc[ot][nt] = __builtin_amdgcn_mfma_f32_16x16x32_bf16(alr, bfr[nt], acc[ot][nt], 0, 0, 0);
      }
    }
    __syncthreads();
  }
  #pragma unroll
  for (int ot = 0; ot < OT; ++ot)
    #pragma unroll
    for (int nt = 0; nt < 4; ++nt)
      #pragma unroll
      for (int r4 = 0; r4 < 4; ++r4) {
        int o = o0 + ot * 64 + wv * 16 + (lane >> 4) * 4 + r4;
        int n = n0 + nt * 16 + (lane & 15);
        if (o < O) {
          float v = acc[ot][nt][r4];
          if (BIAS == 1) v += bias[o];
          if (BIAS == 2) v += bias[(long)bz * bias_bstride + o];
          if (RESADD) v += bf2f(res[(long)bz * res_bstride + (long)o * N + n]);
          long oi = (long)bz * out_bstride + (long)o * N + n;
          if (OUTF) ((float*)outv)[oi] = v;
          else ((u16*)outv)[oi] = f2bf(v);
        }
      }
}

// ---------------- LayerNorm over channel dim (C=128), bf16 in (in-place safe) ----------------
__global__ __launch_bounds__(256) void ln_k(const u16* __restrict__ in,
                                            const float* __restrict__ gamma,
                                            const float* __restrict__ beta,
                                            u16* __restrict__ out) {
  int p0 = blockIdx.x * 64, b = blockIdx.y, tid = threadIdx.x;
  int px = tid & 63, g4 = tid >> 6;
  __shared__ float tile[128][65];
  __shared__ float red[8][64];
  __shared__ float gmm[128], bta[128], mu_s[64], rs_s[64];
  if (tid < 128) { gmm[tid] = gamma[tid]; bta[tid] = beta[tid]; }
  long bofs = (long)b * 128 * N_PIX;
  float s = 0.f;
  for (int c = g4; c < 128; c += 4) {
    float v = bf2f(in[bofs + (long)c * N_PIX + p0 + px]);
    tile[c][px] = v;
    s += v;
  }
  red[g4][px] = s;
  __syncthreads();
  if (g4 == 0) mu_s[px] = (red[0][px] + red[1][px] + red[2][px] + red[3][px]) * (1.f / 128.f);
  __syncthreads();
  float mu = mu_s[px];
  float s2 = 0.f;
  for (int c = g4; c < 128; c += 4) { float d = tile[c][px] - mu; s2 += d * d; }
  red[4 + g4][px] = s2;
  __syncthreads();
  if (g4 == 0) {
    float var = (red[4][px] + red[5][px] + red[6][px] + red[7][px]) * (1.f / 128.f);
    rs_s[px] = rsqrtf(var + 1e-5f);
  }
  __syncthreads();
  float rs = rs_s[px];
  for (int c = g4; c < 128; c += 4)
    out[bofs + (long)c * N_PIX + p0 + px] = f2bf((tile[c][px] - mu) * rs * gmm[c] + bta[c]);
}

// ---------------- depthwise 3x3, SAME, zero pad (bf16 in/out, f32 w) ----------------
__global__ __launch_bounds__(256) void dw3_k(const u16* __restrict__ in,
                                             const float* __restrict__ w,
                                             u16* __restrict__ out,
                                             int C, long total) {
  long idx = (long)blockIdx.x * 256 + threadIdx.x;
  if (idx >= total) return;
  int p = (int)(idx & (N_PIX - 1));
  long rest = idx >> 14;
  int c = (int)(rest % C);
  int y = p >> 7, x = p & 127;
  const u16* ip = in + (idx - p);
  float wv[9];
  #pragma unroll
  for (int j = 0; j < 9; ++j) wv[j] = w[c * 9 + j];
  float s = 0.f;
  #pragma unroll
  for (int ky = -1; ky <= 1; ++ky) {
    int yy = y + ky;
    if (yy < 0 || yy > 127) continue;
    #pragma unroll
    for (int kx = -1; kx <= 1; ++kx) {
      int xx = x + kx;
      if (xx < 0 || xx > 127) continue;
      s += wv[(ky + 1) * 3 + (kx + 1)] * bf2f(ip[yy * 128 + xx]);
    }
  }
  out[idx] = f2bf(s);
}

// ---- fused FFN tail: g = gelu(dw3(t1)) * dw3(t2) ----
__global__ __launch_bounds__(256) void dw3gelu_k(const u16* __restrict__ t1,
                                                 const u16* __restrict__ t2,
                                                 const float* __restrict__ w,
                                                 u16* __restrict__ g) {
  long idx = (long)blockIdx.x * 256 + threadIdx.x;
  if (idx >= 340L * N_PIX) return;
  int p = (int)(idx & (N_PIX - 1));
  int c = (int)(idx >> 14);
  int y = p >> 7, x = p & 127;
  const u16* ip1 = t1 + (idx - p);
  const u16* ip2 = t2 + (idx - p);
  float w1[9], w2[9];
  #pragma unroll
  for (int j = 0; j < 9; ++j) { w1[j] = w[c * 9 + j]; w2[j] = w[(340 + c) * 9 + j]; }
  float s1 = 0.f, s2 = 0.f;
  #pragma unroll
  for (int ky = -1; ky <= 1; ++ky) {
    int yy = y + ky;
    if (yy < 0 || yy > 127) continue;
    #pragma unroll
    for (int kx = -1; kx <= 1; ++kx) {
      int xx = x + kx;
      if (xx < 0 || xx > 127) continue;
      int j = (ky + 1) * 3 + (kx + 1);
      s1 += w1[j] * bf2f(ip1[yy * 128 + xx]);
      s2 += w2[j] * bf2f(ip2[yy * 128 + xx]);
    }
  }
  float gl = 0.5f * s1 * (1.f + erff(s1 * 0.70710678118f));
  g[idx] = f2bf(gl * s2);
}

// ---------------- row L2 norms (bf16 in) ----------------
__global__ __launch_bounds__(256) void rownorm_k(const u16* __restrict__ base, long bstride,
                                                 float* __restrict__ out) {
  int r = blockIdx.x, b = blockIdx.y, tid = threadIdx.x;
  const u16* src = base + (long)b * bstride + (long)r * N_PIX;
  float s = 0.f;
  #pragma unroll
  for (int j = 0; j < 8; ++j) {
    bf16x8 v = *(const bf16x8*)(src + j * 2048 + tid * 8);
    #pragma unroll
    for (int i = 0; i < 8; ++i) { float f = bf2f((u16)v[i]); s += f * f; }
  }
  float t = blockReduceSum256(s);
  if (tid == 0) out[b * 128 + r] = sqrtf(t);
}

// ---- attn partials: per 256-pixel chunk, 16x16 Gram of (Q,K) per (b,h) ----
__global__ __launch_bounds__(256) void attn_part_k(const u16* __restrict__ q,
                                                   const u16* __restrict__ kbase,
                                                   float* __restrict__ part) {
  int ch = blockIdx.x, h = blockIdx.y, b = blockIdx.z, tid = threadIdx.x;
  int n0 = ch * 256;
  __shared__ __align__(16) u16 qc[16][280];
  __shared__ __align__(16) u16 kc[16][280];
  #pragma unroll
  for (int j = 0; j < 2; ++j) {
    int v = tid + j * 256;
    int r = v >> 5, col = (v & 31) << 3;
    long go = ((long)b * 128 + h * 16 + r) * N_PIX + n0 + col;
    *(bf16x8*)&qc[r][col] = *(const bf16x8*)(q + go);
    *(bf16x8*)&kc[r][col] = *(const bf16x8*)(kbase + go);
  }
  __syncthreads();
  int c = tid >> 4, d = tid & 15;
  float acc = 0.f;
  #pragma unroll 4
  for (int nb = 0; nb < 32; ++nb) {
    bf16x8 qv = *(const bf16x8*)&qc[c][nb * 8];
    bf16x8 kv = *(const bf16x8*)&kc[d][nb * 8];
    #pragma unroll
    for (int i = 0; i < 8; ++i) acc += bf2f((u16)qv[i]) * bf2f((u16)kv[i]);
  }
  part[(long)((((b * 8 + h) * 16 + c) * 16 + d)) * 64 + ch] = acc;
}

// ---- reduce partials + cosine scaling -> attnm [4,8,16,16] ----
__global__ __launch_bounds__(256) void attn_reduce_k(const float* __restrict__ part,
                                                     const float* __restrict__ qn,
                                                     const float* __restrict__ kn,
                                                     const float* __restrict__ temp,
                                                     float* __restrict__ attnm) {
  int idx = blockIdx.x * 256 + threadIdx.x;   // 8192 entries
  const float* p = part + (long)idx * 64;
  float s = 0.f;
  #pragma unroll
  for (int j = 0; j < 64; ++j) s += p[j];
  int d = idx & 15, c = (idx >> 4) & 15, h = (idx >> 8) & 7, b = idx >> 11;
  float nq = fmaxf(qn[b * 128 + h * 16 + c], 1e-12f);
  float nk = fmaxf(kn[b * 128 + h * 16 + d], 1e-12f);
  attnm[idx] = s / (nq * nk) * temp[h];
}

// ---------------- top14 threshold + softmax + fold proj into Cmb[b,128,128] ----------------
__global__ __launch_bounds__(128) void score_cmb_k(const float* __restrict__ attnm,
                                                   const float* __restrict__ projw,
                                                   const float* __restrict__ attn4p,
                                                   float* __restrict__ cmb) {
  int b = blockIdx.x, tid = threadIdx.x;
  __shared__ float att_s[2048], score_s[2048];
  for (int i = tid; i < 2048; i += 128) att_s[i] = attnm[(long)b * 2048 + i];
  __syncthreads();
  {
    int h = tid >> 4, c = tid & 15;
    float v[16], t[16];
    #pragma unroll
    for (int d = 0; d < 16; ++d) { v[d] = att_s[(h * 16 + c) * 16 + d]; t[d] = v[d]; }
    float thr = 0.f, M = -1e30f;
    for (int it = 0; it < 14; ++it) {
      float m = -1e30f; int mi = 0;
      #pragma unroll
      for (int d = 0; d < 16; ++d) if (t[d] > m) { m = t[d]; mi = d; }
      if (it == 0) M = m;
      thr = m;
      t[mi] = -1e31f;
    }
    float s = 0.f, e[16];
    #pragma unroll
    for (int d = 0; d < 16; ++d) { e[d] = (v[d] >= thr) ? expf(v[d] - M) : 0.f; s += e[d]; }
    float inv = 1.f / s;
    #pragma unroll
    for (int d = 0; d < 16; ++d) score_s[(h * 16 + c) * 16 + d] = e[d] * inv;
  }
  __syncthreads();
  float a4 = attn4p[0];
  int o = tid;
  for (int hd = 0; hd < 128; ++hd) {
    int h = hd >> 4, d = hd & 15;
    float s = 0.f;
    #pragma unroll
    for (int c = 0; c < 16; ++c)
      s += projw[o * 128 + h * 16 + c] * score_s[(h * 16 + c) * 16 + d];
    cmb[((long)b * 128 + o) * 128 + hd] = a4 * s;
  }
}

extern "C" void kernel_launch(void* const* d_in, const int* in_sizes, int n_in,
                              void* d_out, int out_size, void* d_ws, size_t ws_size,
                              hipStream_t stream) {
  (void)in_sizes; (void)n_in; (void)out_size; (void)ws_size;
  const float* vi        = (const float*)d_in[0];
  const float* ir        = (const float*)d_in[1];
  const float* text_code = (const float*)d_in[2];
  const float* se_w1     = (const float*)d_in[3];
  const float* se_w2     = (const float*)d_in[4];
  const float* conv1x1_w = (const float*)d_in[5];
  const float* conv1x1_b = (const float*)d_in[6];
  const float* conv_out_w= (const float*)d_in[7];
  const float* conv_out_b= (const float*)d_in[8];
  const float* text_w1   = (const float*)d_in[9];
  const float* text_b1   = (const float*)d_in[10];
  const float* text_w2   = (const float*)d_in[11];
  const float* text_b2   = (const float*)d_in[12];
  const float* norm1_w   = (const float*)d_in[13];
  const float* norm1_b   = (const float*)d_in[14];
  const float* norm2_w   = (const float*)d_in[15];
  const float* norm2_b   = (const float*)d_in[16];
  const float* norm3_w   = (const float*)d_in[17];
  const float* norm3_b   = (const float*)d_in[18];
  const float* q_w       = (const float*)d_in[19];
  const float* q_dw_w    = (const float*)d_in[20];
  const float* kv_w      = (const float*)d_in[21];
  const float* kv_dw_w   = (const float*)d_in[22];
  const float* temperature = (const float*)d_in[23];
  const float* attn4     = (const float*)d_in[24];
  const float* proj_w    = (const float*)d_in[25];
  const float* ffn_in_w  = (const float*)d_in[26];
  const float* ffn_dw_w  = (const float*)d_in[27];
  const float* ffn_out_w = (const float*)d_in[28];
  float* out0 = (float*)d_out;
  float* out1 = out0 + NP;

  // ---- workspace: small pool + bf16 arena of 2048*N_PIX elems ----
  char* W = (char*)d_ws;
  float* sq_f  = (float*)(W + 0);        // 4KB
  int*   idx_i = (int*)(W + 4096);       // 2KB
  int*   sidx_i= (int*)(W + 6144);       // 4KB
  float* mcomb = (float*)(W + 12288);    // 512KB
  float* bcomb = (float*)(W + 536576);   // 2KB
  float* qn_f  = (float*)(W + 538624);   // 2KB
  float* kn_f  = (float*)(W + 540672);   // 2KB
  float* attnm = (float*)(W + 542720);   // 32KB
  float* cmb   = (float*)(W + 575488);   // 256KB
  float* t1f   = (float*)(W + 837632);   // 8KB  [4,512]
  float* tf_f  = (float*)(W + 845824);   // 4KB  [4,256]
  u16* S   = (u16*)(W + (1 << 20));      // arena, N_PIX-elem units
  u16* CC  = S;                          // [0,512N)
  u16* KD  = S + 512L * N_PIX;           // [512N,1024N)
  u16* VD  = S + 1024L * N_PIX;          // [1024N,1536N)
  u16* TMP = S + 1536L * N_PIX;          // [1536N,2048N)
  u16* CBF = S + 1024L * N_PIX;          // bf16 concat [4,256,N]
  u16* FT1 = S;                          // FFN t1 [0,340N)
  u16* FT2 = S + 340L * N_PIX;           // FFN t2 [340N,680N)
  u16* FG  = S + 680L * N_PIX;           // FFN g  [680N,1020N)

  const long SN = 128L * N_PIX;

  // control path (+ bf16 concat emit)
  squeeze_k<<<dim3(256, 4), 256, 0, stream>>>(vi, ir, sq_f, CBF);
  se_rank_k<<<4, 256, 0, stream>>>(sq_f, se_w1, se_w2, idx_i);
  text1_k<<<dim3(64, 4), 256, 0, stream>>>(text_code, text_w1, text_b1, t1f);
  text2_k<<<dim3(32, 4), 256, 0, stream>>>(t1f, text_w2, text_b2, tf_f);
  rank2_k<<<4, 256, 0, stream>>>(tf_f, sidx_i);
  mcomb_k<<<dim3(128, 4), 128, 0, stream>>>(conv_out_w, conv_out_b, conv1x1_w,
                                            conv1x1_b, idx_i, sidx_i, mcomb, bcomb);
  // fused: img_feature2 (f32 + bf16 copy) and q_in
  gemm_dual_k<<<dim3(256, 4), 256, 0, stream>>>(
      conv_out_w, conv_out_b, mcomb, bcomb, CBF, out1, KD, CC);
  // LayerNorms (in-place)
  ln_k<<<dim3(256, 4), 256, 0, stream>>>(CC, norm1_w, norm1_b, CC);          // xq
  ln_k<<<dim3(256, 4), 256, 0, stream>>>(KD, norm2_w, norm2_b, KD);          // xkv
  // Q path: qt -> TMP, qd -> CC
  gemm_k<0, 0, 0, 0, 2><<<dim3(256, 1, 4), 256, 0, stream>>>(
      q_w, 0, CC, SN, nullptr, 0, nullptr, 0, TMP, SN, 128, 128);
  dw3_k<<<32768, 256, 0, stream>>>(TMP, q_dw_w, CC, 128, NP);                // Q=CC
  // KV path: K -> VD, V -> KD
  gemm_k<0, 0, 0, 0, 2><<<dim3(256, 1, 4), 256, 0, stream>>>(
      kv_w, 0, KD, SN, nullptr, 0, nullptr, 0, TMP, SN, 128, 128);
  dw3_k<<<32768, 256, 0, stream>>>(TMP, kv_dw_w, VD, 128, NP);               // K=VD
  gemm_k<0, 0, 0, 0, 2><<<dim3(256, 1, 4), 256, 0, stream>>>(
      kv_w + 128 * 128, 0, KD, SN, nullptr, 0, nullptr, 0, TMP, SN, 128, 128);
  dw3_k<<<32768, 256, 0, stream>>>(TMP, kv_dw_w + 128 * 9, KD, 128, NP);     // V=KD
  // attention logits
  rownorm_k<<<dim3(128, 4), 256, 0, stream>>>(CC, SN, qn_f);
  rownorm_k<<<dim3(128, 4), 256, 0, stream>>>(VD, SN, kn_f);
  float* part = (float*)TMP;
  attn_part_k<<<dim3(64, 8, 4), 256, 0, stream>>>(CC, VD, part);
  attn_reduce_k<<<32, 256, 0, stream>>>(part, qn_f, kn_f, temperature, attnm);
  score_cmb_k<<<4, 128, 0, stream>>>(attnm, proj_w, attn4, cmb);
  // att = Cmb_b @ V -> TMP
  gemm_k<1, 0, 0, 0, 2><<<dim3(256, 1, 4), 256, 0, stream>>>(
      cmb, 128L * 128, KD, SN, nullptr, 0, nullptr, 0, TMP, SN, 128, 128);   // ATT=TMP
  ln_k<<<dim3(256, 4), 256, 0, stream>>>(TMP, norm3_w, norm3_b, VD);         // x3=VD
  // FFN per batch
  for (int b = 0; b < 4; ++b) {
    const u16* x3b = VD + (long)b * SN;
    gemm_k<0, 0, 0, 0, 2><<<dim3(256, 3, 1), 256, 0, stream>>>(
        ffn_in_w, 0, x3b, 0, nullptr, 0, nullptr, 0, FT1, 0, 340, 128);
    gemm_k<0, 0, 0, 0, 2><<<dim3(256, 3, 1), 256, 0, stream>>>(
        ffn_in_w + 340 * 128, 0, x3b, 0, nullptr, 0, nullptr, 0, FT2, 0, 340, 128);
    dw3gelu_k<<<21760, 256, 0, stream>>>(FT1, FT2, ffn_dw_w, FG);
    gemm_k<0, 0, 1, 1, 2><<<dim3(256, 1, 1), 256, 0, stream>>>(
        ffn_out_w, 0, FG, 0, nullptr, 0, TMP + (long)b * SN, 0,
        out0 + (long)b * SN, 0, 128, 340);
  }
}

// Round 8
// 569.672 us; speedup vs baseline: 2.3250x; 1.3702x over previous
//
#include <hip/hip_runtime.h>

typedef unsigned short u16;
typedef __attribute__((ext_vector_type(8))) short bf16x8;
typedef __attribute__((ext_vector_type(4))) float f32x4;

#define N_PIX 16384
static constexpr long NP = 4L * 128 * N_PIX;   // elems in one [4,128,128,128]

__device__ __forceinline__ float bf2f(u16 h) {
  unsigned u = ((unsigned)h) << 16; float f; __builtin_memcpy(&f, &u, 4); return f;
}
__device__ __forceinline__ u16 f2bf(float f) {
  unsigned u; __builtin_memcpy(&u, &f, 4);
  u = (u + 0x7fffu + ((u >> 16) & 1u)) >> 16; return (u16)u;
}

__device__ __forceinline__ float blockReduceSum256(float v) {
  #pragma unroll
  for (int o = 32; o > 0; o >>= 1) v += __shfl_down(v, o, 64);
  __shared__ float sw[4];
  int lane = threadIdx.x & 63, w = threadIdx.x >> 6;
  if (lane == 0) sw[w] = v;
  __syncthreads();
  return (threadIdx.x == 0) ? (sw[0] + sw[1] + sw[2] + sw[3]) : 0.f;
}

// ---- squeeze: mean over HW of concat (f32 in) -> [4,256] f32 ; also emit bf16 concat ----
__global__ __launch_bounds__(256) void squeeze_k(const float* __restrict__ vi,
                                                 const float* __restrict__ ir,
                                                 float* __restrict__ sq,
                                                 u16* __restrict__ cbf) {
  int c = blockIdx.x, b = blockIdx.y, tid = threadIdx.x;
  const float* src = (c < 128) ? (vi + ((long)b * 128 + c) * N_PIX)
                               : (ir + ((long)b * 128 + (c - 128)) * N_PIX);
  const f32x4* src4 = (const f32x4*)src;
  u16* dst = cbf + ((long)b * 256 + c) * N_PIX;
  float s = 0.f;
  #pragma unroll
  for (int j = 0; j < 8; ++j) {
    f32x4 v0 = src4[j * 512 + tid * 2];
    f32x4 v1 = src4[j * 512 + tid * 2 + 1];
    s += v0.x + v0.y + v0.z + v0.w + v1.x + v1.y + v1.z + v1.w;
    bf16x8 r;
    r[0] = (short)f2bf(v0.x); r[1] = (short)f2bf(v0.y);
    r[2] = (short)f2bf(v0.z); r[3] = (short)f2bf(v0.w);
    r[4] = (short)f2bf(v1.x); r[5] = (short)f2bf(v1.y);
    r[6] = (short)f2bf(v1.z); r[7] = (short)f2bf(v1.w);
    *(bf16x8*)(dst + j * 2048 + tid * 8) = r;
  }
  float t = blockReduceSum256(s);
  if (tid == 0) sq[b * 256 + c] = t * (1.f / 16384.f);
}

// ---- SE MLP + top128 rank (tiny) ----
__global__ __launch_bounds__(256) void se_rank_k(const float* __restrict__ sq,
                                                 const float* __restrict__ sew1,
                                                 const float* __restrict__ sew2,
                                                 int* __restrict__ idx) {
  int b = blockIdx.x, tid = threadIdx.x;
  __shared__ float s_sq[256], s_h1[32], s_cw[256];
  s_sq[tid] = sq[b * 256 + tid];
  __syncthreads();
  if (tid < 32) {
    float s = 0.f;
    for (int c = 0; c < 256; ++c) s += s_sq[c] * sew1[tid * 256 + c];
    s_h1[tid] = fmaxf(s, 0.f);
  }
  __syncthreads();
  {
    float s = 0.f;
    #pragma unroll
    for (int j = 0; j < 32; ++j) s += s_h1[j] * sew2[tid * 32 + j];
    s_cw[tid] = 1.f / (1.f + expf(-s));
  }
  __syncthreads();
  float my = s_cw[tid];
  int rk = 0;
  for (int c = 0; c < 256; ++c) {
    float o = s_cw[c];
    rk += (o > my) || (o == my && c < tid);
  }
  if (rk < 128) idx[b * 128 + rk] = tid;
}

// ---- text MLP layer1 ----
__global__ __launch_bounds__(256) void text1_k(const float* __restrict__ tc,
                                               const float* __restrict__ tw1,
                                               const float* __restrict__ tb1,
                                               float* __restrict__ t1f) {
  int b = blockIdx.y, j0 = blockIdx.x * 8, tid = threadIdx.x;
  __shared__ float s_tc[512];
  s_tc[tid] = tc[b * 512 + tid];
  s_tc[tid + 256] = tc[b * 512 + 256 + tid];
  __syncthreads();
  int w = tid >> 6, lane = tid & 63;
  #pragma unroll
  for (int r = 0; r < 2; ++r) {
    int j = j0 + w * 2 + r;
    const float* wr = tw1 + (long)j * 512;
    float s = 0.f;
    #pragma unroll
    for (int k = 0; k < 8; ++k) s += s_tc[lane + k * 64] * wr[lane + k * 64];
    #pragma unroll
    for (int o = 32; o > 0; o >>= 1) s += __shfl_down(s, o, 64);
    if (lane == 0) t1f[b * 512 + j] = fmaxf(s + tb1[j], 0.f);
  }
}

// ---- text MLP layer2 ----
__global__ __launch_bounds__(256) void text2_k(const float* __restrict__ t1f,
                                               const float* __restrict__ tw2,
                                               const float* __restrict__ tb2,
                                               float* __restrict__ tf) {
  int b = blockIdx.y, j0 = blockIdx.x * 8, tid = threadIdx.x;
  __shared__ float s_t1[512];
  s_t1[tid] = t1f[b * 512 + tid];
  s_t1[tid + 256] = t1f[b * 512 + 256 + tid];
  __syncthreads();
  int w = tid >> 6, lane = tid & 63;
  #pragma unroll
  for (int r = 0; r < 2; ++r) {
    int j = j0 + w * 2 + r;
    const float* wr = tw2 + (long)j * 512;
    float s = 0.f;
    #pragma unroll
    for (int k = 0; k < 8; ++k) s += s_t1[lane + k * 64] * wr[lane + k * 64];
    #pragma unroll
    for (int o = 32; o > 0; o >>= 1) s += __shfl_down(s, o, 64);
    if (lane == 0) tf[b * 256 + j] = s + tb2[j];
  }
}

// ---- argsort-rank of tf -> sidx ----
__global__ __launch_bounds__(256) void rank2_k(const float* __restrict__ tf,
                                               int* __restrict__ sidx) {
  int b = blockIdx.x, tid = threadIdx.x;
  __shared__ float s_tf[256];
  s_tf[tid] = tf[b * 256 + tid];
  __syncthreads();
  float my = s_tf[tid];
  int rk = 0;
  for (int c = 0; c < 256; ++c) {
    float o = s_tf[c];
    rk += (o > my) || (o == my && c < tid);
  }
  sidx[b * 256 + rk] = tid;
}

// ---------------- fold conv1x1 + shuffle + conv_out + select into M_b[128,256] ----------------
__global__ __launch_bounds__(128) void mcomb_k(const float* __restrict__ w2,
                                               const float* __restrict__ w2b,
                                               const float* __restrict__ w1,
                                               const float* __restrict__ w1b,
                                               const int* __restrict__ idx,
                                               const int* __restrict__ sidx,
                                               float* __restrict__ mcomb,
                                               float* __restrict__ bcomb) {
  int o = blockIdx.x, b = blockIdx.y, tid = threadIdx.x;
  __shared__ float s_w2[256];
  __shared__ int s_sx[256];
  s_w2[tid] = w2[o * 256 + tid];
  s_w2[tid + 128] = w2[o * 256 + tid + 128];
  s_sx[tid] = sidx[b * 256 + tid] & 255;
  s_sx[tid + 128] = sidx[b * 256 + tid + 128] & 255;
  float* mrow = mcomb + ((long)b * 128 + o) * 256;
  mrow[tid] = 0.f;
  mrow[tid + 128] = 0.f;
  __syncthreads();
  float s = 0.f;
  for (int j = 0; j < 256; ++j) s += s_w2[j] * w1[s_sx[j] * 128 + tid];
  int cc = idx[b * 128 + tid] & 255;
  mrow[cc] = s;
  if (tid == 0) {
    float bb = w2b[o];
    for (int j = 0; j < 256; ++j) bb += s_w2[j] * w1b[s_sx[j]];
    bcomb[b * 128 + o] = bb;
  }
}

// ---- fused dual GEMM (128-row o-tile) ----
__global__ __launch_bounds__(256) void gemm_dual_k(
    const float* __restrict__ W2, const float* __restrict__ b2,
    const float* __restrict__ Mc, const float* __restrict__ bc,
    const u16* __restrict__ Xb,
    float* __restrict__ out1, u16* __restrict__ img2b, u16* __restrict__ qin) {
  const int N = N_PIX;
  int n0 = blockIdx.x * 64, bz = blockIdx.y, tid = threadIdx.x;
  __shared__ __align__(16) u16 A1[128][40];
  __shared__ __align__(16) u16 A2h[128][40];
  __shared__ __align__(16) u16 A2l[128][40];
  __shared__ __align__(16) u16 Xs[64][40];
  f32x4 acc1[2][4], acc2[2][4];
  #pragma unroll
  for (int ot = 0; ot < 2; ++ot)
    #pragma unroll
    for (int i = 0; i < 4; ++i) { acc1[ot][i] = (f32x4){0,0,0,0}; acc2[ot][i] = (f32x4){0,0,0,0}; }
  int wv = tid >> 6, lane = tid & 63;
  int lr = lane & 15, lk = (lane >> 4) * 8;
  for (int kt = 0; kt < 8; ++kt) {
    int k0 = kt << 5;
    #pragma unroll
    for (int ot = 0; ot < 2; ++ot) {
      int r = (tid >> 2) + ot * 64, cb = (tid & 3) << 3;
      const float* a1p = W2 + (long)r * 256 + k0 + cb;
      f32x4 u0 = *(const f32x4*)a1p, u1 = *(const f32x4*)(a1p + 4);
      A1[r][cb+0]=f2bf(u0.x); A1[r][cb+1]=f2bf(u0.y); A1[r][cb+2]=f2bf(u0.z); A1[r][cb+3]=f2bf(u0.w);
      A1[r][cb+4]=f2bf(u1.x); A1[r][cb+5]=f2bf(u1.y); A1[r][cb+6]=f2bf(u1.z); A1[r][cb+7]=f2bf(u1.w);
      const float* a2p = Mc + ((long)bz * 128 + r) * 256 + k0 + cb;
      f32x4 v0 = *(const f32x4*)a2p, v1 = *(const f32x4*)(a2p + 4);
      float av[8] = {v0.x, v0.y, v0.z, v0.w, v1.x, v1.y, v1.z, v1.w};
      #pragma unroll
      for (int i = 0; i < 8; ++i) {
        u16 hi = f2bf(av[i]);
        A2h[r][cb + i] = hi;
        A2l[r][cb + i] = f2bf(av[i] - bf2f(hi));
      }
    }
    {
      int kl = tid >> 3, nb = (tid & 7) << 3;
      const u16* src = Xb + ((long)bz * 256 + k0 + kl) * N + n0 + nb;
      bf16x8 t = *(const bf16x8*)src;
      #pragma unroll
      for (int i = 0; i < 8; ++i) Xs[nb + i][kl] = (u16)t[i];
    }
    __syncthreads();
    bf16x8 bfr[4];
    #pragma unroll
    for (int nt = 0; nt < 4; ++nt) bfr[nt] = *(const bf16x8*)&Xs[nt * 16 + lr][lk];
    #pragma unroll
    for (int ot = 0; ot < 2; ++ot) {
      bf16x8 a1 = *(const bf16x8*)&A1[ot * 64 + wv * 16 + lr][lk];
      bf16x8 a2h = *(const bf16x8*)&A2h[ot * 64 + wv * 16 + lr][lk];
      bf16x8 a2l = *(const bf16x8*)&A2l[ot * 64 + wv * 16 + lr][lk];
      #pragma unroll
      for (int nt = 0; nt < 4; ++nt) {
        acc1[ot][nt] = __builtin_amdgcn_mfma_f32_16x16x32_bf16(a1, bfr[nt], acc1[ot][nt], 0, 0, 0);
        acc2[ot][nt] = __builtin_amdgcn_mfma_f32_16x16x32_bf16(a2h, bfr[nt], acc2[ot][nt], 0, 0, 0);
        acc2[ot][nt] = __builtin_amdgcn_mfma_f32_16x16x32_bf16(a2l, bfr[nt], acc2[ot][nt], 0, 0, 0);
      }
    }
    __syncthreads();
  }
  #pragma unroll
  for (int ot = 0; ot < 2; ++ot)
    #pragma unroll
    for (int nt = 0; nt < 4; ++nt)
      #pragma unroll
      for (int r4 = 0; r4 < 4; ++r4) {
        int o = ot * 64 + wv * 16 + (lane >> 4) * 4 + r4;
        int n = n0 + nt * 16 + (lane & 15);
        long oi = ((long)bz * 128 + o) * N + n;
        float v1 = acc1[ot][nt][r4] + b2[o];
        out1[oi] = v1;
        img2b[oi] = f2bf(v1);
        qin[oi] = f2bf(acc2[ot][nt][r4] + bc[bz * 128 + o]);
      }
}

// ---------------- generic MFMA GEMM, OT o-tiles of 64 rows per block ----------------
template<int AMODE, int BIAS, int RESADD, int OUTF, int OT>
__global__ __launch_bounds__(256) void gemm_k(
    const float* __restrict__ Aw, long a_bstride,
    const u16* __restrict__ X, long x_bstride,
    const float* __restrict__ bias, long bias_bstride,
    const u16* __restrict__ res, long res_bstride,
    void* __restrict__ outv, long out_bstride,
    int O, int K) {
  const int N = N_PIX;
  int n0 = blockIdx.x * 64;
  int o0 = blockIdx.y * 64 * OT;
  int bz = blockIdx.z;
  int tid = threadIdx.x;
  __shared__ __align__(16) u16 As[64 * OT][40];
  __shared__ __align__(16) u16 Al[AMODE ? 64 * OT : 1][40];
  __shared__ __align__(16) u16 Xs[64][40];
  f32x4 acc[OT][4];
  #pragma unroll
  for (int ot = 0; ot < OT; ++ot)
    #pragma unroll
    for (int i = 0; i < 4; ++i) acc[ot][i] = (f32x4){0.f, 0.f, 0.f, 0.f};
  int wv = tid >> 6, lane = tid & 63;
  int lr = lane & 15, lk = (lane >> 4) * 8;
  int nk = (K + 31) >> 5;
  for (int kt = 0; kt < nk; ++kt) {
    int k0 = kt << 5;
    #pragma unroll
    for (int ot = 0; ot < OT; ++ot) {
      int r = (tid >> 2) + ot * 64, cb = (tid & 3) << 3;
      int o = o0 + r;
      if (AMODE == 0) {
        if (o < O && (k0 + cb + 8 <= K)) {
          const float* ap = Aw + (long)o * K + k0 + cb;
          f32x4 v0 = *(const f32x4*)ap;
          f32x4 v1 = *(const f32x4*)(ap + 4);
          As[r][cb + 0] = f2bf(v0.x); As[r][cb + 1] = f2bf(v0.y);
          As[r][cb + 2] = f2bf(v0.z); As[r][cb + 3] = f2bf(v0.w);
          As[r][cb + 4] = f2bf(v1.x); As[r][cb + 5] = f2bf(v1.y);
          As[r][cb + 6] = f2bf(v1.z); As[r][cb + 7] = f2bf(v1.w);
        } else {
          #pragma unroll
          for (int i = 0; i < 8; ++i) {
            int k = k0 + cb + i;
            As[r][cb + i] = (o < O && k < K) ? f2bf(Aw[(long)o * K + k]) : (u16)0;
          }
        }
      } else {
        #pragma unroll
        for (int i = 0; i < 8; ++i) {
          int k = k0 + cb + i;
          float av = (o < O && k < K) ? Aw[(long)bz * a_bstride + (long)o * K + k] : 0.f;
          u16 hi = f2bf(av);
          As[r][cb + i] = hi;
          Al[r][cb + i] = f2bf(av - bf2f(hi));
        }
      }
    }
    {
      int kl = tid >> 3, nb = (tid & 7) << 3;
      int k = k0 + kl;
      u16 tmp[8];
      if (k < K) {
        const u16* src = X + (long)bz * x_bstride + (long)k * N;
        bf16x8 t = *(const bf16x8*)(src + n0 + nb);
        #pragma unroll
        for (int i = 0; i < 8; ++i) tmp[i] = (u16)t[i];
      } else {
        #pragma unroll
        for (int i = 0; i < 8; ++i) tmp[i] = 0;
      }
      #pragma unroll
      for (int i = 0; i < 8; ++i) Xs[nb + i][kl] = tmp[i];
    }
    __syncthreads();
    bf16x8 bfr[4];
    #pragma unroll
    for (int nt = 0; nt < 4; ++nt) bfr[nt] = *(const bf16x8*)&Xs[nt * 16 + lr][lk];
    #pragma unroll
    for (int ot = 0; ot < OT; ++ot) {
      bf16x8 afr = *(const bf16x8*)&As[ot * 64 + wv * 16 + lr][lk];
      bf16x8 alr;
      if (AMODE == 1) alr = *(const bf16x8*)&Al[ot * 64 + wv * 16 + lr][lk];
      #pragma unroll
      for (int nt = 0; nt < 4; ++nt) {
        acc[ot][nt] = __builtin_amdgcn_mfma_f32_16x16x32_bf16(afr, bfr[nt], acc[ot][nt], 0, 0, 0);
        if (AMODE == 1)
          acc[ot][nt] = __builtin_amdgcn_mfma_f32_16x16x32_bf16(alr, bfr[nt], acc[ot][nt], 0, 0, 0);
      }
    }
    __syncthreads();
  }
  #pragma unroll
  for (int ot = 0; ot < OT; ++ot)
    #pragma unroll
    for (int nt = 0; nt < 4; ++nt)
      #pragma unroll
      for (int r4 = 0; r4 < 4; ++r4) {
        int o = o0 + ot * 64 + wv * 16 + (lane >> 4) * 4 + r4;
        int n = n0 + nt * 16 + (lane & 15);
        if (o < O) {
          float v = acc[ot][nt][r4];
          if (BIAS == 1) v += bias[o];
          if (BIAS == 2) v += bias[(long)bz * bias_bstride + o];
          if (RESADD) v += bf2f(res[(long)bz * res_bstride + (long)o * N + n]);
          long oi = (long)bz * out_bstride + (long)o * N + n;
          if (OUTF) ((float*)outv)[oi] = v;
          else ((u16*)outv)[oi] = f2bf(v);
        }
      }
}

// ---------------- LayerNorm over channel dim (C=128), bf16 in (in-place safe) ----------------
__global__ __launch_bounds__(256) void ln_k(const u16* __restrict__ in,
                                            const float* __restrict__ gamma,
                                            const float* __restrict__ beta,
                                            u16* __restrict__ out) {
  int p0 = blockIdx.x * 64, b = blockIdx.y, tid = threadIdx.x;
  int px = tid & 63, g4 = tid >> 6;
  __shared__ float tile[128][65];
  __shared__ float red[8][64];
  __shared__ float gmm[128], bta[128], mu_s[64], rs_s[64];
  if (tid < 128) { gmm[tid] = gamma[tid]; bta[tid] = beta[tid]; }
  long bofs = (long)b * 128 * N_PIX;
  float s = 0.f;
  for (int c = g4; c < 128; c += 4) {
    float v = bf2f(in[bofs + (long)c * N_PIX + p0 + px]);
    tile[c][px] = v;
    s += v;
  }
  red[g4][px] = s;
  __syncthreads();
  if (g4 == 0) mu_s[px] = (red[0][px] + red[1][px] + red[2][px] + red[3][px]) * (1.f / 128.f);
  __syncthreads();
  float mu = mu_s[px];
  float s2 = 0.f;
  for (int c = g4; c < 128; c += 4) { float d = tile[c][px] - mu; s2 += d * d; }
  red[4 + g4][px] = s2;
  __syncthreads();
  if (g4 == 0) {
    float var = (red[4][px] + red[5][px] + red[6][px] + red[7][px]) * (1.f / 128.f);
    rs_s[px] = rsqrtf(var + 1e-5f);
  }
  __syncthreads();
  float rs = rs_s[px];
  for (int c = g4; c < 128; c += 4)
    out[bofs + (long)c * N_PIX + p0 + px] = f2bf((tile[c][px] - mu) * rs * gmm[c] + bta[c]);
}

// ---- LDS-tiled depthwise 3x3: one block = 16-row stripe of one channel plane ----
__global__ __launch_bounds__(256) void dw3t_k(const u16* __restrict__ in,
                                              const float* __restrict__ w,
                                              u16* __restrict__ out, int C) {
  int plane = blockIdx.x >> 3, stripe = blockIdx.x & 7, tid = threadIdx.x;
  int c = plane % C;
  long pbase = (long)plane * N_PIX;
  int y0 = stripe * 16;
  __shared__ __align__(16) u16 tile[18][136];
  for (int v = tid; v < 288; v += 256) {
    int r = v >> 4, col = (v & 15) << 3;
    int y = y0 - 1 + r;
    bf16x8 t;
    #pragma unroll
    for (int i = 0; i < 8; ++i) t[i] = 0;
    if (y >= 0 && y < 128) t = *(const bf16x8*)(in + pbase + y * 128 + col);
    *(bf16x8*)&tile[r][col] = t;
  }
  float wv[9];
  #pragma unroll
  for (int j = 0; j < 9; ++j) wv[j] = w[c * 9 + j];
  __syncthreads();
  int row = tid >> 4, col0 = (tid & 15) << 3;
  float a[3][10];
  #pragma unroll
  for (int dr = 0; dr < 3; ++dr)
    #pragma unroll
    for (int i = 0; i < 10; ++i) {
      int x = col0 - 1 + i;
      a[dr][i] = (x >= 0 && x < 128) ? bf2f(tile[row + dr][x]) : 0.f;
    }
  bf16x8 res;
  #pragma unroll
  for (int j = 0; j < 8; ++j) {
    float s = 0.f;
    #pragma unroll
    for (int dr = 0; dr < 3; ++dr)
      #pragma unroll
      for (int dx = 0; dx < 3; ++dx) s += wv[dr * 3 + dx] * a[dr][j + dx];
    res[j] = (short)f2bf(s);
  }
  *(bf16x8*)(out + pbase + (y0 + row) * 128 + col0) = res;
}

// ---- LDS-tiled fused FFN tail: g = gelu(dw3(t1)) * dw3(t2), 340 planes ----
__global__ __launch_bounds__(256) void dw3gelu_t_k(const u16* __restrict__ t1,
                                                   const u16* __restrict__ t2,
                                                   const float* __restrict__ w,
                                                   u16* __restrict__ g) {
  int plane = blockIdx.x >> 3, stripe = blockIdx.x & 7, tid = threadIdx.x;
  long pbase = (long)plane * N_PIX;
  int y0 = stripe * 16;
  __shared__ __align__(16) u16 ta[18][136];
  __shared__ __align__(16) u16 tb[18][136];
  for (int v = tid; v < 288; v += 256) {
    int r = v >> 4, col = (v & 15) << 3;
    int y = y0 - 1 + r;
    bf16x8 u1, u2;
    #pragma unroll
    for (int i = 0; i < 8; ++i) { u1[i] = 0; u2[i] = 0; }
    if (y >= 0 && y < 128) {
      u1 = *(const bf16x8*)(t1 + pbase + y * 128 + col);
      u2 = *(const bf16x8*)(t2 + pbase + y * 128 + col);
    }
    *(bf16x8*)&ta[r][col] = u1;
    *(bf16x8*)&tb[r][col] = u2;
  }
  float w1[9], w2[9];
  #pragma unroll
  for (int j = 0; j < 9; ++j) { w1[j] = w[plane * 9 + j]; w2[j] = w[(340 + plane) * 9 + j]; }
  __syncthreads();
  int row = tid >> 4, col0 = (tid & 15) << 3;
  float a[3][10], b[3][10];
  #pragma unroll
  for (int dr = 0; dr < 3; ++dr)
    #pragma unroll
    for (int i = 0; i < 10; ++i) {
      int x = col0 - 1 + i;
      bool ok = (x >= 0 && x < 128);
      a[dr][i] = ok ? bf2f(ta[row + dr][x]) : 0.f;
      b[dr][i] = ok ? bf2f(tb[row + dr][x]) : 0.f;
    }
  bf16x8 res;
  #pragma unroll
  for (int j = 0; j < 8; ++j) {
    float s1 = 0.f, s2 = 0.f;
    #pragma unroll
    for (int dr = 0; dr < 3; ++dr)
      #pragma unroll
      for (int dx = 0; dx < 3; ++dx) {
        s1 += w1[dr * 3 + dx] * a[dr][j + dx];
        s2 += w2[dr * 3 + dx] * b[dr][j + dx];
      }
    float gl = 0.5f * s1 * (1.f + erff(s1 * 0.70710678118f));
    res[j] = (short)f2bf(gl * s2);
  }
  *(bf16x8*)(g + pbase + (y0 + row) * 128 + col0) = res;
}

// ---------------- row L2 norms (bf16 in) ----------------
__global__ __launch_bounds__(256) void rownorm_k(const u16* __restrict__ base, long bstride,
                                                 float* __restrict__ out) {
  int r = blockIdx.x, b = blockIdx.y, tid = threadIdx.x;
  const u16* src = base + (long)b * bstride + (long)r * N_PIX;
  float s = 0.f;
  #pragma unroll
  for (int j = 0; j < 8; ++j) {
    bf16x8 v = *(const bf16x8*)(src + j * 2048 + tid * 8);
    #pragma unroll
    for (int i = 0; i < 8; ++i) { float f = bf2f((u16)v[i]); s += f * f; }
  }
  float t = blockReduceSum256(s);
  if (tid == 0) out[b * 128 + r] = sqrtf(t);
}

// ---- attn partials ----
__global__ __launch_bounds__(256) void attn_part_k(const u16* __restrict__ q,
                                                   const u16* __restrict__ kbase,
                                                   float* __restrict__ part) {
  int ch = blockIdx.x, h = blockIdx.y, b = blockIdx.z, tid = threadIdx.x;
  int n0 = ch * 256;
  __shared__ __align__(16) u16 qc[16][280];
  __shared__ __align__(16) u16 kc[16][280];
  #pragma unroll
  for (int j = 0; j < 2; ++j) {
    int v = tid + j * 256;
    int r = v >> 5, col = (v & 31) << 3;
    long go = ((long)b * 128 + h * 16 + r) * N_PIX + n0 + col;
    *(bf16x8*)&qc[r][col] = *(const bf16x8*)(q + go);
    *(bf16x8*)&kc[r][col] = *(const bf16x8*)(kbase + go);
  }
  __syncthreads();
  int c = tid >> 4, d = tid & 15;
  float acc = 0.f;
  #pragma unroll 4
  for (int nb = 0; nb < 32; ++nb) {
    bf16x8 qv = *(const bf16x8*)&qc[c][nb * 8];
    bf16x8 kv = *(const bf16x8*)&kc[d][nb * 8];
    #pragma unroll
    for (int i = 0; i < 8; ++i) acc += bf2f((u16)qv[i]) * bf2f((u16)kv[i]);
  }
  part[(long)((((b * 8 + h) * 16 + c) * 16 + d)) * 64 + ch] = acc;
}

// ---- reduce partials + cosine scaling ----
__global__ __launch_bounds__(256) void attn_reduce_k(const float* __restrict__ part,
                                                     const float* __restrict__ qn,
                                                     const float* __restrict__ kn,
                                                     const float* __restrict__ temp,
                                                     float* __restrict__ attnm) {
  int idx = blockIdx.x * 256 + threadIdx.x;
  const float* p = part + (long)idx * 64;
  float s = 0.f;
  #pragma unroll
  for (int j = 0; j < 64; ++j) s += p[j];
  int d = idx & 15, c = (idx >> 4) & 15, h = (idx >> 8) & 7, b = idx >> 11;
  float nq = fmaxf(qn[b * 128 + h * 16 + c], 1e-12f);
  float nk = fmaxf(kn[b * 128 + h * 16 + d], 1e-12f);
  attnm[idx] = s / (nq * nk) * temp[h];
}

// ---------------- top14 threshold + softmax + fold proj into Cmb[b,128,128] ----------------
__global__ __launch_bounds__(128) void score_cmb_k(const float* __restrict__ attnm,
                                                   const float* __restrict__ projw,
                                                   const float* __restrict__ attn4p,
                                                   float* __restrict__ cmb) {
  int b = blockIdx.x, tid = threadIdx.x;
  __shared__ float att_s[2048], score_s[2048];
  for (int i = tid; i < 2048; i += 128) att_s[i] = attnm[(long)b * 2048 + i];
  __syncthreads();
  {
    int h = tid >> 4, c = tid & 15;
    float v[16], t[16];
    #pragma unroll
    for (int d = 0; d < 16; ++d) { v[d] = att_s[(h * 16 + c) * 16 + d]; t[d] = v[d]; }
    float thr = 0.f, M = -1e30f;
    for (int it = 0; it < 14; ++it) {
      float m = -1e30f; int mi = 0;
      #pragma unroll
      for (int d = 0; d < 16; ++d) if (t[d] > m) { m = t[d]; mi = d; }
      if (it == 0) M = m;
      thr = m;
      t[mi] = -1e31f;
    }
    float s = 0.f, e[16];
    #pragma unroll
    for (int d = 0; d < 16; ++d) { e[d] = (v[d] >= thr) ? expf(v[d] - M) : 0.f; s += e[d]; }
    float inv = 1.f / s;
    #pragma unroll
    for (int d = 0; d < 16; ++d) score_s[(h * 16 + c) * 16 + d] = e[d] * inv;
  }
  __syncthreads();
  float a4 = attn4p[0];
  int o = tid;
  for (int hd = 0; hd < 128; ++hd) {
    int h = hd >> 4, d = hd & 15;
    float s = 0.f;
    #pragma unroll
    for (int c = 0; c < 16; ++c)
      s += projw[o * 128 + h * 16 + c] * score_s[(h * 16 + c) * 16 + d];
    cmb[((long)b * 128 + o) * 128 + hd] = a4 * s;
  }
}

extern "C" void kernel_launch(void* const* d_in, const int* in_sizes, int n_in,
                              void* d_out, int out_size, void* d_ws, size_t ws_size,
                              hipStream_t stream) {
  (void)in_sizes; (void)n_in; (void)out_size; (void)ws_size;
  const float* vi        = (const float*)d_in[0];
  const float* ir        = (const float*)d_in[1];
  const float* text_code = (const float*)d_in[2];
  const float* se_w1     = (const float*)d_in[3];
  const float* se_w2     = (const float*)d_in[4];
  const float* conv1x1_w = (const float*)d_in[5];
  const float* conv1x1_b = (const float*)d_in[6];
  const float* conv_out_w= (const float*)d_in[7];
  const float* conv_out_b= (const float*)d_in[8];
  const float* text_w1   = (const float*)d_in[9];
  const float* text_b1   = (const float*)d_in[10];
  const float* text_w2   = (const float*)d_in[11];
  const float* text_b2   = (const float*)d_in[12];
  const float* norm1_w   = (const float*)d_in[13];
  const float* norm1_b   = (const float*)d_in[14];
  const float* norm2_w   = (const float*)d_in[15];
  const float* norm2_b   = (const float*)d_in[16];
  const float* norm3_w   = (const float*)d_in[17];
  const float* norm3_b   = (const float*)d_in[18];
  const float* q_w       = (const float*)d_in[19];
  const float* q_dw_w    = (const float*)d_in[20];
  const float* kv_w      = (const float*)d_in[21];
  const float* kv_dw_w   = (const float*)d_in[22];
  const float* temperature = (const float*)d_in[23];
  const float* attn4     = (const float*)d_in[24];
  const float* proj_w    = (const float*)d_in[25];
  const float* ffn_in_w  = (const float*)d_in[26];
  const float* ffn_dw_w  = (const float*)d_in[27];
  const float* ffn_out_w = (const float*)d_in[28];
  float* out0 = (float*)d_out;
  float* out1 = out0 + NP;

  char* W = (char*)d_ws;
  float* sq_f  = (float*)(W + 0);
  int*   idx_i = (int*)(W + 4096);
  int*   sidx_i= (int*)(W + 6144);
  float* mcomb = (float*)(W + 12288);
  float* bcomb = (float*)(W + 536576);
  float* qn_f  = (float*)(W + 538624);
  float* kn_f  = (float*)(W + 540672);
  float* attnm = (float*)(W + 542720);
  float* cmb   = (float*)(W + 575488);
  float* t1f   = (float*)(W + 837632);
  float* tf_f  = (float*)(W + 845824);
  u16* S   = (u16*)(W + (1 << 20));
  u16* CC  = S;
  u16* KD  = S + 512L * N_PIX;
  u16* VD  = S + 1024L * N_PIX;
  u16* TMP = S + 1536L * N_PIX;
  u16* CBF = S + 1024L * N_PIX;
  u16* FT1 = S;
  u16* FT2 = S + 340L * N_PIX;
  u16* FG  = S + 680L * N_PIX;

  const long SN = 128L * N_PIX;

  squeeze_k<<<dim3(256, 4), 256, 0, stream>>>(vi, ir, sq_f, CBF);
  se_rank_k<<<4, 256, 0, stream>>>(sq_f, se_w1, se_w2, idx_i);
  text1_k<<<dim3(64, 4), 256, 0, stream>>>(text_code, text_w1, text_b1, t1f);
  text2_k<<<dim3(32, 4), 256, 0, stream>>>(t1f, text_w2, text_b2, tf_f);
  rank2_k<<<4, 256, 0, stream>>>(tf_f, sidx_i);
  mcomb_k<<<dim3(128, 4), 128, 0, stream>>>(conv_out_w, conv_out_b, conv1x1_w,
                                            conv1x1_b, idx_i, sidx_i, mcomb, bcomb);
  gemm_dual_k<<<dim3(256, 4), 256, 0, stream>>>(
      conv_out_w, conv_out_b, mcomb, bcomb, CBF, out1, KD, CC);
  ln_k<<<dim3(256, 4), 256, 0, stream>>>(CC, norm1_w, norm1_b, CC);          // xq
  ln_k<<<dim3(256, 4), 256, 0, stream>>>(KD, norm2_w, norm2_b, KD);          // xkv
  gemm_k<0, 0, 0, 0, 2><<<dim3(256, 1, 4), 256, 0, stream>>>(
      q_w, 0, CC, SN, nullptr, 0, nullptr, 0, TMP, SN, 128, 128);
  dw3t_k<<<4096, 256, 0, stream>>>(TMP, q_dw_w, CC, 128);                    // Q=CC
  gemm_k<0, 0, 0, 0, 2><<<dim3(256, 1, 4), 256, 0, stream>>>(
      kv_w, 0, KD, SN, nullptr, 0, nullptr, 0, TMP, SN, 128, 128);
  dw3t_k<<<4096, 256, 0, stream>>>(TMP, kv_dw_w, VD, 128);                   // K=VD
  gemm_k<0, 0, 0, 0, 2><<<dim3(256, 1, 4), 256, 0, stream>>>(
      kv_w + 128 * 128, 0, KD, SN, nullptr, 0, nullptr, 0, TMP, SN, 128, 128);
  dw3t_k<<<4096, 256, 0, stream>>>(TMP, kv_dw_w + 128 * 9, KD, 128);         // V=KD
  rownorm_k<<<dim3(128, 4), 256, 0, stream>>>(CC, SN, qn_f);
  rownorm_k<<<dim3(128, 4), 256, 0, stream>>>(VD, SN, kn_f);
  float* part = (float*)TMP;
  attn_part_k<<<dim3(64, 8, 4), 256, 0, stream>>>(CC, VD, part);
  attn_reduce_k<<<32, 256, 0, stream>>>(part, qn_f, kn_f, temperature, attnm);
  score_cmb_k<<<4, 128, 0, stream>>>(attnm, proj_w, attn4, cmb);
  gemm_k<1, 0, 0, 0, 2><<<dim3(256, 1, 4), 256, 0, stream>>>(
      cmb, 128L * 128, KD, SN, nullptr, 0, nullptr, 0, TMP, SN, 128, 128);   // ATT=TMP
  ln_k<<<dim3(256, 4), 256, 0, stream>>>(TMP, norm3_w, norm3_b, VD);         // x3=VD
  for (int b = 0; b < 4; ++b) {
    const u16* x3b = VD + (long)b * SN;
    gemm_k<0, 0, 0, 0, 2><<<dim3(256, 3, 1), 256, 0, stream>>>(
        ffn_in_w, 0, x3b, 0, nullptr, 0, nullptr, 0, FT1, 0, 340, 128);
    gemm_k<0, 0, 0, 0, 2><<<dim3(256, 3, 1), 256, 0, stream>>>(
        ffn_in_w + 340 * 128, 0, x3b, 0, nullptr, 0, nullptr, 0, FT2, 0, 340, 128);
    dw3gelu_t_k<<<2720, 256, 0, stream>>>(FT1, FT2, ffn_dw_w, FG);
    gemm_k<0, 0, 1, 1, 2><<<dim3(256, 1, 1), 256, 0, stream>>>(
        ffn_out_w, 0, FG, 0, nullptr, 0, TMP + (long)b * SN, 0,
        out0 + (long)b * SN, 0, 128, 340);
  }
}

// Round 9
// 534.579 us; speedup vs baseline: 2.4777x; 1.0656x over previous
//
#include <hip/hip_runtime.h>

typedef unsigned short u16;
typedef __attribute__((ext_vector_type(8))) short bf16x8;
typedef __attribute__((ext_vector_type(4))) float f32x4;

#define N_PIX 16384
static constexpr long NP = 4L * 128 * N_PIX;   // elems in one [4,128,128,128]

__device__ __forceinline__ float bf2f(u16 h) {
  unsigned u = ((unsigned)h) << 16; float f; __builtin_memcpy(&f, &u, 4); return f;
}
__device__ __forceinline__ u16 f2bf(float f) {
  unsigned u; __builtin_memcpy(&u, &f, 4);
  u = (u + 0x7fffu + ((u >> 16) & 1u)) >> 16; return (u16)u;
}
// XOR-swizzled LDS index (row stride 40 u16 = 80B, 16B-aligned; swizzle keeps 8-col blocks)
__device__ __forceinline__ int xsw(int r, int c) {
  return r * 40 + (c ^ (((r >> 3) & 3) << 3));
}

__device__ __forceinline__ float blockReduceSum256(float v) {
  #pragma unroll
  for (int o = 32; o > 0; o >>= 1) v += __shfl_down(v, o, 64);
  __shared__ float sw[4];
  int lane = threadIdx.x & 63, w = threadIdx.x >> 6;
  if (lane == 0) sw[w] = v;
  __syncthreads();
  return (threadIdx.x == 0) ? (sw[0] + sw[1] + sw[2] + sw[3]) : 0.f;
}

// ---- squeeze: mean over HW of concat (f32 in) -> [4,256] f32 ; also emit bf16 concat ----
__global__ __launch_bounds__(256) void squeeze_k(const float* __restrict__ vi,
                                                 const float* __restrict__ ir,
                                                 float* __restrict__ sq,
                                                 u16* __restrict__ cbf) {
  int c = blockIdx.x, b = blockIdx.y, tid = threadIdx.x;
  const float* src = (c < 128) ? (vi + ((long)b * 128 + c) * N_PIX)
                               : (ir + ((long)b * 128 + (c - 128)) * N_PIX);
  const f32x4* src4 = (const f32x4*)src;
  u16* dst = cbf + ((long)b * 256 + c) * N_PIX;
  float s = 0.f;
  #pragma unroll
  for (int j = 0; j < 8; ++j) {
    f32x4 v0 = src4[j * 512 + tid * 2];
    f32x4 v1 = src4[j * 512 + tid * 2 + 1];
    s += v0.x + v0.y + v0.z + v0.w + v1.x + v1.y + v1.z + v1.w;
    bf16x8 r;
    r[0] = (short)f2bf(v0.x); r[1] = (short)f2bf(v0.y);
    r[2] = (short)f2bf(v0.z); r[3] = (short)f2bf(v0.w);
    r[4] = (short)f2bf(v1.x); r[5] = (short)f2bf(v1.y);
    r[6] = (short)f2bf(v1.z); r[7] = (short)f2bf(v1.w);
    *(bf16x8*)(dst + j * 2048 + tid * 8) = r;
  }
  float t = blockReduceSum256(s);
  if (tid == 0) sq[b * 256 + c] = t * (1.f / 16384.f);
}

// ---- SE MLP + top128 rank ----
__global__ __launch_bounds__(256) void se_rank_k(const float* __restrict__ sq,
                                                 const float* __restrict__ sew1,
                                                 const float* __restrict__ sew2,
                                                 int* __restrict__ idx) {
  int b = blockIdx.x, tid = threadIdx.x;
  __shared__ float s_sq[256], s_h1[32], s_cw[256];
  s_sq[tid] = sq[b * 256 + tid];
  __syncthreads();
  if (tid < 32) {
    float s = 0.f;
    for (int c = 0; c < 256; ++c) s += s_sq[c] * sew1[tid * 256 + c];
    s_h1[tid] = fmaxf(s, 0.f);
  }
  __syncthreads();
  {
    float s = 0.f;
    #pragma unroll
    for (int j = 0; j < 32; ++j) s += s_h1[j] * sew2[tid * 32 + j];
    s_cw[tid] = 1.f / (1.f + expf(-s));
  }
  __syncthreads();
  float my = s_cw[tid];
  int rk = 0;
  for (int c = 0; c < 256; ++c) {
    float o = s_cw[c];
    rk += (o > my) || (o == my && c < tid);
  }
  if (rk < 128) idx[b * 128 + rk] = tid;
}

// ---- text MLP layer1 ----
__global__ __launch_bounds__(256) void text1_k(const float* __restrict__ tc,
                                               const float* __restrict__ tw1,
                                               const float* __restrict__ tb1,
                                               float* __restrict__ t1f) {
  int b = blockIdx.y, j0 = blockIdx.x * 8, tid = threadIdx.x;
  __shared__ float s_tc[512];
  s_tc[tid] = tc[b * 512 + tid];
  s_tc[tid + 256] = tc[b * 512 + 256 + tid];
  __syncthreads();
  int w = tid >> 6, lane = tid & 63;
  #pragma unroll
  for (int r = 0; r < 2; ++r) {
    int j = j0 + w * 2 + r;
    const float* wr = tw1 + (long)j * 512;
    float s = 0.f;
    #pragma unroll
    for (int k = 0; k < 8; ++k) s += s_tc[lane + k * 64] * wr[lane + k * 64];
    #pragma unroll
    for (int o = 32; o > 0; o >>= 1) s += __shfl_down(s, o, 64);
    if (lane == 0) t1f[b * 512 + j] = fmaxf(s + tb1[j], 0.f);
  }
}

// ---- text MLP layer2 ----
__global__ __launch_bounds__(256) void text2_k(const float* __restrict__ t1f,
                                               const float* __restrict__ tw2,
                                               const float* __restrict__ tb2,
                                               float* __restrict__ tf) {
  int b = blockIdx.y, j0 = blockIdx.x * 8, tid = threadIdx.x;
  __shared__ float s_t1[512];
  s_t1[tid] = t1f[b * 512 + tid];
  s_t1[tid + 256] = t1f[b * 512 + 256 + tid];
  __syncthreads();
  int w = tid >> 6, lane = tid & 63;
  #pragma unroll
  for (int r = 0; r < 2; ++r) {
    int j = j0 + w * 2 + r;
    const float* wr = tw2 + (long)j * 512;
    float s = 0.f;
    #pragma unroll
    for (int k = 0; k < 8; ++k) s += s_t1[lane + k * 64] * wr[lane + k * 64];
    #pragma unroll
    for (int o = 32; o > 0; o >>= 1) s += __shfl_down(s, o, 64);
    if (lane == 0) tf[b * 256 + j] = s + tb2[j];
  }
}

// ---- argsort-rank of tf -> sidx ----
__global__ __launch_bounds__(256) void rank2_k(const float* __restrict__ tf,
                                               int* __restrict__ sidx) {
  int b = blockIdx.x, tid = threadIdx.x;
  __shared__ float s_tf[256];
  s_tf[tid] = tf[b * 256 + tid];
  __syncthreads();
  float my = s_tf[tid];
  int rk = 0;
  for (int c = 0; c < 256; ++c) {
    float o = s_tf[c];
    rk += (o > my) || (o == my && c < tid);
  }
  sidx[b * 256 + rk] = tid;
}

// ---------------- fold conv1x1 + shuffle + conv_out + select into M_b[128,256] ----------------
__global__ __launch_bounds__(128) void mcomb_k(const float* __restrict__ w2,
                                               const float* __restrict__ w2b,
                                               const float* __restrict__ w1,
                                               const float* __restrict__ w1b,
                                               const int* __restrict__ idx,
                                               const int* __restrict__ sidx,
                                               float* __restrict__ mcomb,
                                               float* __restrict__ bcomb) {
  int o = blockIdx.x, b = blockIdx.y, tid = threadIdx.x;
  __shared__ float s_w2[256];
  __shared__ int s_sx[256];
  s_w2[tid] = w2[o * 256 + tid];
  s_w2[tid + 128] = w2[o * 256 + tid + 128];
  s_sx[tid] = sidx[b * 256 + tid] & 255;
  s_sx[tid + 128] = sidx[b * 256 + tid + 128] & 255;
  float* mrow = mcomb + ((long)b * 128 + o) * 256;
  mrow[tid] = 0.f;
  mrow[tid + 128] = 0.f;
  __syncthreads();
  float s = 0.f;
  for (int j = 0; j < 256; ++j) s += s_w2[j] * w1[s_sx[j] * 128 + tid];
  int cc = idx[b * 128 + tid] & 255;
  mrow[cc] = s;
  if (tid == 0) {
    float bb = w2b[o];
    for (int j = 0; j < 256; ++j) bb += s_w2[j] * w1b[s_sx[j]];
    bcomb[b * 128 + o] = bb;
  }
}

// ---- fused dual GEMM (128-row o-tile), swizzled LDS ----
__global__ __launch_bounds__(256) void gemm_dual_k(
    const float* __restrict__ W2, const float* __restrict__ b2,
    const float* __restrict__ Mc, const float* __restrict__ bc,
    const u16* __restrict__ Xb,
    float* __restrict__ out1, u16* __restrict__ img2b, u16* __restrict__ qin) {
  const int N = N_PIX;
  int n0 = blockIdx.x * 64, bz = blockIdx.y, tid = threadIdx.x;
  __shared__ __align__(16) u16 A1[128 * 40];
  __shared__ __align__(16) u16 A2h[128 * 40];
  __shared__ __align__(16) u16 A2l[128 * 40];
  __shared__ __align__(16) u16 Xs[64 * 40];
  f32x4 acc1[2][4], acc2[2][4];
  #pragma unroll
  for (int ot = 0; ot < 2; ++ot)
    #pragma unroll
    for (int i = 0; i < 4; ++i) { acc1[ot][i] = (f32x4){0,0,0,0}; acc2[ot][i] = (f32x4){0,0,0,0}; }
  int wv = tid >> 6, lane = tid & 63;
  int lr = lane & 15, lk = (lane >> 4) * 8;
  for (int kt = 0; kt < 8; ++kt) {
    int k0 = kt << 5;
    #pragma unroll
    for (int ot = 0; ot < 2; ++ot) {
      int r = (tid >> 2) + ot * 64, cb = (tid & 3) << 3;
      const float* a1p = W2 + (long)r * 256 + k0 + cb;
      f32x4 u0 = *(const f32x4*)a1p, u1 = *(const f32x4*)(a1p + 4);
      float a1v[8] = {u0.x, u0.y, u0.z, u0.w, u1.x, u1.y, u1.z, u1.w};
      const float* a2p = Mc + ((long)bz * 128 + r) * 256 + k0 + cb;
      f32x4 v0 = *(const f32x4*)a2p, v1 = *(const f32x4*)(a2p + 4);
      float av[8] = {v0.x, v0.y, v0.z, v0.w, v1.x, v1.y, v1.z, v1.w};
      #pragma unroll
      for (int i = 0; i < 8; ++i) {
        A1[xsw(r, cb + i)] = f2bf(a1v[i]);
        u16 hi = f2bf(av[i]);
        A2h[xsw(r, cb + i)] = hi;
        A2l[xsw(r, cb + i)] = f2bf(av[i] - bf2f(hi));
      }
    }
    {
      int kl = tid >> 3, nb = (tid & 7) << 3;
      const u16* src = Xb + ((long)bz * 256 + k0 + kl) * N + n0 + nb;
      bf16x8 t = *(const bf16x8*)src;
      #pragma unroll
      for (int i = 0; i < 8; ++i) Xs[xsw(nb + i, kl)] = (u16)t[i];
    }
    __syncthreads();
    bf16x8 bfr[4];
    #pragma unroll
    for (int nt = 0; nt < 4; ++nt) bfr[nt] = *(const bf16x8*)&Xs[xsw(nt * 16 + lr, lk)];
    #pragma unroll
    for (int ot = 0; ot < 2; ++ot) {
      bf16x8 a1 = *(const bf16x8*)&A1[xsw(ot * 64 + wv * 16 + lr, lk)];
      bf16x8 a2h = *(const bf16x8*)&A2h[xsw(ot * 64 + wv * 16 + lr, lk)];
      bf16x8 a2l = *(const bf16x8*)&A2l[xsw(ot * 64 + wv * 16 + lr, lk)];
      #pragma unroll
      for (int nt = 0; nt < 4; ++nt) {
        acc1[ot][nt] = __builtin_amdgcn_mfma_f32_16x16x32_bf16(a1, bfr[nt], acc1[ot][nt], 0, 0, 0);
        acc2[ot][nt] = __builtin_amdgcn_mfma_f32_16x16x32_bf16(a2h, bfr[nt], acc2[ot][nt], 0, 0, 0);
        acc2[ot][nt] = __builtin_amdgcn_mfma_f32_16x16x32_bf16(a2l, bfr[nt], acc2[ot][nt], 0, 0, 0);
      }
    }
    __syncthreads();
  }
  #pragma unroll
  for (int ot = 0; ot < 2; ++ot)
    #pragma unroll
    for (int nt = 0; nt < 4; ++nt)
      #pragma unroll
      for (int r4 = 0; r4 < 4; ++r4) {
        int o = ot * 64 + wv * 16 + (lane >> 4) * 4 + r4;
        int n = n0 + nt * 16 + (lane & 15);
        long oi = ((long)bz * 128 + o) * N + n;
        float v1 = acc1[ot][nt][r4] + b2[o];
        out1[oi] = v1;
        img2b[oi] = f2bf(v1);
        qin[oi] = f2bf(acc2[ot][nt][r4] + bc[bz * 128 + o]);
      }
}

// ---------------- generic MFMA GEMM, OT o-tiles, swizzled LDS ----------------
template<int AMODE, int BIAS, int RESADD, int OUTF, int OT>
__global__ __launch_bounds__(256) void gemm_k(
    const float* __restrict__ Aw, long a_bstride,
    const u16* __restrict__ X, long x_bstride,
    const float* __restrict__ bias, long bias_bstride,
    const u16* __restrict__ res, long res_bstride,
    void* __restrict__ outv, long out_bstride,
    int O, int K) {
  const int N = N_PIX;
  int n0 = blockIdx.x * 64;
  int o0 = blockIdx.y * 64 * OT;
  int bz = blockIdx.z;
  int tid = threadIdx.x;
  __shared__ __align__(16) u16 As[64 * OT * 40];
  __shared__ __align__(16) u16 Al[(AMODE ? 64 * OT : 1) * 40];
  __shared__ __align__(16) u16 Xs[64 * 40];
  f32x4 acc[OT][4];
  #pragma unroll
  for (int ot = 0; ot < OT; ++ot)
    #pragma unroll
    for (int i = 0; i < 4; ++i) acc[ot][i] = (f32x4){0.f, 0.f, 0.f, 0.f};
  int wv = tid >> 6, lane = tid & 63;
  int lr = lane & 15, lk = (lane >> 4) * 8;
  int nk = (K + 31) >> 5;
  for (int kt = 0; kt < nk; ++kt) {
    int k0 = kt << 5;
    #pragma unroll
    for (int ot = 0; ot < OT; ++ot) {
      int r = (tid >> 2) + ot * 64, cb = (tid & 3) << 3;
      int o = o0 + r;
      if (AMODE == 0) {
        if (o < O && (k0 + cb + 8 <= K)) {
          const float* ap = Aw + (long)o * K + k0 + cb;
          f32x4 v0 = *(const f32x4*)ap;
          f32x4 v1 = *(const f32x4*)(ap + 4);
          float av[8] = {v0.x, v0.y, v0.z, v0.w, v1.x, v1.y, v1.z, v1.w};
          #pragma unroll
          for (int i = 0; i < 8; ++i) As[xsw(r, cb + i)] = f2bf(av[i]);
        } else {
          #pragma unroll
          for (int i = 0; i < 8; ++i) {
            int k = k0 + cb + i;
            As[xsw(r, cb + i)] = (o < O && k < K) ? f2bf(Aw[(long)o * K + k]) : (u16)0;
          }
        }
      } else {
        #pragma unroll
        for (int i = 0; i < 8; ++i) {
          int k = k0 + cb + i;
          float av = (o < O && k < K) ? Aw[(long)bz * a_bstride + (long)o * K + k] : 0.f;
          u16 hi = f2bf(av);
          As[xsw(r, cb + i)] = hi;
          Al[xsw(r, cb + i)] = f2bf(av - bf2f(hi));
        }
      }
    }
    {
      int kl = tid >> 3, nb = (tid & 7) << 3;
      int k = k0 + kl;
      u16 tmp[8];
      if (k < K) {
        const u16* src = X + (long)bz * x_bstride + (long)k * N;
        bf16x8 t = *(const bf16x8*)(src + n0 + nb);
        #pragma unroll
        for (int i = 0; i < 8; ++i) tmp[i] = (u16)t[i];
      } else {
        #pragma unroll
        for (int i = 0; i < 8; ++i) tmp[i] = 0;
      }
      #pragma unroll
      for (int i = 0; i < 8; ++i) Xs[xsw(nb + i, kl)] = tmp[i];
    }
    __syncthreads();
    bf16x8 bfr[4];
    #pragma unroll
    for (int nt = 0; nt < 4; ++nt) bfr[nt] = *(const bf16x8*)&Xs[xsw(nt * 16 + lr, lk)];
    #pragma unroll
    for (int ot = 0; ot < OT; ++ot) {
      bf16x8 afr = *(const bf16x8*)&As[xsw(ot * 64 + wv * 16 + lr, lk)];
      bf16x8 alr;
      if (AMODE == 1) alr = *(const bf16x8*)&Al[xsw(ot * 64 + wv * 16 + lr, lk)];
      #pragma unroll
      for (int nt = 0; nt < 4; ++nt) {
        acc[ot][nt] = __builtin_amdgcn_mfma_f32_16x16x32_bf16(afr, bfr[nt], acc[ot][nt], 0, 0, 0);
        if (AMODE == 1)
          acc[ot][nt] = __builtin_amdgcn_mfma_f32_16x16x32_bf16(alr, bfr[nt], acc[ot][nt], 0, 0, 0);
      }
    }
    __syncthreads();
  }
  #pragma unroll
  for (int ot = 0; ot < OT; ++ot)
    #pragma unroll
    for (int nt = 0; nt < 4; ++nt)
      #pragma unroll
      for (int r4 = 0; r4 < 4; ++r4) {
        int o = o0 + ot * 64 + wv * 16 + (lane >> 4) * 4 + r4;
        int n = n0 + nt * 16 + (lane & 15);
        if (o < O) {
          float v = acc[ot][nt][r4];
          if (BIAS == 1) v += bias[o];
          if (BIAS == 2) v += bias[(long)bz * bias_bstride + o];
          if (RESADD) v += bf2f(res[(long)bz * res_bstride + (long)o * N + n]);
          long oi = (long)bz * out_bstride + (long)o * N + n;
          if (OUTF) ((float*)outv)[oi] = v;
          else ((u16*)outv)[oi] = f2bf(v);
        }
      }
}

// ---------------- LayerNorm over channel dim (C=128), bf16 in ----------------
__global__ __launch_bounds__(256) void ln_k(const u16* __restrict__ in,
                                            const float* __restrict__ gamma,
                                            const float* __restrict__ beta,
                                            u16* __restrict__ out) {
  int p0 = blockIdx.x * 64, b = blockIdx.y, tid = threadIdx.x;
  int px = tid & 63, g4 = tid >> 6;
  __shared__ float tile[128][65];
  __shared__ float red[8][64];
  __shared__ float gmm[128], bta[128], mu_s[64], rs_s[64];
  if (tid < 128) { gmm[tid] = gamma[tid]; bta[tid] = beta[tid]; }
  long bofs = (long)b * 128 * N_PIX;
  float s = 0.f;
  for (int c = g4; c < 128; c += 4) {
    float v = bf2f(in[bofs + (long)c * N_PIX + p0 + px]);
    tile[c][px] = v;
    s += v;
  }
  red[g4][px] = s;
  __syncthreads();
  if (g4 == 0) mu_s[px] = (red[0][px] + red[1][px] + red[2][px] + red[3][px]) * (1.f / 128.f);
  __syncthreads();
  float mu = mu_s[px];
  float s2 = 0.f;
  for (int c = g4; c < 128; c += 4) { float d = tile[c][px] - mu; s2 += d * d; }
  red[4 + g4][px] = s2;
  __syncthreads();
  if (g4 == 0) {
    float var = (red[4][px] + red[5][px] + red[6][px] + red[7][px]) * (1.f / 128.f);
    rs_s[px] = rsqrtf(var + 1e-5f);
  }
  __syncthreads();
  float rs = rs_s[px];
  for (int c = g4; c < 128; c += 4)
    out[bofs + (long)c * N_PIX + p0 + px] = f2bf((tile[c][px] - mu) * rs * gmm[c] + bta[c]);
}

// ---- LDS-tiled depthwise 3x3 ----
__global__ __launch_bounds__(256) void dw3t_k(const u16* __restrict__ in,
                                              const float* __restrict__ w,
                                              u16* __restrict__ out, int C) {
  int plane = blockIdx.x >> 3, stripe = blockIdx.x & 7, tid = threadIdx.x;
  int c = plane % C;
  long pbase = (long)plane * N_PIX;
  int y0 = stripe * 16;
  __shared__ __align__(16) u16 tile[18][136];
  for (int v = tid; v < 288; v += 256) {
    int r = v >> 4, col = (v & 15) << 3;
    int y = y0 - 1 + r;
    bf16x8 t;
    #pragma unroll
    for (int i = 0; i < 8; ++i) t[i] = 0;
    if (y >= 0 && y < 128) t = *(const bf16x8*)(in + pbase + y * 128 + col);
    *(bf16x8*)&tile[r][col] = t;
  }
  float wv[9];
  #pragma unroll
  for (int j = 0; j < 9; ++j) wv[j] = w[c * 9 + j];
  __syncthreads();
  int row = tid >> 4, col0 = (tid & 15) << 3;
  float a[3][10];
  #pragma unroll
  for (int dr = 0; dr < 3; ++dr)
    #pragma unroll
    for (int i = 0; i < 10; ++i) {
      int x = col0 - 1 + i;
      a[dr][i] = (x >= 0 && x < 128) ? bf2f(tile[row + dr][x]) : 0.f;
    }
  bf16x8 res;
  #pragma unroll
  for (int j = 0; j < 8; ++j) {
    float s = 0.f;
    #pragma unroll
    for (int dr = 0; dr < 3; ++dr)
      #pragma unroll
      for (int dx = 0; dx < 3; ++dx) s += wv[dr * 3 + dx] * a[dr][j + dx];
    res[j] = (short)f2bf(s);
  }
  *(bf16x8*)(out + pbase + (y0 + row) * 128 + col0) = res;
}

// ---- LDS-tiled fused FFN tail: g = gelu(dw3(t1)) * dw3(t2), 340 planes ----
__global__ __launch_bounds__(256) void dw3gelu_t_k(const u16* __restrict__ t1,
                                                   const u16* __restrict__ t2,
                                                   const float* __restrict__ w,
                                                   u16* __restrict__ g) {
  int plane = blockIdx.x >> 3, stripe = blockIdx.x & 7, tid = threadIdx.x;
  long pbase = (long)plane * N_PIX;
  int y0 = stripe * 16;
  __shared__ __align__(16) u16 ta[18][136];
  __shared__ __align__(16) u16 tb[18][136];
  for (int v = tid; v < 288; v += 256) {
    int r = v >> 4, col = (v & 15) << 3;
    int y = y0 - 1 + r;
    bf16x8 u1, u2;
    #pragma unroll
    for (int i = 0; i < 8; ++i) { u1[i] = 0; u2[i] = 0; }
    if (y >= 0 && y < 128) {
      u1 = *(const bf16x8*)(t1 + pbase + y * 128 + col);
      u2 = *(const bf16x8*)(t2 + pbase + y * 128 + col);
    }
    *(bf16x8*)&ta[r][col] = u1;
    *(bf16x8*)&tb[r][col] = u2;
  }
  float w1[9], w2[9];
  #pragma unroll
  for (int j = 0; j < 9; ++j) { w1[j] = w[plane * 9 + j]; w2[j] = w[(340 + plane) * 9 + j]; }
  __syncthreads();
  int row = tid >> 4, col0 = (tid & 15) << 3;
  float a[3][10], b[3][10];
  #pragma unroll
  for (int dr = 0; dr < 3; ++dr)
    #pragma unroll
    for (int i = 0; i < 10; ++i) {
      int x = col0 - 1 + i;
      bool ok = (x >= 0 && x < 128);
      a[dr][i] = ok ? bf2f(ta[row + dr][x]) : 0.f;
      b[dr][i] = ok ? bf2f(tb[row + dr][x]) : 0.f;
    }
  bf16x8 res;
  #pragma unroll
  for (int j = 0; j < 8; ++j) {
    float s1 = 0.f, s2 = 0.f;
    #pragma unroll
    for (int dr = 0; dr < 3; ++dr)
      #pragma unroll
      for (int dx = 0; dx < 3; ++dx) {
        s1 += w1[dr * 3 + dx] * a[dr][j + dx];
        s2 += w2[dr * 3 + dx] * b[dr][j + dx];
      }
    float gl = 0.5f * s1 * (1.f + erff(s1 * 0.70710678118f));
    res[j] = (short)f2bf(gl * s2);
  }
  *(bf16x8*)(g + pbase + (y0 + row) * 128 + col0) = res;
}

// ---------------- row L2 norms (bf16 in) ----------------
__global__ __launch_bounds__(256) void rownorm_k(const u16* __restrict__ base, long bstride,
                                                 float* __restrict__ out) {
  int r = blockIdx.x, b = blockIdx.y, tid = threadIdx.x;
  const u16* src = base + (long)b * bstride + (long)r * N_PIX;
  float s = 0.f;
  #pragma unroll
  for (int j = 0; j < 8; ++j) {
    bf16x8 v = *(const bf16x8*)(src + j * 2048 + tid * 8);
    #pragma unroll
    for (int i = 0; i < 8; ++i) { float f = bf2f((u16)v[i]); s += f * f; }
  }
  float t = blockReduceSum256(s);
  if (tid == 0) out[b * 128 + r] = sqrtf(t);
}

// ---- attn partials: per 256-pixel chunk, 16x16 Gram ----
__global__ __launch_bounds__(256) void attn_part_k(const u16* __restrict__ q,
                                                   const u16* __restrict__ kbase,
                                                   long kbstride,
                                                   float* __restrict__ part) {
  int ch = blockIdx.x, h = blockIdx.y, b = blockIdx.z, tid = threadIdx.x;
  int n0 = ch * 256;
  __shared__ __align__(16) u16 qc[16][280];
  __shared__ __align__(16) u16 kc[16][280];
  #pragma unroll
  for (int j = 0; j < 2; ++j) {
    int v = tid + j * 256;
    int r = v >> 5, col = (v & 31) << 3;
    *(bf16x8*)&qc[r][col] = *(const bf16x8*)(q + ((long)b * 128 + h * 16 + r) * N_PIX + n0 + col);
    *(bf16x8*)&kc[r][col] = *(const bf16x8*)(kbase + (long)b * kbstride + (long)(h * 16 + r) * N_PIX + n0 + col);
  }
  __syncthreads();
  int c = tid >> 4, d = tid & 15;
  float acc = 0.f;
  #pragma unroll 4
  for (int nb = 0; nb < 32; ++nb) {
    bf16x8 qv = *(const bf16x8*)&qc[c][nb * 8];
    bf16x8 kv = *(const bf16x8*)&kc[d][nb * 8];
    #pragma unroll
    for (int i = 0; i < 8; ++i) acc += bf2f((u16)qv[i]) * bf2f((u16)kv[i]);
  }
  part[(long)((((b * 8 + h) * 16 + c) * 16 + d)) * 64 + ch] = acc;
}

// ---- reduce partials + cosine scaling ----
__global__ __launch_bounds__(256) void attn_reduce_k(const float* __restrict__ part,
                                                     const float* __restrict__ qn,
                                                     const float* __restrict__ kn,
                                                     const float* __restrict__ temp,
                                                     float* __restrict__ attnm) {
  int idx = blockIdx.x * 256 + threadIdx.x;
  const float* p = part + (long)idx * 64;
  float s = 0.f;
  #pragma unroll
  for (int j = 0; j < 64; ++j) s += p[j];
  int d = idx & 15, c = (idx >> 4) & 15, h = (idx >> 8) & 7, b = idx >> 11;
  float nq = fmaxf(qn[b * 128 + h * 16 + c], 1e-12f);
  float nk = fmaxf(kn[b * 128 + h * 16 + d], 1e-12f);
  attnm[idx] = s / (nq * nk) * temp[h];
}

// ---------------- top14 threshold + softmax + fold proj into Cmb[b,128,128] ----------------
__global__ __launch_bounds__(128) void score_cmb_k(const float* __restrict__ attnm,
                                                   const float* __restrict__ projw,
                                                   const float* __restrict__ attn4p,
                                                   float* __restrict__ cmb) {
  int b = blockIdx.x, tid = threadIdx.x;
  __shared__ float att_s[2048], score_s[2048];
  for (int i = tid; i < 2048; i += 128) att_s[i] = attnm[(long)b * 2048 + i];
  __syncthreads();
  {
    int h = tid >> 4, c = tid & 15;
    float v[16], t[16];
    #pragma unroll
    for (int d = 0; d < 16; ++d) { v[d] = att_s[(h * 16 + c) * 16 + d]; t[d] = v[d]; }
    float thr = 0.f, M = -1e30f;
    for (int it = 0; it < 14; ++it) {
      float m = -1e30f; int mi = 0;
      #pragma unroll
      for (int d = 0; d < 16; ++d) if (t[d] > m) { m = t[d]; mi = d; }
      if (it == 0) M = m;
      thr = m;
      t[mi] = -1e31f;
    }
    float s = 0.f, e[16];
    #pragma unroll
    for (int d = 0; d < 16; ++d) { e[d] = (v[d] >= thr) ? expf(v[d] - M) : 0.f; s += e[d]; }
    float inv = 1.f / s;
    #pragma unroll
    for (int d = 0; d < 16; ++d) score_s[(h * 16 + c) * 16 + d] = e[d] * inv;
  }
  __syncthreads();
  float a4 = attn4p[0];
  int o = tid;
  for (int hd = 0; hd < 128; ++hd) {
    int h = hd >> 4, d = hd & 15;
    float s = 0.f;
    #pragma unroll
    for (int c = 0; c < 16; ++c)
      s += projw[o * 128 + h * 16 + c] * score_s[(h * 16 + c) * 16 + d];
    cmb[((long)b * 128 + o) * 128 + hd] = a4 * s;
  }
}

extern "C" void kernel_launch(void* const* d_in, const int* in_sizes, int n_in,
                              void* d_out, int out_size, void* d_ws, size_t ws_size,
                              hipStream_t stream) {
  (void)in_sizes; (void)n_in; (void)out_size; (void)ws_size;
  const float* vi        = (const float*)d_in[0];
  const float* ir        = (const float*)d_in[1];
  const float* text_code = (const float*)d_in[2];
  const float* se_w1     = (const float*)d_in[3];
  const float* se_w2     = (const float*)d_in[4];
  const float* conv1x1_w = (const float*)d_in[5];
  const float* conv1x1_b = (const float*)d_in[6];
  const float* conv_out_w= (const float*)d_in[7];
  const float* conv_out_b= (const float*)d_in[8];
  const float* text_w1   = (const float*)d_in[9];
  const float* text_b1   = (const float*)d_in[10];
  const float* text_w2   = (const float*)d_in[11];
  const float* text_b2   = (const float*)d_in[12];
  const float* norm1_w   = (const float*)d_in[13];
  const float* norm1_b   = (const float*)d_in[14];
  const float* norm2_w   = (const float*)d_in[15];
  const float* norm2_b   = (const float*)d_in[16];
  const float* norm3_w   = (const float*)d_in[17];
  const float* norm3_b   = (const float*)d_in[18];
  const float* q_w       = (const float*)d_in[19];
  const float* q_dw_w    = (const float*)d_in[20];
  const float* kv_w      = (const float*)d_in[21];
  const float* kv_dw_w   = (const float*)d_in[22];
  const float* temperature = (const float*)d_in[23];
  const float* attn4     = (const float*)d_in[24];
  const float* proj_w    = (const float*)d_in[25];
  const float* ffn_in_w  = (const float*)d_in[26];
  const float* ffn_dw_w  = (const float*)d_in[27];
  const float* ffn_out_w = (const float*)d_in[28];
  float* out0 = (float*)d_out;
  float* out1 = out0 + NP;

  char* W = (char*)d_ws;
  float* sq_f  = (float*)(W + 0);
  int*   idx_i = (int*)(W + 4096);
  int*   sidx_i= (int*)(W + 6144);
  float* mcomb = (float*)(W + 12288);
  float* bcomb = (float*)(W + 536576);
  float* qn_f  = (float*)(W + 538624);
  float* kn_f  = (float*)(W + 540672);
  float* attnm = (float*)(W + 542720);
  float* cmb   = (float*)(W + 575488);
  float* t1f   = (float*)(W + 837632);
  float* tf_f  = (float*)(W + 845824);
  u16* S   = (u16*)(W + (1 << 20));       // arena 2048*N_PIX u16 (64 MiB)
  u16* CC  = S;                           // [0,512N): qin->xq->Q->x3
  u16* KD  = S + 512L * N_PIX;            // [512N,1024N): img2b->xkv -> ATT
  u16* CBF = S + 1024L * N_PIX;           // [1024N,2048N): concat bf16
  u16* QT  = S + 1024L * N_PIX;           // qt temp (CBF dead)
  u16* KVD = S + 1024L * N_PIX;           // K/V dw [4,256,N] (QT dead)
  u16* FT  = S + 1024L * N_PIX;           // FFN t [680N] (KVD dead)
  u16* FG  = S + 1704L * N_PIX;           // FFN g [340N]
  u16* KVT = (u16*)out0;                  // kv-proj temp [4,256,N] in out0 scratch
  u16* ATT = KD;

  const long SN = 128L * N_PIX;
  const long SN2 = 256L * N_PIX;

  squeeze_k<<<dim3(256, 4), 256, 0, stream>>>(vi, ir, sq_f, CBF);
  se_rank_k<<<4, 256, 0, stream>>>(sq_f, se_w1, se_w2, idx_i);
  text1_k<<<dim3(64, 4), 256, 0, stream>>>(text_code, text_w1, text_b1, t1f);
  text2_k<<<dim3(32, 4), 256, 0, stream>>>(t1f, text_w2, text_b2, tf_f);
  rank2_k<<<4, 256, 0, stream>>>(tf_f, sidx_i);
  mcomb_k<<<dim3(128, 4), 128, 0, stream>>>(conv_out_w, conv_out_b, conv1x1_w,
                                            conv1x1_b, idx_i, sidx_i, mcomb, bcomb);
  gemm_dual_k<<<dim3(256, 4), 256, 0, stream>>>(
      conv_out_w, conv_out_b, mcomb, bcomb, CBF, out1, KD, CC);
  ln_k<<<dim3(256, 4), 256, 0, stream>>>(CC, norm1_w, norm1_b, CC);          // xq
  ln_k<<<dim3(256, 4), 256, 0, stream>>>(KD, norm2_w, norm2_b, KD);          // xkv
  // Q path: qt -> QT, dw3 -> CC   (must finish before KVD overwrites [1024N..))
  gemm_k<0, 0, 0, 0, 2><<<dim3(256, 1, 4), 256, 0, stream>>>(
      q_w, 0, CC, SN, nullptr, 0, nullptr, 0, QT, SN, 128, 128);
  dw3t_k<<<4096, 256, 0, stream>>>(QT, q_dw_w, CC, 128);                     // Q=CC
  // KV path: one O=256 gemm -> KVT(out0), one dw3 C=256 -> KVD
  gemm_k<0, 0, 0, 0, 2><<<dim3(256, 2, 4), 256, 0, stream>>>(
      kv_w, 0, KD, SN, nullptr, 0, nullptr, 0, KVT, SN2, 256, 128);
  dw3t_k<<<8192, 256, 0, stream>>>(KVT, kv_dw_w, KVD, 256);                  // K,V
  rownorm_k<<<dim3(128, 4), 256, 0, stream>>>(CC, SN, qn_f);
  rownorm_k<<<dim3(128, 4), 256, 0, stream>>>(KVD, SN2, kn_f);               // K rows
  float* part = (float*)out0;   // 2 MB, KVT dead
  attn_part_k<<<dim3(64, 8, 4), 256, 0, stream>>>(CC, KVD, SN2, part);
  attn_reduce_k<<<32, 256, 0, stream>>>(part, qn_f, kn_f, temperature, attnm);
  score_cmb_k<<<4, 128, 0, stream>>>(attnm, proj_w, attn4, cmb);
  // att = Cmb_b @ V -> ATT (=KD slot)
  gemm_k<1, 0, 0, 0, 2><<<dim3(256, 1, 4), 256, 0, stream>>>(
      cmb, 128L * 128, KVD + SN, SN2, nullptr, 0, nullptr, 0, ATT, SN, 128, 128);
  ln_k<<<dim3(256, 4), 256, 0, stream>>>(ATT, norm3_w, norm3_b, CC);         // x3=CC
  // FFN per batch: one O=680 gemm -> FT, fused dw3+gelu -> FG, out-gemm + residual
  for (int b = 0; b < 4; ++b) {
    const u16* x3b = CC + (long)b * SN;
    gemm_k<0, 0, 0, 0, 2><<<dim3(256, 6, 1), 256, 0, stream>>>(
        ffn_in_w, 0, x3b, 0, nullptr, 0, nullptr, 0, FT, 0, 680, 128);
    dw3gelu_t_k<<<2720, 256, 0, stream>>>(FT, FT + 340L * N_PIX, ffn_dw_w, FG);
    gemm_k<0, 0, 1, 1, 2><<<dim3(256, 1, 1), 256, 0, stream>>>(
        ffn_out_w, 0, FG, 0, nullptr, 0, ATT + (long)b * SN, 0,
        out0 + (long)b * SN, 0, 128, 340);
  }
}

// Round 10
// 516.163 us; speedup vs baseline: 2.5661x; 1.0357x over previous
//
#include <hip/hip_runtime.h>

typedef unsigned short u16;
typedef __attribute__((ext_vector_type(8))) short bf16x8;
typedef __attribute__((ext_vector_type(4))) float f32x4;

#define N_PIX 16384
static constexpr long NP = 4L * 128 * N_PIX;   // elems in one [4,128,128,128]

__device__ __forceinline__ float bf2f(u16 h) {
  unsigned u = ((unsigned)h) << 16; float f; __builtin_memcpy(&f, &u, 4); return f;
}
__device__ __forceinline__ u16 f2bf(float f) {
  unsigned u; __builtin_memcpy(&u, &f, 4);
  u = (u + 0x7fffu + ((u >> 16) & 1u)) >> 16; return (u16)u;
}

__device__ __forceinline__ float blockReduceSum256(float v) {
  #pragma unroll
  for (int o = 32; o > 0; o >>= 1) v += __shfl_down(v, o, 64);
  __shared__ float sw[4];
  int lane = threadIdx.x & 63, w = threadIdx.x >> 6;
  if (lane == 0) sw[w] = v;
  __syncthreads();
  return (threadIdx.x == 0) ? (sw[0] + sw[1] + sw[2] + sw[3]) : 0.f;
}

// ---- squeeze: mean over HW of concat (f32 in) -> [4,256] f32 ; also emit bf16 concat ----
__global__ __launch_bounds__(256) void squeeze_k(const float* __restrict__ vi,
                                                 const float* __restrict__ ir,
                                                 float* __restrict__ sq,
                                                 u16* __restrict__ cbf) {
  int c = blockIdx.x, b = blockIdx.y, tid = threadIdx.x;
  const float* src = (c < 128) ? (vi + ((long)b * 128 + c) * N_PIX)
                               : (ir + ((long)b * 128 + (c - 128)) * N_PIX);
  const f32x4* src4 = (const f32x4*)src;
  u16* dst = cbf + ((long)b * 256 + c) * N_PIX;
  float s = 0.f;
  #pragma unroll
  for (int j = 0; j < 8; ++j) {
    f32x4 v0 = src4[j * 512 + tid * 2];
    f32x4 v1 = src4[j * 512 + tid * 2 + 1];
    s += v0.x + v0.y + v0.z + v0.w + v1.x + v1.y + v1.z + v1.w;
    bf16x8 r;
    r[0] = (short)f2bf(v0.x); r[1] = (short)f2bf(v0.y);
    r[2] = (short)f2bf(v0.z); r[3] = (short)f2bf(v0.w);
    r[4] = (short)f2bf(v1.x); r[5] = (short)f2bf(v1.y);
    r[6] = (short)f2bf(v1.z); r[7] = (short)f2bf(v1.w);
    *(bf16x8*)(dst + j * 2048 + tid * 8) = r;
  }
  float t = blockReduceSum256(s);
  if (tid == 0) sq[b * 256 + c] = t * (1.f / 16384.f);
}

// ---- SE MLP + top128 rank ----
__global__ __launch_bounds__(256) void se_rank_k(const float* __restrict__ sq,
                                                 const float* __restrict__ sew1,
                                                 const float* __restrict__ sew2,
                                                 int* __restrict__ idx) {
  int b = blockIdx.x, tid = threadIdx.x;
  __shared__ float s_sq[256], s_h1[32], s_cw[256];
  s_sq[tid] = sq[b * 256 + tid];
  __syncthreads();
  if (tid < 32) {
    float s = 0.f;
    for (int c = 0; c < 256; ++c) s += s_sq[c] * sew1[tid * 256 + c];
    s_h1[tid] = fmaxf(s, 0.f);
  }
  __syncthreads();
  {
    float s = 0.f;
    #pragma unroll
    for (int j = 0; j < 32; ++j) s += s_h1[j] * sew2[tid * 32 + j];
    s_cw[tid] = 1.f / (1.f + expf(-s));
  }
  __syncthreads();
  float my = s_cw[tid];
  int rk = 0;
  for (int c = 0; c < 256; ++c) {
    float o = s_cw[c];
    rk += (o > my) || (o == my && c < tid);
  }
  if (rk < 128) idx[b * 128 + rk] = tid;
}

// ---- text MLP layer1 ----
__global__ __launch_bounds__(256) void text1_k(const float* __restrict__ tc,
                                               const float* __restrict__ tw1,
                                               const float* __restrict__ tb1,
                                               float* __restrict__ t1f) {
  int b = blockIdx.y, j0 = blockIdx.x * 8, tid = threadIdx.x;
  __shared__ float s_tc[512];
  s_tc[tid] = tc[b * 512 + tid];
  s_tc[tid + 256] = tc[b * 512 + 256 + tid];
  __syncthreads();
  int w = tid >> 6, lane = tid & 63;
  #pragma unroll
  for (int r = 0; r < 2; ++r) {
    int j = j0 + w * 2 + r;
    const float* wr = tw1 + (long)j * 512;
    float s = 0.f;
    #pragma unroll
    for (int k = 0; k < 8; ++k) s += s_tc[lane + k * 64] * wr[lane + k * 64];
    #pragma unroll
    for (int o = 32; o > 0; o >>= 1) s += __shfl_down(s, o, 64);
    if (lane == 0) t1f[b * 512 + j] = fmaxf(s + tb1[j], 0.f);
  }
}

// ---- text MLP layer2 ----
__global__ __launch_bounds__(256) void text2_k(const float* __restrict__ t1f,
                                               const float* __restrict__ tw2,
                                               const float* __restrict__ tb2,
                                               float* __restrict__ tf) {
  int b = blockIdx.y, j0 = blockIdx.x * 8, tid = threadIdx.x;
  __shared__ float s_t1[512];
  s_t1[tid] = t1f[b * 512 + tid];
  s_t1[tid + 256] = t1f[b * 512 + 256 + tid];
  __syncthreads();
  int w = tid >> 6, lane = tid & 63;
  #pragma unroll
  for (int r = 0; r < 2; ++r) {
    int j = j0 + w * 2 + r;
    const float* wr = tw2 + (long)j * 512;
    float s = 0.f;
    #pragma unroll
    for (int k = 0; k < 8; ++k) s += s_t1[lane + k * 64] * wr[lane + k * 64];
    #pragma unroll
    for (int o = 32; o > 0; o >>= 1) s += __shfl_down(s, o, 64);
    if (lane == 0) tf[b * 256 + j] = s + tb2[j];
  }
}

// ---- argsort-rank of tf -> sidx ----
__global__ __launch_bounds__(256) void rank2_k(const float* __restrict__ tf,
                                               int* __restrict__ sidx) {
  int b = blockIdx.x, tid = threadIdx.x;
  __shared__ float s_tf[256];
  s_tf[tid] = tf[b * 256 + tid];
  __syncthreads();
  float my = s_tf[tid];
  int rk = 0;
  for (int c = 0; c < 256; ++c) {
    float o = s_tf[c];
    rk += (o > my) || (o == my && c < tid);
  }
  sidx[b * 256 + rk] = tid;
}

// ---------------- fold conv1x1 + shuffle + conv_out + select into M_b[128,256] ----------------
__global__ __launch_bounds__(128) void mcomb_k(const float* __restrict__ w2,
                                               const float* __restrict__ w2b,
                                               const float* __restrict__ w1,
                                               const float* __restrict__ w1b,
                                               const int* __restrict__ idx,
                                               const int* __restrict__ sidx,
                                               float* __restrict__ mcomb,
                                               float* __restrict__ bcomb) {
  int o = blockIdx.x, b = blockIdx.y, tid = threadIdx.x;
  __shared__ float s_w2[256];
  __shared__ int s_sx[256];
  s_w2[tid] = w2[o * 256 + tid];
  s_w2[tid + 128] = w2[o * 256 + tid + 128];
  s_sx[tid] = sidx[b * 256 + tid] & 255;
  s_sx[tid + 128] = sidx[b * 256 + tid + 128] & 255;
  float* mrow = mcomb + ((long)b * 128 + o) * 256;
  mrow[tid] = 0.f;
  mrow[tid + 128] = 0.f;
  __syncthreads();
  float s = 0.f;
  for (int j = 0; j < 256; ++j) s += s_w2[j] * w1[s_sx[j] * 128 + tid];
  int cc = idx[b * 128 + tid] & 255;
  mrow[cc] = s;
  if (tid == 0) {
    float bb = w2b[o];
    for (int j = 0; j < 256; ++j) bb += s_w2[j] * w1b[s_sx[j]];
    bcomb[b * 128 + o] = bb;
  }
}

// ---- fused dual GEMM (128-row o-tile); X staged via per-row k-gather (no LDS scatter) ----
__global__ __launch_bounds__(256) void gemm_dual_k(
    const float* __restrict__ W2, const float* __restrict__ b2,
    const float* __restrict__ Mc, const float* __restrict__ bc,
    const u16* __restrict__ Xb,
    float* __restrict__ out1, u16* __restrict__ img2b, u16* __restrict__ qin) {
  const int N = N_PIX;
  int n0 = blockIdx.x * 64, bz = blockIdx.y, tid = threadIdx.x;
  __shared__ __align__(16) u16 A1[128][40];
  __shared__ __align__(16) u16 A2h[128][40];
  __shared__ __align__(16) u16 A2l[128][40];
  __shared__ __align__(16) u16 Xs[64][40];
  f32x4 acc1[2][4], acc2[2][4];
  #pragma unroll
  for (int ot = 0; ot < 2; ++ot)
    #pragma unroll
    for (int i = 0; i < 4; ++i) { acc1[ot][i] = (f32x4){0,0,0,0}; acc2[ot][i] = (f32x4){0,0,0,0}; }
  int wv = tid >> 6, lane = tid & 63;
  int lr = lane & 15, lk = (lane >> 4) * 8;
  for (int kt = 0; kt < 8; ++kt) {
    int k0 = kt << 5;
    #pragma unroll
    for (int ot = 0; ot < 2; ++ot) {
      int r = (tid >> 2) + ot * 64, cb = (tid & 3) << 3;
      const float* a1p = W2 + (long)r * 256 + k0 + cb;
      f32x4 u0 = *(const f32x4*)a1p, u1 = *(const f32x4*)(a1p + 4);
      float a1v[8] = {u0.x, u0.y, u0.z, u0.w, u1.x, u1.y, u1.z, u1.w};
      const float* a2p = Mc + ((long)bz * 128 + r) * 256 + k0 + cb;
      f32x4 v0 = *(const f32x4*)a2p, v1 = *(const f32x4*)(a2p + 4);
      float av[8] = {v0.x, v0.y, v0.z, v0.w, v1.x, v1.y, v1.z, v1.w};
      bf16x8 w1v, whv, wlv;
      #pragma unroll
      for (int i = 0; i < 8; ++i) {
        w1v[i] = (short)f2bf(a1v[i]);
        u16 hi = f2bf(av[i]);
        whv[i] = (short)hi;
        wlv[i] = (short)f2bf(av[i] - bf2f(hi));
      }
      *(bf16x8*)&A1[r][cb] = w1v;
      *(bf16x8*)&A2h[r][cb] = whv;
      *(bf16x8*)&A2l[r][cb] = wlv;
    }
    {
      int n = tid & 63, kb = (tid >> 6) << 3;
      const u16* src = Xb + ((long)bz * 256 + k0 + kb) * N + n0 + n;
      bf16x8 t;
      #pragma unroll
      for (int i = 0; i < 8; ++i) t[i] = (short)src[(long)i * N];
      *(bf16x8*)&Xs[n][kb] = t;
    }
    __syncthreads();
    bf16x8 bfr[4];
    #pragma unroll
    for (int nt = 0; nt < 4; ++nt) bfr[nt] = *(const bf16x8*)&Xs[nt * 16 + lr][lk];
    #pragma unroll
    for (int ot = 0; ot < 2; ++ot) {
      bf16x8 a1 = *(const bf16x8*)&A1[ot * 64 + wv * 16 + lr][lk];
      bf16x8 a2h = *(const bf16x8*)&A2h[ot * 64 + wv * 16 + lr][lk];
      bf16x8 a2l = *(const bf16x8*)&A2l[ot * 64 + wv * 16 + lr][lk];
      #pragma unroll
      for (int nt = 0; nt < 4; ++nt) {
        acc1[ot][nt] = __builtin_amdgcn_mfma_f32_16x16x32_bf16(a1, bfr[nt], acc1[ot][nt], 0, 0, 0);
        acc2[ot][nt] = __builtin_amdgcn_mfma_f32_16x16x32_bf16(a2h, bfr[nt], acc2[ot][nt], 0, 0, 0);
        acc2[ot][nt] = __builtin_amdgcn_mfma_f32_16x16x32_bf16(a2l, bfr[nt], acc2[ot][nt], 0, 0, 0);
      }
    }
    __syncthreads();
  }
  #pragma unroll
  for (int ot = 0; ot < 2; ++ot)
    #pragma unroll
    for (int nt = 0; nt < 4; ++nt)
      #pragma unroll
      for (int r4 = 0; r4 < 4; ++r4) {
        int o = ot * 64 + wv * 16 + (lane >> 4) * 4 + r4;
        int n = n0 + nt * 16 + (lane & 15);
        long oi = ((long)bz * 128 + o) * N + n;
        float v1 = acc1[ot][nt][r4] + b2[o];
        out1[oi] = v1;
        img2b[oi] = f2bf(v1);
        qin[oi] = f2bf(acc2[ot][nt][r4] + bc[bz * 128 + o]);
      }
}

// ---------------- generic MFMA GEMM, OT o-tiles; X staged via per-row k-gather ----------------
template<int AMODE, int BIAS, int RESADD, int OUTF, int OT>
__global__ __launch_bounds__(256) void gemm_k(
    const float* __restrict__ Aw, long a_bstride,
    const u16* __restrict__ X, long x_bstride,
    const float* __restrict__ bias, long bias_bstride,
    const u16* __restrict__ res, long res_bstride,
    void* __restrict__ outv, long out_bstride,
    int O, int K) {
  const int N = N_PIX;
  int n0 = blockIdx.x * 64;
  int o0 = blockIdx.y * 64 * OT;
  int bz = blockIdx.z;
  int tid = threadIdx.x;
  __shared__ __align__(16) u16 As[64 * OT][40];
  __shared__ __align__(16) u16 Al[AMODE ? 64 * OT : 1][40];
  __shared__ __align__(16) u16 Xs[64][40];
  f32x4 acc[OT][4];
  #pragma unroll
  for (int ot = 0; ot < OT; ++ot)
    #pragma unroll
    for (int i = 0; i < 4; ++i) acc[ot][i] = (f32x4){0.f, 0.f, 0.f, 0.f};
  int wv = tid >> 6, lane = tid & 63;
  int lr = lane & 15, lk = (lane >> 4) * 8;
  int nk = (K + 31) >> 5;
  for (int kt = 0; kt < nk; ++kt) {
    int k0 = kt << 5;
    #pragma unroll
    for (int ot = 0; ot < OT; ++ot) {
      int r = (tid >> 2) + ot * 64, cb = (tid & 3) << 3;
      int o = o0 + r;
      if (AMODE == 0) {
        bf16x8 wv8;
        if (o < O && (k0 + cb + 8 <= K)) {
          const float* ap = Aw + (long)o * K + k0 + cb;
          f32x4 v0 = *(const f32x4*)ap;
          f32x4 v1 = *(const f32x4*)(ap + 4);
          float av[8] = {v0.x, v0.y, v0.z, v0.w, v1.x, v1.y, v1.z, v1.w};
          #pragma unroll
          for (int i = 0; i < 8; ++i) wv8[i] = (short)f2bf(av[i]);
        } else {
          #pragma unroll
          for (int i = 0; i < 8; ++i) {
            int k = k0 + cb + i;
            wv8[i] = (short)((o < O && k < K) ? f2bf(Aw[(long)o * K + k]) : (u16)0);
          }
        }
        *(bf16x8*)&As[r][cb] = wv8;
      } else {
        bf16x8 hv, lv;
        #pragma unroll
        for (int i = 0; i < 8; ++i) {
          int k = k0 + cb + i;
          float av = (o < O && k < K) ? Aw[(long)bz * a_bstride + (long)o * K + k] : 0.f;
          u16 hi = f2bf(av);
          hv[i] = (short)hi;
          lv[i] = (short)f2bf(av - bf2f(hi));
        }
        *(bf16x8*)&As[r][cb] = hv;
        *(bf16x8*)&Al[r][cb] = lv;
      }
    }
    {
      int n = tid & 63, kb = (tid >> 6) << 3;
      int k = k0 + kb;
      const u16* src = X + (long)bz * x_bstride + n0 + n;
      bf16x8 t;
      #pragma unroll
      for (int i = 0; i < 8; ++i)
        t[i] = (short)((k + i < K) ? src[(long)(k + i) * N] : (u16)0);
      *(bf16x8*)&Xs[n][kb] = t;
    }
    __syncthreads();
    bf16x8 bfr[4];
    #pragma unroll
    for (int nt = 0; nt < 4; ++nt) bfr[nt] = *(const bf16x8*)&Xs[nt * 16 + lr][lk];
    #pragma unroll
    for (int ot = 0; ot < OT; ++ot) {
      bf16x8 afr = *(const bf16x8*)&As[ot * 64 + wv * 16 + lr][lk];
      bf16x8 alr;
      if (AMODE == 1) alr = *(const bf16x8*)&Al[ot * 64 + wv * 16 + lr][lk];
      #pragma unroll
      for (int nt = 0; nt < 4; ++nt) {
        acc[ot][nt] = __builtin_amdgcn_mfma_f32_16x16x32_bf16(afr, bfr[nt], acc[ot][nt], 0, 0, 0);
        if (AMODE == 1)
          acc[ot][nt] = __builtin_amdgcn_mfma_f32_16x16x32_bf16(alr, bfr[nt], acc[ot][nt], 0, 0, 0);
      }
    }
    __syncthreads();
  }
  #pragma unroll
  for (int ot = 0; ot < OT; ++ot)
    #pragma unroll
    for (int nt = 0; nt < 4; ++nt)
      #pragma unroll
      for (int r4 = 0; r4 < 4; ++r4) {
        int o = o0 + ot * 64 + wv * 16 + (lane >> 4) * 4 + r4;
        int n = n0 + nt * 16 + (lane & 15);
        if (o < O) {
          float v = acc[ot][nt][r4];
          if (BIAS == 1) v += bias[o];
          if (BIAS == 2) v += bias[(long)bz * bias_bstride + o];
          if (RESADD) v += bf2f(res[(long)bz * res_bstride + (long)o * N + n]);
          long oi = (long)bz * out_bstride + (long)o * N + n;
          if (OUTF) ((float*)outv)[oi] = v;
          else ((u16*)outv)[oi] = f2bf(v);
        }
      }
}

// ---------------- LayerNorm over channel dim (C=128), bf16 in ----------------
__global__ __launch_bounds__(256) void ln_k(const u16* __restrict__ in,
                                            const float* __restrict__ gamma,
                                            const float* __restrict__ beta,
                                            u16* __restrict__ out) {
  int p0 = blockIdx.x * 64, b = blockIdx.y, tid = threadIdx.x;
  int px = tid & 63, g4 = tid >> 6;
  __shared__ float tile[128][65];
  __shared__ float red[8][64];
  __shared__ float gmm[128], bta[128], mu_s[64], rs_s[64];
  if (tid < 128) { gmm[tid] = gamma[tid]; bta[tid] = beta[tid]; }
  long bofs = (long)b * 128 * N_PIX;
  float s = 0.f;
  for (int c = g4; c < 128; c += 4) {
    float v = bf2f(in[bofs + (long)c * N_PIX + p0 + px]);
    tile[c][px] = v;
    s += v;
  }
  red[g4][px] = s;
  __syncthreads();
  if (g4 == 0) mu_s[px] = (red[0][px] + red[1][px] + red[2][px] + red[3][px]) * (1.f / 128.f);
  __syncthreads();
  float mu = mu_s[px];
  float s2 = 0.f;
  for (int c = g4; c < 128; c += 4) { float d = tile[c][px] - mu; s2 += d * d; }
  red[4 + g4][px] = s2;
  __syncthreads();
  if (g4 == 0) {
    float var = (red[4][px] + red[5][px] + red[6][px] + red[7][px]) * (1.f / 128.f);
    rs_s[px] = rsqrtf(var + 1e-5f);
  }
  __syncthreads();
  float rs = rs_s[px];
  for (int c = g4; c < 128; c += 4)
    out[bofs + (long)c * N_PIX + p0 + px] = f2bf((tile[c][px] - mu) * rs * gmm[c] + bta[c]);
}

// ---- LDS-tiled depthwise 3x3 ----
__global__ __launch_bounds__(256) void dw3t_k(const u16* __restrict__ in,
                                              const float* __restrict__ w,
                                              u16* __restrict__ out, int C) {
  int plane = blockIdx.x >> 3, stripe = blockIdx.x & 7, tid = threadIdx.x;
  int c = plane % C;
  long pbase = (long)plane * N_PIX;
  int y0 = stripe * 16;
  __shared__ __align__(16) u16 tile[18][136];
  for (int v = tid; v < 288; v += 256) {
    int r = v >> 4, col = (v & 15) << 3;
    int y = y0 - 1 + r;
    bf16x8 t;
    #pragma unroll
    for (int i = 0; i < 8; ++i) t[i] = 0;
    if (y >= 0 && y < 128) t = *(const bf16x8*)(in + pbase + y * 128 + col);
    *(bf16x8*)&tile[r][col] = t;
  }
  float wv[9];
  #pragma unroll
  for (int j = 0; j < 9; ++j) wv[j] = w[c * 9 + j];
  __syncthreads();
  int row = tid >> 4, col0 = (tid & 15) << 3;
  float a[3][10];
  #pragma unroll
  for (int dr = 0; dr < 3; ++dr)
    #pragma unroll
    for (int i = 0; i < 10; ++i) {
      int x = col0 - 1 + i;
      a[dr][i] = (x >= 0 && x < 128) ? bf2f(tile[row + dr][x]) : 0.f;
    }
  bf16x8 res;
  #pragma unroll
  for (int j = 0; j < 8; ++j) {
    float s = 0.f;
    #pragma unroll
    for (int dr = 0; dr < 3; ++dr)
      #pragma unroll
      for (int dx = 0; dx < 3; ++dx) s += wv[dr * 3 + dx] * a[dr][j + dx];
    res[j] = (short)f2bf(s);
  }
  *(bf16x8*)(out + pbase + (y0 + row) * 128 + col0) = res;
}

// ---- LDS-tiled fused FFN tail: g = gelu(dw3(t1)) * dw3(t2), 340 planes ----
__global__ __launch_bounds__(256) void dw3gelu_t_k(const u16* __restrict__ t1,
                                                   const u16* __restrict__ t2,
                                                   const float* __restrict__ w,
                                                   u16* __restrict__ g) {
  int plane = blockIdx.x >> 3, stripe = blockIdx.x & 7, tid = threadIdx.x;
  long pbase = (long)plane * N_PIX;
  int y0 = stripe * 16;
  __shared__ __align__(16) u16 ta[18][136];
  __shared__ __align__(16) u16 tb[18][136];
  for (int v = tid; v < 288; v += 256) {
    int r = v >> 4, col = (v & 15) << 3;
    int y = y0 - 1 + r;
    bf16x8 u1, u2;
    #pragma unroll
    for (int i = 0; i < 8; ++i) { u1[i] = 0; u2[i] = 0; }
    if (y >= 0 && y < 128) {
      u1 = *(const bf16x8*)(t1 + pbase + y * 128 + col);
      u2 = *(const bf16x8*)(t2 + pbase + y * 128 + col);
    }
    *(bf16x8*)&ta[r][col] = u1;
    *(bf16x8*)&tb[r][col] = u2;
  }
  float w1[9], w2[9];
  #pragma unroll
  for (int j = 0; j < 9; ++j) { w1[j] = w[plane * 9 + j]; w2[j] = w[(340 + plane) * 9 + j]; }
  __syncthreads();
  int row = tid >> 4, col0 = (tid & 15) << 3;
  float a[3][10], b[3][10];
  #pragma unroll
  for (int dr = 0; dr < 3; ++dr)
    #pragma unroll
    for (int i = 0; i < 10; ++i) {
      int x = col0 - 1 + i;
      bool ok = (x >= 0 && x < 128);
      a[dr][i] = ok ? bf2f(ta[row + dr][x]) : 0.f;
      b[dr][i] = ok ? bf2f(tb[row + dr][x]) : 0.f;
    }
  bf16x8 res;
  #pragma unroll
  for (int j = 0; j < 8; ++j) {
    float s1 = 0.f, s2 = 0.f;
    #pragma unroll
    for (int dr = 0; dr < 3; ++dr)
      #pragma unroll
      for (int dx = 0; dx < 3; ++dx) {
        s1 += w1[dr * 3 + dx] * a[dr][j + dx];
        s2 += w2[dr * 3 + dx] * b[dr][j + dx];
      }
    float gl = 0.5f * s1 * (1.f + erff(s1 * 0.70710678118f));
    res[j] = (short)f2bf(gl * s2);
  }
  *(bf16x8*)(g + pbase + (y0 + row) * 128 + col0) = res;
}

// ---------------- row L2 norms (bf16 in) ----------------
__global__ __launch_bounds__(256) void rownorm_k(const u16* __restrict__ base, long bstride,
                                                 float* __restrict__ out) {
  int r = blockIdx.x, b = blockIdx.y, tid = threadIdx.x;
  const u16* src = base + (long)b * bstride + (long)r * N_PIX;
  float s = 0.f;
  #pragma unroll
  for (int j = 0; j < 8; ++j) {
    bf16x8 v = *(const bf16x8*)(src + j * 2048 + tid * 8);
    #pragma unroll
    for (int i = 0; i < 8; ++i) { float f = bf2f((u16)v[i]); s += f * f; }
  }
  float t = blockReduceSum256(s);
  if (tid == 0) out[b * 128 + r] = sqrtf(t);
}

// ---- attn partials: per 256-pixel chunk, 16x16 Gram ----
__global__ __launch_bounds__(256) void attn_part_k(const u16* __restrict__ q,
                                                   const u16* __restrict__ kbase,
                                                   long kbstride,
                                                   float* __restrict__ part) {
  int ch = blockIdx.x, h = blockIdx.y, b = blockIdx.z, tid = threadIdx.x;
  int n0 = ch * 256;
  __shared__ __align__(16) u16 qc[16][280];
  __shared__ __align__(16) u16 kc[16][280];
  #pragma unroll
  for (int j = 0; j < 2; ++j) {
    int v = tid + j * 256;
    int r = v >> 5, col = (v & 31) << 3;
    *(bf16x8*)&qc[r][col] = *(const bf16x8*)(q + ((long)b * 128 + h * 16 + r) * N_PIX + n0 + col);
    *(bf16x8*)&kc[r][col] = *(const bf16x8*)(kbase + (long)b * kbstride + (long)(h * 16 + r) * N_PIX + n0 + col);
  }
  __syncthreads();
  int c = tid >> 4, d = tid & 15;
  float acc = 0.f;
  #pragma unroll 4
  for (int nb = 0; nb < 32; ++nb) {
    bf16x8 qv = *(const bf16x8*)&qc[c][nb * 8];
    bf16x8 kv = *(const bf16x8*)&kc[d][nb * 8];
    #pragma unroll
    for (int i = 0; i < 8; ++i) acc += bf2f((u16)qv[i]) * bf2f((u16)kv[i]);
  }
  part[(long)((((b * 8 + h) * 16 + c) * 16 + d)) * 64 + ch] = acc;
}

// ---- reduce partials + cosine scaling ----
__global__ __launch_bounds__(256) void attn_reduce_k(const float* __restrict__ part,
                                                     const float* __restrict__ qn,
                                                     const float* __restrict__ kn,
                                                     const float* __restrict__ temp,
                                                     float* __restrict__ attnm) {
  int idx = blockIdx.x * 256 + threadIdx.x;
  const float* p = part + (long)idx * 64;
  float s = 0.f;
  #pragma unroll
  for (int j = 0; j < 64; ++j) s += p[j];
  int d = idx & 15, c = (idx >> 4) & 15, h = (idx >> 8) & 7, b = idx >> 11;
  float nq = fmaxf(qn[b * 128 + h * 16 + c], 1e-12f);
  float nk = fmaxf(kn[b * 128 + h * 16 + d], 1e-12f);
  attnm[idx] = s / (nq * nk) * temp[h];
}

// ---------------- top14 threshold + softmax + fold proj into Cmb[b,128,128] ----------------
__global__ __launch_bounds__(128) void score_cmb_k(const float* __restrict__ attnm,
                                                   const float* __restrict__ projw,
                                                   const float* __restrict__ attn4p,
                                                   float* __restrict__ cmb) {
  int b = blockIdx.x, tid = threadIdx.x;
  __shared__ float att_s[2048], score_s[2048];
  for (int i = tid; i < 2048; i += 128) att_s[i] = attnm[(long)b * 2048 + i];
  __syncthreads();
  {
    int h = tid >> 4, c = tid & 15;
    float v[16], t[16];
    #pragma unroll
    for (int d = 0; d < 16; ++d) { v[d] = att_s[(h * 16 + c) * 16 + d]; t[d] = v[d]; }
    float thr = 0.f, M = -1e30f;
    for (int it = 0; it < 14; ++it) {
      float m = -1e30f; int mi = 0;
      #pragma unroll
      for (int d = 0; d < 16; ++d) if (t[d] > m) { m = t[d]; mi = d; }
      if (it == 0) M = m;
      thr = m;
      t[mi] = -1e31f;
    }
    float s = 0.f, e[16];
    #pragma unroll
    for (int d = 0; d < 16; ++d) { e[d] = (v[d] >= thr) ? expf(v[d] - M) : 0.f; s += e[d]; }
    float inv = 1.f / s;
    #pragma unroll
    for (int d = 0; d < 16; ++d) score_s[(h * 16 + c) * 16 + d] = e[d] * inv;
  }
  __syncthreads();
  float a4 = attn4p[0];
  int o = tid;
  for (int hd = 0; hd < 128; ++hd) {
    int h = hd >> 4, d = hd & 15;
    float s = 0.f;
    #pragma unroll
    for (int c = 0; c < 16; ++c)
      s += projw[o * 128 + h * 16 + c] * score_s[(h * 16 + c) * 16 + d];
    cmb[((long)b * 128 + o) * 128 + hd] = a4 * s;
  }
}

extern "C" void kernel_launch(void* const* d_in, const int* in_sizes, int n_in,
                              void* d_out, int out_size, void* d_ws, size_t ws_size,
                              hipStream_t stream) {
  (void)in_sizes; (void)n_in; (void)out_size; (void)ws_size;
  const float* vi        = (const float*)d_in[0];
  const float* ir        = (const float*)d_in[1];
  const float* text_code = (const float*)d_in[2];
  const float* se_w1     = (const float*)d_in[3];
  const float* se_w2     = (const float*)d_in[4];
  const float* conv1x1_w = (const float*)d_in[5];
  const float* conv1x1_b = (const float*)d_in[6];
  const float* conv_out_w= (const float*)d_in[7];
  const float* conv_out_b= (const float*)d_in[8];
  const float* text_w1   = (const float*)d_in[9];
  const float* text_b1   = (const float*)d_in[10];
  const float* text_w2   = (const float*)d_in[11];
  const float* text_b2   = (const float*)d_in[12];
  const float* norm1_w   = (const float*)d_in[13];
  const float* norm1_b   = (const float*)d_in[14];
  const float* norm2_w   = (const float*)d_in[15];
  const float* norm2_b   = (const float*)d_in[16];
  const float* norm3_w   = (const float*)d_in[17];
  const float* norm3_b   = (const float*)d_in[18];
  const float* q_w       = (const float*)d_in[19];
  const float* q_dw_w    = (const float*)d_in[20];
  const float* kv_w      = (const float*)d_in[21];
  const float* kv_dw_w   = (const float*)d_in[22];
  const float* temperature = (const float*)d_in[23];
  const float* attn4     = (const float*)d_in[24];
  const float* proj_w    = (const float*)d_in[25];
  const float* ffn_in_w  = (const float*)d_in[26];
  const float* ffn_dw_w  = (const float*)d_in[27];
  const float* ffn_out_w = (const float*)d_in[28];
  float* out0 = (float*)d_out;
  float* out1 = out0 + NP;

  char* W = (char*)d_ws;
  float* sq_f  = (float*)(W + 0);
  int*   idx_i = (int*)(W + 4096);
  int*   sidx_i= (int*)(W + 6144);
  float* mcomb = (float*)(W + 12288);
  float* bcomb = (float*)(W + 536576);
  float* qn_f  = (float*)(W + 538624);
  float* kn_f  = (float*)(W + 540672);
  float* attnm = (float*)(W + 542720);
  float* cmb   = (float*)(W + 575488);
  float* t1f   = (float*)(W + 837632);
  float* tf_f  = (float*)(W + 845824);
  u16* S   = (u16*)(W + (1 << 20));       // arena 2048*N_PIX u16 (64 MiB)
  u16* CC  = S;                           // [0,512N): qin->xq->Q->x3
  u16* KD  = S + 512L * N_PIX;            // [512N,1024N): img2b->xkv -> ATT
  u16* CBF = S + 1024L * N_PIX;           // [1024N,2048N): concat bf16
  u16* QT  = S + 1024L * N_PIX;           // qt temp (CBF dead)
  u16* KVD = S + 1024L * N_PIX;           // K/V dw [4,256,N] (QT dead)
  u16* FT  = S + 1024L * N_PIX;           // FFN t [680N] (KVD dead)
  u16* FG  = S + 1704L * N_PIX;           // FFN g [340N]
  u16* KVT = (u16*)out0;                  // kv-proj temp [4,256,N] in out0 scratch
  u16* ATT = KD;

  const long SN = 128L * N_PIX;
  const long SN2 = 256L * N_PIX;

  squeeze_k<<<dim3(256, 4), 256, 0, stream>>>(vi, ir, sq_f, CBF);
  se_rank_k<<<4, 256, 0, stream>>>(sq_f, se_w1, se_w2, idx_i);
  text1_k<<<dim3(64, 4), 256, 0, stream>>>(text_code, text_w1, text_b1, t1f);
  text2_k<<<dim3(32, 4), 256, 0, stream>>>(t1f, text_w2, text_b2, tf_f);
  rank2_k<<<4, 256, 0, stream>>>(tf_f, sidx_i);
  mcomb_k<<<dim3(128, 4), 128, 0, stream>>>(conv_out_w, conv_out_b, conv1x1_w,
                                            conv1x1_b, idx_i, sidx_i, mcomb, bcomb);
  gemm_dual_k<<<dim3(256, 4), 256, 0, stream>>>(
      conv_out_w, conv_out_b, mcomb, bcomb, CBF, out1, KD, CC);
  ln_k<<<dim3(256, 4), 256, 0, stream>>>(CC, norm1_w, norm1_b, CC);          // xq
  ln_k<<<dim3(256, 4), 256, 0, stream>>>(KD, norm2_w, norm2_b, KD);          // xkv
  // Q path: qt -> QT, dw3 -> CC
  gemm_k<0, 0, 0, 0, 2><<<dim3(256, 1, 4), 256, 0, stream>>>(
      q_w, 0, CC, SN, nullptr, 0, nullptr, 0, QT, SN, 128, 128);
  dw3t_k<<<4096, 256, 0, stream>>>(QT, q_dw_w, CC, 128);                     // Q=CC
  // KV path: one O=256 gemm -> KVT(out0), one dw3 C=256 -> KVD
  gemm_k<0, 0, 0, 0, 2><<<dim3(256, 2, 4), 256, 0, stream>>>(
      kv_w, 0, KD, SN, nullptr, 0, nullptr, 0, KVT, SN2, 256, 128);
  dw3t_k<<<8192, 256, 0, stream>>>(KVT, kv_dw_w, KVD, 256);                  // K,V
  rownorm_k<<<dim3(128, 4), 256, 0, stream>>>(CC, SN, qn_f);
  rownorm_k<<<dim3(128, 4), 256, 0, stream>>>(KVD, SN2, kn_f);               // K rows
  float* part = (float*)out0;   // 2 MB, KVT dead
  attn_part_k<<<dim3(64, 8, 4), 256, 0, stream>>>(CC, KVD, SN2, part);
  attn_reduce_k<<<32, 256, 0, stream>>>(part, qn_f, kn_f, temperature, attnm);
  score_cmb_k<<<4, 128, 0, stream>>>(attnm, proj_w, attn4, cmb);
  // att = Cmb_b @ V -> ATT (=KD slot)
  gemm_k<1, 0, 0, 0, 2><<<dim3(256, 1, 4), 256, 0, stream>>>(
      cmb, 128L * 128, KVD + SN, SN2, nullptr, 0, nullptr, 0, ATT, SN, 128, 128);
  ln_k<<<dim3(256, 4), 256, 0, stream>>>(ATT, norm3_w, norm3_b, CC);         // x3=CC
  // FFN per batch
  for (int b = 0; b < 4; ++b) {
    const u16* x3b = CC + (long)b * SN;
    gemm_k<0, 0, 0, 0, 2><<<dim3(256, 6, 1), 256, 0, stream>>>(
        ffn_in_w, 0, x3b, 0, nullptr, 0, nullptr, 0, FT, 0, 680, 128);
    dw3gelu_t_k<<<2720, 256, 0, stream>>>(FT, FT + 340L * N_PIX, ffn_dw_w, FG);
    gemm_k<0, 0, 1, 1, 2><<<dim3(256, 1, 1), 256, 0, stream>>>(
        ffn_out_w, 0, FG, 0, nullptr, 0, ATT + (long)b * SN, 0,
        out0 + (long)b * SN, 0, 128, 340);
  }
}

// Round 11
// 499.542 us; speedup vs baseline: 2.6515x; 1.0333x over previous
//
#include <hip/hip_runtime.h>

typedef unsigned short u16;
typedef __attribute__((ext_vector_type(8))) short bf16x8;
typedef __attribute__((ext_vector_type(4))) float f32x4;

#define N_PIX 16384
static constexpr long NP = 4L * 128 * N_PIX;   // elems in one [4,128,128,128]

__device__ __forceinline__ float bf2f(u16 h) {
  unsigned u = ((unsigned)h) << 16; float f; __builtin_memcpy(&f, &u, 4); return f;
}
__device__ __forceinline__ u16 f2bf(float f) {
  unsigned u; __builtin_memcpy(&u, &f, 4);
  u = (u + 0x7fffu + ((u >> 16) & 1u)) >> 16; return (u16)u;
}

__device__ __forceinline__ float blockReduceSum256(float v) {
  #pragma unroll
  for (int o = 32; o > 0; o >>= 1) v += __shfl_down(v, o, 64);
  __shared__ float sw[4];
  int lane = threadIdx.x & 63, w = threadIdx.x >> 6;
  if (lane == 0) sw[w] = v;
  __syncthreads();
  return (threadIdx.x == 0) ? (sw[0] + sw[1] + sw[2] + sw[3]) : 0.f;
}

// ---- weight f32 -> bf16 copy ----
__global__ __launch_bounds__(256) void wconv_k(const float* __restrict__ a,
                                               u16* __restrict__ o, long n) {
  long i = (long)blockIdx.x * 256 + threadIdx.x;
  if (i < n) o[i] = f2bf(a[i]);
}

// ---- squeeze: mean over HW of concat (f32 in) -> [4,256] f32 ; also emit bf16 concat ----
__global__ __launch_bounds__(256) void squeeze_k(const float* __restrict__ vi,
                                                 const float* __restrict__ ir,
                                                 float* __restrict__ sq,
                                                 u16* __restrict__ cbf) {
  int c = blockIdx.x, b = blockIdx.y, tid = threadIdx.x;
  const float* src = (c < 128) ? (vi + ((long)b * 128 + c) * N_PIX)
                               : (ir + ((long)b * 128 + (c - 128)) * N_PIX);
  const f32x4* src4 = (const f32x4*)src;
  u16* dst = cbf + ((long)b * 256 + c) * N_PIX;
  float s = 0.f;
  #pragma unroll
  for (int j = 0; j < 8; ++j) {
    f32x4 v0 = src4[j * 512 + tid * 2];
    f32x4 v1 = src4[j * 512 + tid * 2 + 1];
    s += v0.x + v0.y + v0.z + v0.w + v1.x + v1.y + v1.z + v1.w;
    bf16x8 r;
    r[0] = (short)f2bf(v0.x); r[1] = (short)f2bf(v0.y);
    r[2] = (short)f2bf(v0.z); r[3] = (short)f2bf(v0.w);
    r[4] = (short)f2bf(v1.x); r[5] = (short)f2bf(v1.y);
    r[6] = (short)f2bf(v1.z); r[7] = (short)f2bf(v1.w);
    *(bf16x8*)(dst + j * 2048 + tid * 8) = r;
  }
  float t = blockReduceSum256(s);
  if (tid == 0) sq[b * 256 + c] = t * (1.f / 16384.f);
}

// ---- SE MLP + top128 rank ----
__global__ __launch_bounds__(256) void se_rank_k(const float* __restrict__ sq,
                                                 const float* __restrict__ sew1,
                                                 const float* __restrict__ sew2,
                                                 int* __restrict__ idx) {
  int b = blockIdx.x, tid = threadIdx.x;
  __shared__ float s_sq[256], s_h1[32], s_cw[256];
  s_sq[tid] = sq[b * 256 + tid];
  __syncthreads();
  if (tid < 32) {
    float s = 0.f;
    for (int c = 0; c < 256; ++c) s += s_sq[c] * sew1[tid * 256 + c];
    s_h1[tid] = fmaxf(s, 0.f);
  }
  __syncthreads();
  {
    float s = 0.f;
    #pragma unroll
    for (int j = 0; j < 32; ++j) s += s_h1[j] * sew2[tid * 32 + j];
    s_cw[tid] = 1.f / (1.f + expf(-s));
  }
  __syncthreads();
  float my = s_cw[tid];
  int rk = 0;
  for (int c = 0; c < 256; ++c) {
    float o = s_cw[c];
    rk += (o > my) || (o == my && c < tid);
  }
  if (rk < 128) idx[b * 128 + rk] = tid;
}

// ---- text MLP layer1 ----
__global__ __launch_bounds__(256) void text1_k(const float* __restrict__ tc,
                                               const float* __restrict__ tw1,
                                               const float* __restrict__ tb1,
                                               float* __restrict__ t1f) {
  int b = blockIdx.y, j0 = blockIdx.x * 8, tid = threadIdx.x;
  __shared__ float s_tc[512];
  s_tc[tid] = tc[b * 512 + tid];
  s_tc[tid + 256] = tc[b * 512 + 256 + tid];
  __syncthreads();
  int w = tid >> 6, lane = tid & 63;
  #pragma unroll
  for (int r = 0; r < 2; ++r) {
    int j = j0 + w * 2 + r;
    const float* wr = tw1 + (long)j * 512;
    float s = 0.f;
    #pragma unroll
    for (int k = 0; k < 8; ++k) s += s_tc[lane + k * 64] * wr[lane + k * 64];
    #pragma unroll
    for (int o = 32; o > 0; o >>= 1) s += __shfl_down(s, o, 64);
    if (lane == 0) t1f[b * 512 + j] = fmaxf(s + tb1[j], 0.f);
  }
}

// ---- text MLP layer2 ----
__global__ __launch_bounds__(256) void text2_k(const float* __restrict__ t1f,
                                               const float* __restrict__ tw2,
                                               const float* __restrict__ tb2,
                                               float* __restrict__ tf) {
  int b = blockIdx.y, j0 = blockIdx.x * 8, tid = threadIdx.x;
  __shared__ float s_t1[512];
  s_t1[tid] = t1f[b * 512 + tid];
  s_t1[tid + 256] = t1f[b * 512 + 256 + tid];
  __syncthreads();
  int w = tid >> 6, lane = tid & 63;
  #pragma unroll
  for (int r = 0; r < 2; ++r) {
    int j = j0 + w * 2 + r;
    const float* wr = tw2 + (long)j * 512;
    float s = 0.f;
    #pragma unroll
    for (int k = 0; k < 8; ++k) s += s_t1[lane + k * 64] * wr[lane + k * 64];
    #pragma unroll
    for (int o = 32; o > 0; o >>= 1) s += __shfl_down(s, o, 64);
    if (lane == 0) tf[b * 256 + j] = s + tb2[j];
  }
}

// ---- argsort-rank of tf -> sidx ----
__global__ __launch_bounds__(256) void rank2_k(const float* __restrict__ tf,
                                               int* __restrict__ sidx) {
  int b = blockIdx.x, tid = threadIdx.x;
  __shared__ float s_tf[256];
  s_tf[tid] = tf[b * 256 + tid];
  __syncthreads();
  float my = s_tf[tid];
  int rk = 0;
  for (int c = 0; c < 256; ++c) {
    float o = s_tf[c];
    rk += (o > my) || (o == my && c < tid);
  }
  sidx[b * 256 + rk] = tid;
}

// ---- fold conv1x1+shuffle+conv_out+select into hi/lo bf16 M_b[128,256] ----
__global__ __launch_bounds__(128) void mcomb_k(const float* __restrict__ w2,
                                               const float* __restrict__ w2b,
                                               const float* __restrict__ w1,
                                               const float* __restrict__ w1b,
                                               const int* __restrict__ idx,
                                               const int* __restrict__ sidx,
                                               u16* __restrict__ mch,
                                               u16* __restrict__ mcl,
                                               float* __restrict__ bcomb) {
  int o = blockIdx.x, b = blockIdx.y, tid = threadIdx.x;
  __shared__ float s_w2[256];
  __shared__ int s_sx[256];
  s_w2[tid] = w2[o * 256 + tid];
  s_w2[tid + 128] = w2[o * 256 + tid + 128];
  s_sx[tid] = sidx[b * 256 + tid] & 255;
  s_sx[tid + 128] = sidx[b * 256 + tid + 128] & 255;
  u16* hrow = mch + ((long)b * 128 + o) * 256;
  u16* lrow = mcl + ((long)b * 128 + o) * 256;
  hrow[tid] = 0; hrow[tid + 128] = 0;
  lrow[tid] = 0; lrow[tid + 128] = 0;
  __syncthreads();
  float s = 0.f;
  for (int j = 0; j < 256; ++j) s += s_w2[j] * w1[s_sx[j] * 128 + tid];
  int cc = idx[b * 128 + tid] & 255;
  u16 hi = f2bf(s);
  hrow[cc] = hi;
  lrow[cc] = f2bf(s - bf2f(hi));
  if (tid == 0) {
    float bb = w2b[o];
    for (int j = 0; j < 256; ++j) bb += s_w2[j] * w1b[s_sx[j]];
    bcomb[b * 128 + o] = bb;
  }
}

// ---- fused dual GEMM (128-row o-tile); all-bf16 A staging ----
__global__ __launch_bounds__(256) void gemm_dual_k(
    const u16* __restrict__ W2b, const float* __restrict__ b2,
    const u16* __restrict__ Mch, const u16* __restrict__ Mcl,
    const float* __restrict__ bc, const u16* __restrict__ Xb,
    float* __restrict__ out1, u16* __restrict__ img2b, u16* __restrict__ qin) {
  const int N = N_PIX;
  int n0 = blockIdx.x * 64, bz = blockIdx.y, tid = threadIdx.x;
  __shared__ __align__(16) u16 A1[128][40];
  __shared__ __align__(16) u16 A2h[128][40];
  __shared__ __align__(16) u16 A2l[128][40];
  __shared__ __align__(16) u16 Xs[64][40];
  f32x4 acc1[2][4], acc2[2][4];
  #pragma unroll
  for (int ot = 0; ot < 2; ++ot)
    #pragma unroll
    for (int i = 0; i < 4; ++i) { acc1[ot][i] = (f32x4){0,0,0,0}; acc2[ot][i] = (f32x4){0,0,0,0}; }
  int wv = tid >> 6, lane = tid & 63;
  int lr = lane & 15, lk = (lane >> 4) * 8;
  for (int kt = 0; kt < 8; ++kt) {
    int k0 = kt << 5;
    #pragma unroll
    for (int ot = 0; ot < 2; ++ot) {
      int r = (tid >> 2) + ot * 64, cb = (tid & 3) << 3;
      *(bf16x8*)&A1[r][cb] = *(const bf16x8*)(W2b + (long)r * 256 + k0 + cb);
      *(bf16x8*)&A2h[r][cb] = *(const bf16x8*)(Mch + ((long)bz * 128 + r) * 256 + k0 + cb);
      *(bf16x8*)&A2l[r][cb] = *(const bf16x8*)(Mcl + ((long)bz * 128 + r) * 256 + k0 + cb);
    }
    {
      int n = tid & 63, kb = (tid >> 6) << 3;
      const u16* src = Xb + ((long)bz * 256 + k0 + kb) * N + n0 + n;
      bf16x8 t;
      #pragma unroll
      for (int i = 0; i < 8; ++i) t[i] = (short)src[(long)i * N];
      *(bf16x8*)&Xs[n][kb] = t;
    }
    __syncthreads();
    bf16x8 bfr[4];
    #pragma unroll
    for (int nt = 0; nt < 4; ++nt) bfr[nt] = *(const bf16x8*)&Xs[nt * 16 + lr][lk];
    #pragma unroll
    for (int ot = 0; ot < 2; ++ot) {
      bf16x8 a1 = *(const bf16x8*)&A1[ot * 64 + wv * 16 + lr][lk];
      bf16x8 a2h = *(const bf16x8*)&A2h[ot * 64 + wv * 16 + lr][lk];
      bf16x8 a2l = *(const bf16x8*)&A2l[ot * 64 + wv * 16 + lr][lk];
      #pragma unroll
      for (int nt = 0; nt < 4; ++nt) {
        acc1[ot][nt] = __builtin_amdgcn_mfma_f32_16x16x32_bf16(a1, bfr[nt], acc1[ot][nt], 0, 0, 0);
        acc2[ot][nt] = __builtin_amdgcn_mfma_f32_16x16x32_bf16(a2h, bfr[nt], acc2[ot][nt], 0, 0, 0);
        acc2[ot][nt] = __builtin_amdgcn_mfma_f32_16x16x32_bf16(a2l, bfr[nt], acc2[ot][nt], 0, 0, 0);
      }
    }
    __syncthreads();
  }
  #pragma unroll
  for (int ot = 0; ot < 2; ++ot)
    #pragma unroll
    for (int nt = 0; nt < 4; ++nt)
      #pragma unroll
      for (int r4 = 0; r4 < 4; ++r4) {
        int o = ot * 64 + wv * 16 + (lane >> 4) * 4 + r4;
        int n = n0 + nt * 16 + (lane & 15);
        long oi = ((long)bz * 128 + o) * N + n;
        float v1 = acc1[ot][nt][r4] + b2[o];
        out1[oi] = v1;
        img2b[oi] = f2bf(v1);
        qin[oi] = f2bf(acc2[ot][nt][r4] + bc[bz * 128 + o]);
      }
}

// ---------------- generic MFMA GEMM ----------------
// AMODE: 0 = f32 weights (convert on stage), 2 = bf16 weights, 3 = per-batch bf16 hi/lo
template<int AMODE, int BIAS, int RESADD, int OUTF, int OT>
__global__ __launch_bounds__(256) void gemm_k(
    const float* __restrict__ Af, const u16* __restrict__ Ah,
    const u16* __restrict__ Alo, long a_bstride,
    const u16* __restrict__ X, long x_bstride,
    const float* __restrict__ bias, long bias_bstride,
    const u16* __restrict__ res, long res_bstride,
    void* __restrict__ outv, long out_bstride,
    int O, int K) {
  const int N = N_PIX;
  int n0 = blockIdx.x * 64;
  int o0 = blockIdx.y * 64 * OT;
  int bz = blockIdx.z;
  int tid = threadIdx.x;
  __shared__ __align__(16) u16 As[64 * OT][40];
  __shared__ __align__(16) u16 Al[(AMODE == 3) ? 64 * OT : 1][40];
  __shared__ __align__(16) u16 Xs[64][40];
  f32x4 acc[OT][4];
  #pragma unroll
  for (int ot = 0; ot < OT; ++ot)
    #pragma unroll
    for (int i = 0; i < 4; ++i) acc[ot][i] = (f32x4){0.f, 0.f, 0.f, 0.f};
  int wv = tid >> 6, lane = tid & 63;
  int lr = lane & 15, lk = (lane >> 4) * 8;
  int nk = (K + 31) >> 5;
  for (int kt = 0; kt < nk; ++kt) {
    int k0 = kt << 5;
    #pragma unroll
    for (int ot = 0; ot < OT; ++ot) {
      int r = (tid >> 2) + ot * 64, cb = (tid & 3) << 3;
      int o = o0 + r;
      if (AMODE == 0) {
        bf16x8 wv8;
        if (o < O && (k0 + cb + 8 <= K)) {
          const float* ap = Af + (long)o * K + k0 + cb;
          f32x4 v0 = *(const f32x4*)ap;
          f32x4 v1 = *(const f32x4*)(ap + 4);
          float av[8] = {v0.x, v0.y, v0.z, v0.w, v1.x, v1.y, v1.z, v1.w};
          #pragma unroll
          for (int i = 0; i < 8; ++i) wv8[i] = (short)f2bf(av[i]);
        } else {
          #pragma unroll
          for (int i = 0; i < 8; ++i) {
            int k = k0 + cb + i;
            wv8[i] = (short)((o < O && k < K) ? f2bf(Af[(long)o * K + k]) : (u16)0);
          }
        }
        *(bf16x8*)&As[r][cb] = wv8;
      } else if (AMODE == 2) {
        bf16x8 t;
        if (o < O && (k0 + cb + 8 <= K)) {
          t = *(const bf16x8*)(Ah + (long)o * K + k0 + cb);
        } else {
          #pragma unroll
          for (int i = 0; i < 8; ++i) {
            int k = k0 + cb + i;
            t[i] = (short)((o < O && k < K) ? Ah[(long)o * K + k] : (u16)0);
          }
        }
        *(bf16x8*)&As[r][cb] = t;
      } else {  // AMODE 3
        long base = (long)bz * a_bstride + (long)o * K + k0 + cb;
        *(bf16x8*)&As[r][cb] = *(const bf16x8*)(Ah + base);
        *(bf16x8*)&Al[r][cb] = *(const bf16x8*)(Alo + base);
      }
    }
    {
      int n = tid & 63, kb = (tid >> 6) << 3;
      int k = k0 + kb;
      const u16* src = X + (long)bz * x_bstride + n0 + n;
      bf16x8 t;
      #pragma unroll
      for (int i = 0; i < 8; ++i)
        t[i] = (short)((k + i < K) ? src[(long)(k + i) * N] : (u16)0);
      *(bf16x8*)&Xs[n][kb] = t;
    }
    __syncthreads();
    bf16x8 bfr[4];
    #pragma unroll
    for (int nt = 0; nt < 4; ++nt) bfr[nt] = *(const bf16x8*)&Xs[nt * 16 + lr][lk];
    #pragma unroll
    for (int ot = 0; ot < OT; ++ot) {
      bf16x8 afr = *(const bf16x8*)&As[ot * 64 + wv * 16 + lr][lk];
      bf16x8 alr;
      if (AMODE == 3) alr = *(const bf16x8*)&Al[ot * 64 + wv * 16 + lr][lk];
      #pragma unroll
      for (int nt = 0; nt < 4; ++nt) {
        acc[ot][nt] = __builtin_amdgcn_mfma_f32_16x16x32_bf16(afr, bfr[nt], acc[ot][nt], 0, 0, 0);
        if (AMODE == 3)
          acc[ot][nt] = __builtin_amdgcn_mfma_f32_16x16x32_bf16(alr, bfr[nt], acc[ot][nt], 0, 0, 0);
      }
    }
    __syncthreads();
  }
  #pragma unroll
  for (int ot = 0; ot < OT; ++ot)
    #pragma unroll
    for (int nt = 0; nt < 4; ++nt)
      #pragma unroll
      for (int r4 = 0; r4 < 4; ++r4) {
        int o = o0 + ot * 64 + wv * 16 + (lane >> 4) * 4 + r4;
        int n = n0 + nt * 16 + (lane & 15);
        if (o < O) {
          float v = acc[ot][nt][r4];
          if (BIAS == 1) v += bias[o];
          if (BIAS == 2) v += bias[(long)bz * bias_bstride + o];
          if (RESADD) v += bf2f(res[(long)bz * res_bstride + (long)o * N + n]);
          long oi = (long)bz * out_bstride + (long)o * N + n;
          if (OUTF) ((float*)outv)[oi] = v;
          else ((u16*)outv)[oi] = f2bf(v);
        }
      }
}

// ---------------- LayerNorm over channel dim (C=128), bf16 in ----------------
__global__ __launch_bounds__(256) void ln_k(const u16* __restrict__ in,
                                            const float* __restrict__ gamma,
                                            const float* __restrict__ beta,
                                            u16* __restrict__ out) {
  int p0 = blockIdx.x * 64, b = blockIdx.y, tid = threadIdx.x;
  int px = tid & 63, g4 = tid >> 6;
  __shared__ float tile[128][65];
  __shared__ float red[8][64];
  __shared__ float gmm[128], bta[128], mu_s[64], rs_s[64];
  if (tid < 128) { gmm[tid] = gamma[tid]; bta[tid] = beta[tid]; }
  long bofs = (long)b * 128 * N_PIX;
  float s = 0.f;
  for (int c = g4; c < 128; c += 4) {
    float v = bf2f(in[bofs + (long)c * N_PIX + p0 + px]);
    tile[c][px] = v;
    s += v;
  }
  red[g4][px] = s;
  __syncthreads();
  if (g4 == 0) mu_s[px] = (red[0][px] + red[1][px] + red[2][px] + red[3][px]) * (1.f / 128.f);
  __syncthreads();
  float mu = mu_s[px];
  float s2 = 0.f;
  for (int c = g4; c < 128; c += 4) { float d = tile[c][px] - mu; s2 += d * d; }
  red[4 + g4][px] = s2;
  __syncthreads();
  if (g4 == 0) {
    float var = (red[4][px] + red[5][px] + red[6][px] + red[7][px]) * (1.f / 128.f);
    rs_s[px] = rsqrtf(var + 1e-5f);
  }
  __syncthreads();
  float rs = rs_s[px];
  for (int c = g4; c < 128; c += 4)
    out[bofs + (long)c * N_PIX + p0 + px] = f2bf((tile[c][px] - mu) * rs * gmm[c] + bta[c]);
}

// ---- LDS-tiled depthwise 3x3 ----
__global__ __launch_bounds__(256) void dw3t_k(const u16* __restrict__ in,
                                              const float* __restrict__ w,
                                              u16* __restrict__ out, int C) {
  int plane = blockIdx.x >> 3, stripe = blockIdx.x & 7, tid = threadIdx.x;
  int c = plane % C;
  long pbase = (long)plane * N_PIX;
  int y0 = stripe * 16;
  __shared__ __align__(16) u16 tile[18][136];
  for (int v = tid; v < 288; v += 256) {
    int r = v >> 4, col = (v & 15) << 3;
    int y = y0 - 1 + r;
    bf16x8 t;
    #pragma unroll
    for (int i = 0; i < 8; ++i) t[i] = 0;
    if (y >= 0 && y < 128) t = *(const bf16x8*)(in + pbase + y * 128 + col);
    *(bf16x8*)&tile[r][col] = t;
  }
  float wv[9];
  #pragma unroll
  for (int j = 0; j < 9; ++j) wv[j] = w[c * 9 + j];
  __syncthreads();
  int row = tid >> 4, col0 = (tid & 15) << 3;
  float a[3][10];
  #pragma unroll
  for (int dr = 0; dr < 3; ++dr)
    #pragma unroll
    for (int i = 0; i < 10; ++i) {
      int x = col0 - 1 + i;
      a[dr][i] = (x >= 0 && x < 128) ? bf2f(tile[row + dr][x]) : 0.f;
    }
  bf16x8 res;
  #pragma unroll
  for (int j = 0; j < 8; ++j) {
    float s = 0.f;
    #pragma unroll
    for (int dr = 0; dr < 3; ++dr)
      #pragma unroll
      for (int dx = 0; dx < 3; ++dx) s += wv[dr * 3 + dx] * a[dr][j + dx];
    res[j] = (short)f2bf(s);
  }
  *(bf16x8*)(out + pbase + (y0 + row) * 128 + col0) = res;
}

// ---- LDS-tiled fused FFN tail: g = gelu(dw3(t1)) * dw3(t2), 340 planes ----
__global__ __launch_bounds__(256) void dw3gelu_t_k(const u16* __restrict__ t1,
                                                   const u16* __restrict__ t2,
                                                   const float* __restrict__ w,
                                                   u16* __restrict__ g) {
  int plane = blockIdx.x >> 3, stripe = blockIdx.x & 7, tid = threadIdx.x;
  long pbase = (long)plane * N_PIX;
  int y0 = stripe * 16;
  __shared__ __align__(16) u16 ta[18][136];
  __shared__ __align__(16) u16 tb[18][136];
  for (int v = tid; v < 288; v += 256) {
    int r = v >> 4, col = (v & 15) << 3;
    int y = y0 - 1 + r;
    bf16x8 u1, u2;
    #pragma unroll
    for (int i = 0; i < 8; ++i) { u1[i] = 0; u2[i] = 0; }
    if (y >= 0 && y < 128) {
      u1 = *(const bf16x8*)(t1 + pbase + y * 128 + col);
      u2 = *(const bf16x8*)(t2 + pbase + y * 128 + col);
    }
    *(bf16x8*)&ta[r][col] = u1;
    *(bf16x8*)&tb[r][col] = u2;
  }
  float w1[9], w2[9];
  #pragma unroll
  for (int j = 0; j < 9; ++j) { w1[j] = w[plane * 9 + j]; w2[j] = w[(340 + plane) * 9 + j]; }
  __syncthreads();
  int row = tid >> 4, col0 = (tid & 15) << 3;
  float a[3][10], b[3][10];
  #pragma unroll
  for (int dr = 0; dr < 3; ++dr)
    #pragma unroll
    for (int i = 0; i < 10; ++i) {
      int x = col0 - 1 + i;
      bool ok = (x >= 0 && x < 128);
      a[dr][i] = ok ? bf2f(ta[row + dr][x]) : 0.f;
      b[dr][i] = ok ? bf2f(tb[row + dr][x]) : 0.f;
    }
  bf16x8 res;
  #pragma unroll
  for (int j = 0; j < 8; ++j) {
    float s1 = 0.f, s2 = 0.f;
    #pragma unroll
    for (int dr = 0; dr < 3; ++dr)
      #pragma unroll
      for (int dx = 0; dx < 3; ++dx) {
        s1 += w1[dr * 3 + dx] * a[dr][j + dx];
        s2 += w2[dr * 3 + dx] * b[dr][j + dx];
      }
    float gl = 0.5f * s1 * (1.f + erff(s1 * 0.70710678118f));
    res[j] = (short)f2bf(gl * s2);
  }
  *(bf16x8*)(g + pbase + (y0 + row) * 128 + col0) = res;
}

// ---------------- row L2 norms (bf16 in) ----------------
__global__ __launch_bounds__(256) void rownorm_k(const u16* __restrict__ base, long bstride,
                                                 float* __restrict__ out) {
  int r = blockIdx.x, b = blockIdx.y, tid = threadIdx.x;
  const u16* src = base + (long)b * bstride + (long)r * N_PIX;
  float s = 0.f;
  #pragma unroll
  for (int j = 0; j < 8; ++j) {
    bf16x8 v = *(const bf16x8*)(src + j * 2048 + tid * 8);
    #pragma unroll
    for (int i = 0; i < 8; ++i) { float f = bf2f((u16)v[i]); s += f * f; }
  }
  float t = blockReduceSum256(s);
  if (tid == 0) out[b * 128 + r] = sqrtf(t);
}

// ---- attn partials: per 256-pixel chunk, 16x16 Gram ----
__global__ __launch_bounds__(256) void attn_part_k(const u16* __restrict__ q,
                                                   const u16* __restrict__ kbase,
                                                   long kbstride,
                                                   float* __restrict__ part) {
  int ch = blockIdx.x, h = blockIdx.y, b = blockIdx.z, tid = threadIdx.x;
  int n0 = ch * 256;
  __shared__ __align__(16) u16 qc[16][280];
  __shared__ __align__(16) u16 kc[16][280];
  #pragma unroll
  for (int j = 0; j < 2; ++j) {
    int v = tid + j * 256;
    int r = v >> 5, col = (v & 31) << 3;
    *(bf16x8*)&qc[r][col] = *(const bf16x8*)(q + ((long)b * 128 + h * 16 + r) * N_PIX + n0 + col);
    *(bf16x8*)&kc[r][col] = *(const bf16x8*)(kbase + (long)b * kbstride + (long)(h * 16 + r) * N_PIX + n0 + col);
  }
  __syncthreads();
  int c = tid >> 4, d = tid & 15;
  float acc = 0.f;
  #pragma unroll 4
  for (int nb = 0; nb < 32; ++nb) {
    bf16x8 qv = *(const bf16x8*)&qc[c][nb * 8];
    bf16x8 kv = *(const bf16x8*)&kc[d][nb * 8];
    #pragma unroll
    for (int i = 0; i < 8; ++i) acc += bf2f((u16)qv[i]) * bf2f((u16)kv[i]);
  }
  part[(long)((((b * 8 + h) * 16 + c) * 16 + d)) * 64 + ch] = acc;
}

// ---- reduce partials + cosine scaling ----
__global__ __launch_bounds__(256) void attn_reduce_k(const float* __restrict__ part,
                                                     const float* __restrict__ qn,
                                                     const float* __restrict__ kn,
                                                     const float* __restrict__ temp,
                                                     float* __restrict__ attnm) {
  int idx = blockIdx.x * 256 + threadIdx.x;
  const float* p = part + (long)idx * 64;
  float s = 0.f;
  #pragma unroll
  for (int j = 0; j < 64; ++j) s += p[j];
  int d = idx & 15, c = (idx >> 4) & 15, h = (idx >> 8) & 7, b = idx >> 11;
  float nq = fmaxf(qn[b * 128 + h * 16 + c], 1e-12f);
  float nk = fmaxf(kn[b * 128 + h * 16 + d], 1e-12f);
  attnm[idx] = s / (nq * nk) * temp[h];
}

// ---- top14 threshold + softmax + fold proj into hi/lo Cmb[b,128,128] ----
__global__ __launch_bounds__(128) void score_cmb_k(const float* __restrict__ attnm,
                                                   const float* __restrict__ projw,
                                                   const float* __restrict__ attn4p,
                                                   u16* __restrict__ cmbh,
                                                   u16* __restrict__ cmbl) {
  int b = blockIdx.x, tid = threadIdx.x;
  __shared__ float att_s[2048], score_s[2048];
  for (int i = tid; i < 2048; i += 128) att_s[i] = attnm[(long)b * 2048 + i];
  __syncthreads();
  {
    int h = tid >> 4, c = tid & 15;
    float v[16], t[16];
    #pragma unroll
    for (int d = 0; d < 16; ++d) { v[d] = att_s[(h * 16 + c) * 16 + d]; t[d] = v[d]; }
    float thr = 0.f, M = -1e30f;
    for (int it = 0; it < 14; ++it) {
      float m = -1e30f; int mi = 0;
      #pragma unroll
      for (int d = 0; d < 16; ++d) if (t[d] > m) { m = t[d]; mi = d; }
      if (it == 0) M = m;
      thr = m;
      t[mi] = -1e31f;
    }
    float s = 0.f, e[16];
    #pragma unroll
    for (int d = 0; d < 16; ++d) { e[d] = (v[d] >= thr) ? expf(v[d] - M) : 0.f; s += e[d]; }
    float inv = 1.f / s;
    #pragma unroll
    for (int d = 0; d < 16; ++d) score_s[(h * 16 + c) * 16 + d] = e[d] * inv;
  }
  __syncthreads();
  float a4 = attn4p[0];
  int o = tid;
  for (int hd = 0; hd < 128; ++hd) {
    int h = hd >> 4, d = hd & 15;
    float s = 0.f;
    #pragma unroll
    for (int c = 0; c < 16; ++c)
      s += projw[o * 128 + h * 16 + c] * score_s[(h * 16 + c) * 16 + d];
    float v = a4 * s;
    long oi = ((long)b * 128 + o) * 128 + hd;
    u16 hi = f2bf(v);
    cmbh[oi] = hi;
    cmbl[oi] = f2bf(v - bf2f(hi));
  }
}

extern "C" void kernel_launch(void* const* d_in, const int* in_sizes, int n_in,
                              void* d_out, int out_size, void* d_ws, size_t ws_size,
                              hipStream_t stream) {
  (void)in_sizes; (void)n_in; (void)out_size; (void)ws_size;
  const float* vi        = (const float*)d_in[0];
  const float* ir        = (const float*)d_in[1];
  const float* text_code = (const float*)d_in[2];
  const float* se_w1     = (const float*)d_in[3];
  const float* se_w2     = (const float*)d_in[4];
  const float* conv1x1_w = (const float*)d_in[5];
  const float* conv1x1_b = (const float*)d_in[6];
  const float* conv_out_w= (const float*)d_in[7];
  const float* conv_out_b= (const float*)d_in[8];
  const float* text_w1   = (const float*)d_in[9];
  const float* text_b1   = (const float*)d_in[10];
  const float* text_w2   = (const float*)d_in[11];
  const float* text_b2   = (const float*)d_in[12];
  const float* norm1_w   = (const float*)d_in[13];
  const float* norm1_b   = (const float*)d_in[14];
  const float* norm2_w   = (const float*)d_in[15];
  const float* norm2_b   = (const float*)d_in[16];
  const float* norm3_w   = (const float*)d_in[17];
  const float* norm3_b   = (const float*)d_in[18];
  const float* q_w       = (const float*)d_in[19];
  const float* q_dw_w    = (const float*)d_in[20];
  const float* kv_w      = (const float*)d_in[21];
  const float* kv_dw_w   = (const float*)d_in[22];
  const float* temperature = (const float*)d_in[23];
  const float* attn4     = (const float*)d_in[24];
  const float* proj_w    = (const float*)d_in[25];
  const float* ffn_in_w  = (const float*)d_in[26];
  const float* ffn_dw_w  = (const float*)d_in[27];
  const float* ffn_out_w = (const float*)d_in[28];
  float* out0 = (float*)d_out;
  float* out1 = out0 + NP;

  char* W = (char*)d_ws;
  float* sq_f  = (float*)(W + 0);        // 4K
  int*   idx_i = (int*)(W + 4096);       // 2K
  int*   sidx_i= (int*)(W + 6144);       // 4K
  u16*   Mch   = (u16*)(W + 12288);      // 256K
  u16*   Mcl   = (u16*)(W + 274432);     // 256K
  float* bcomb = (float*)(W + 536576);   // 2K
  float* qn_f  = (float*)(W + 538624);   // 2K
  float* kn_f  = (float*)(W + 540672);   // 2K
  float* attnm = (float*)(W + 542720);   // 32K
  u16*   cmbh  = (u16*)(W + 575488);     // 128K
  u16*   cmbl  = (u16*)(W + 706560);     // 128K
  float* t1f   = (float*)(W + 834560);   // 8K
  float* tf_f  = (float*)(W + 842752);   // 4K
  u16*   W2b   = (u16*)(W + 846848);     // 64K  (conv_out_w bf16)
  u16*   qwb   = (u16*)(W + 912384);     // 32K
  u16*   kvwb  = (u16*)(W + 945152);     // 64K -> ends 1010688 < 1MiB
  u16* S   = (u16*)(W + (1 << 20));       // arena 2048*N_PIX u16 (64 MiB)
  u16* CC  = S;                           // [0,512N): qin->xq->Q->x3
  u16* KD  = S + 512L * N_PIX;            // [512N,1024N): img2b->xkv -> ATT
  u16* CBF = S + 1024L * N_PIX;           // [1024N,2048N): concat bf16
  u16* QT  = S + 1024L * N_PIX;           // qt temp (CBF dead)
  u16* KVD = S + 1024L * N_PIX;           // K/V dw [4,256,N]
  u16* FT  = S + 1024L * N_PIX;           // FFN t [680N]
  u16* FG  = S + 1704L * N_PIX;           // FFN g [340N]
  u16* KVT = (u16*)out0;                  // kv-proj temp in out0 scratch
  u16* ATT = KD;

  const long SN = 128L * N_PIX;
  const long SN2 = 256L * N_PIX;

  // weight conversions (independent)
  wconv_k<<<128, 256, 0, stream>>>(conv_out_w, W2b, 32768);
  wconv_k<<<64, 256, 0, stream>>>(q_w, qwb, 16384);
  wconv_k<<<128, 256, 0, stream>>>(kv_w, kvwb, 32768);
  // control path
  squeeze_k<<<dim3(256, 4), 256, 0, stream>>>(vi, ir, sq_f, CBF);
  se_rank_k<<<4, 256, 0, stream>>>(sq_f, se_w1, se_w2, idx_i);
  text1_k<<<dim3(64, 4), 256, 0, stream>>>(text_code, text_w1, text_b1, t1f);
  text2_k<<<dim3(32, 4), 256, 0, stream>>>(t1f, text_w2, text_b2, tf_f);
  rank2_k<<<4, 256, 0, stream>>>(tf_f, sidx_i);
  mcomb_k<<<dim3(128, 4), 128, 0, stream>>>(conv_out_w, conv_out_b, conv1x1_w,
                                            conv1x1_b, idx_i, sidx_i, Mch, Mcl, bcomb);
  gemm_dual_k<<<dim3(256, 4), 256, 0, stream>>>(
      W2b, conv_out_b, Mch, Mcl, bcomb, CBF, out1, KD, CC);
  ln_k<<<dim3(256, 4), 256, 0, stream>>>(CC, norm1_w, norm1_b, CC);          // xq
  ln_k<<<dim3(256, 4), 256, 0, stream>>>(KD, norm2_w, norm2_b, KD);          // xkv
  // Q path: qt -> QT, dw3 -> CC
  gemm_k<2, 0, 0, 0, 1><<<dim3(256, 2, 4), 256, 0, stream>>>(
      nullptr, qwb, nullptr, 0, CC, SN, nullptr, 0, nullptr, 0, QT, SN, 128, 128);
  dw3t_k<<<4096, 256, 0, stream>>>(QT, q_dw_w, CC, 128);                     // Q=CC
  // KV path
  gemm_k<2, 0, 0, 0, 1><<<dim3(256, 4, 4), 256, 0, stream>>>(
      nullptr, kvwb, nullptr, 0, KD, SN, nullptr, 0, nullptr, 0, KVT, SN2, 256, 128);
  dw3t_k<<<8192, 256, 0, stream>>>(KVT, kv_dw_w, KVD, 256);                  // K,V
  rownorm_k<<<dim3(128, 4), 256, 0, stream>>>(CC, SN, qn_f);
  rownorm_k<<<dim3(128, 4), 256, 0, stream>>>(KVD, SN2, kn_f);               // K rows
  float* part = (float*)out0;   // KVT dead
  attn_part_k<<<dim3(64, 8, 4), 256, 0, stream>>>(CC, KVD, SN2, part);
  attn_reduce_k<<<32, 256, 0, stream>>>(part, qn_f, kn_f, temperature, attnm);
  score_cmb_k<<<4, 128, 0, stream>>>(attnm, proj_w, attn4, cmbh, cmbl);
  // att = Cmb_b @ V -> ATT
  gemm_k<3, 0, 0, 0, 1><<<dim3(256, 2, 4), 256, 0, stream>>>(
      nullptr, cmbh, cmbl, 128L * 128, KVD + SN, SN2, nullptr, 0, nullptr, 0,
      ATT, SN, 128, 128);
  ln_k<<<dim3(256, 4), 256, 0, stream>>>(ATT, norm3_w, norm3_b, CC);         // x3=CC
  // FFN per batch
  for (int b = 0; b < 4; ++b) {
    const u16* x3b = CC + (long)b * SN;
    gemm_k<0, 0, 0, 0, 1><<<dim3(256, 11, 1), 256, 0, stream>>>(
        ffn_in_w, nullptr, nullptr, 0, x3b, 0, nullptr, 0, nullptr, 0,
        FT, 0, 680, 128);
    dw3gelu_t_k<<<2720, 256, 0, stream>>>(FT, FT + 340L * N_PIX, ffn_dw_w, FG);
    gemm_k<0, 0, 1, 1, 1><<<dim3(256, 2, 1), 256, 0, stream>>>(
        ffn_out_w, nullptr, nullptr, 0, FG, 0, nullptr, 0, ATT + (long)b * SN, 0,
        out0 + (long)b * SN, 0, 128, 340);
  }
}